// Round 1
// baseline (7222.883 us; speedup 1.0000x reference)
//
#include <hip/hip_runtime.h>
#include <cstdint>
#include <cstddef>

#define B_ 2
#define S_ 1024
#define H_ 2048
#define HV_ 32
#define HK_ 16
#define DK_ 128
#define DV_ 128
#define CC_ 8192
#define KEYDIM_ 2048
#define VALDIM_ 4096

// ---------------------------------------------------------------------------
// Generic SGEMM: Out[m][n] = sum_k A[m*Kd + k] * W[n*Kd + k]
// A: (M, Kd) row-major. W: (N, Kd) row-major. Out: (M, N) row-major.
// Requires: M % 64 == 0, Kd % 16 == 0. N arbitrary (guarded).
// ---------------------------------------------------------------------------
__global__ __launch_bounds__(256) void sgemm_nt(
    const float* __restrict__ A, const float* __restrict__ W,
    float* __restrict__ Out, int M, int N, int Kd)
{
  __shared__ float As[16][65];
  __shared__ float Bs[16][65];
  int bm = blockIdx.y, bn = blockIdx.x;
  int t = threadIdx.x;
  int tr = t >> 4, tc = t & 15;       // 16x16 thread grid, each 4x4 outputs
  int lr = t >> 2, lc4 = (t & 3) << 2; // loader: row lr (0..63), 4 cols

  float acc[4][4];
  #pragma unroll
  for (int i = 0; i < 4; i++)
    #pragma unroll
    for (int j = 0; j < 4; j++) acc[i][j] = 0.f;

  const float* aBase = A + (size_t)(bm * 64 + lr) * Kd + lc4;
  int n_load = bn * 64 + lr;
  const float* wBase = W + (size_t)n_load * Kd + lc4;

  for (int k0 = 0; k0 < Kd; k0 += 16) {
    float4 av = *(const float4*)(aBase + k0);
    float4 wv = make_float4(0.f, 0.f, 0.f, 0.f);
    if (n_load < N) wv = *(const float4*)(wBase + k0);
    As[lc4 + 0][lr] = av.x; As[lc4 + 1][lr] = av.y;
    As[lc4 + 2][lr] = av.z; As[lc4 + 3][lr] = av.w;
    Bs[lc4 + 0][lr] = wv.x; Bs[lc4 + 1][lr] = wv.y;
    Bs[lc4 + 2][lr] = wv.z; Bs[lc4 + 3][lr] = wv.w;
    __syncthreads();
    #pragma unroll
    for (int kk = 0; kk < 16; kk++) {
      float ar[4], br[4];
      #pragma unroll
      for (int i = 0; i < 4; i++) ar[i] = As[kk][tr * 4 + i];
      #pragma unroll
      for (int j = 0; j < 4; j++) br[j] = Bs[kk][tc * 4 + j];
      #pragma unroll
      for (int i = 0; i < 4; i++)
        #pragma unroll
        for (int j = 0; j < 4; j++)
          acc[i][j] += ar[i] * br[j];
    }
    __syncthreads();
  }

  #pragma unroll
  for (int i = 0; i < 4; i++) {
    int m = bm * 64 + tr * 4 + i;
    #pragma unroll
    for (int j = 0; j < 4; j++) {
      int n = bn * 64 + tc * 4 + j;
      if (n < N) Out[(size_t)m * N + n] = acc[i][j];
    }
  }
}

// ---------------------------------------------------------------------------
// conv_state_new[b][c][j] = mixed_qkv[b][S-3+j][c]   (from (B,S,C) layout)
// ---------------------------------------------------------------------------
__global__ void convstate_kernel(const float* __restrict__ qkv_raw,
                                 float* __restrict__ out)
{
  int idx = blockIdx.x * blockDim.x + threadIdx.x;
  if (idx >= B_ * CC_ * 3) return;
  int j = idx % 3;
  int c = (idx / 3) % CC_;
  int b = idx / (3 * CC_);
  out[idx] = qkv_raw[((size_t)(b * S_ + (S_ - 3 + j))) * CC_ + c];
}

// ---------------------------------------------------------------------------
// Fused scan: per (b, hv) head. 128 threads; thread t owns state column v=t
// (128 fp32 in registers). Fuses: causal conv (K=4) + silu for q/k/v channels,
// l2norm(q)/l2norm(k), beta/g scalars, the sequential delta-rule scan,
// RMS-norm over Dv, norm_weight, silu(z) gating (written in-place over z).
// ---------------------------------------------------------------------------
__global__ __launch_bounds__(128) void scan_kernel(
    const float* __restrict__ qkv_raw,     // (B,S,C)
    const float* __restrict__ conv_state,  // (B,C,3)
    const float* __restrict__ conv_w,      // (C,4)
    const float* __restrict__ rec_state,   // (B,HV,DK,DV)
    const float* __restrict__ b_act,       // (B,S,HV)
    const float* __restrict__ a_act,       // (B,S,HV)
    const float* __restrict__ A_log,       // (HV)
    const float* __restrict__ dt_bias,     // (HV)
    const float* __restrict__ norm_weight, // (DV)
    float* __restrict__ z_gated,           // (B,S,VALDIM) in/out
    float* __restrict__ final_state)       // (B,HV,DK,DV)
{
  const int blk = blockIdx.x;   // 0..63
  const int b  = blk >> 5;
  const int hv = blk & 31;
  const int hk = hv >> 1;
  const int t  = threadIdx.x;   // column v

  const int cq = hk * DK_ + t;
  const int ck = KEYDIM_ + hk * DK_ + t;
  const int cv = 2 * KEYDIM_ + hv * DV_ + t;

  // conv weights for this thread's 3 channels
  const float wq0 = conv_w[cq * 4 + 0], wq1 = conv_w[cq * 4 + 1],
              wq2 = conv_w[cq * 4 + 2], wq3 = conv_w[cq * 4 + 3];
  const float wk0 = conv_w[ck * 4 + 0], wk1 = conv_w[ck * 4 + 1],
              wk2 = conv_w[ck * 4 + 2], wk3 = conv_w[ck * 4 + 3];
  const float wv0 = conv_w[cv * 4 + 0], wv1 = conv_w[cv * 4 + 1],
              wv2 = conv_w[cv * 4 + 2], wv3 = conv_w[cv * 4 + 3];

  // conv window shift registers: h0 = x[s-3], h1 = x[s-2], h2 = x[s-1]
  float hq0 = conv_state[(size_t)(b * CC_ + cq) * 3 + 0];
  float hq1 = conv_state[(size_t)(b * CC_ + cq) * 3 + 1];
  float hq2 = conv_state[(size_t)(b * CC_ + cq) * 3 + 2];
  float hk0 = conv_state[(size_t)(b * CC_ + ck) * 3 + 0];
  float hk1 = conv_state[(size_t)(b * CC_ + ck) * 3 + 1];
  float hk2 = conv_state[(size_t)(b * CC_ + ck) * 3 + 2];
  float hv0 = conv_state[(size_t)(b * CC_ + cv) * 3 + 0];
  float hv1 = conv_state[(size_t)(b * CC_ + cv) * 3 + 1];
  float hv2 = conv_state[(size_t)(b * CC_ + cv) * 3 + 2];

  // state column in registers
  float st[DK_];
  #pragma unroll
  for (int k = 0; k < DK_; k++)
    st[k] = rec_state[((size_t)(b * HV_ + hv) * DK_ + k) * DV_ + t];

  const float negexpA = -__expf(A_log[hv]);
  const float dtb = dt_bias[hv];
  const float nw = norm_weight[t];
  const float qscale = 0.08838834764831845f;  // 128^-0.5

  __shared__ float sq[128], sk[128];
  __shared__ float redA[4];
  __shared__ float redB[2];

  const float* bptr = b_act + (size_t)b * S_ * HV_ + hv;
  const float* aptr = a_act + (size_t)b * S_ * HV_ + hv;

  // preload s = 0
  const float* row0 = qkv_raw + ((size_t)(b * S_ + 0)) * CC_;
  float xq = row0[cq], xk = row0[ck], xv = row0[cv];
  float bcur = bptr[0], acur = aptr[0];

  for (int s = 0; s < S_; ++s) {
    // ---- prefetch next row (hides HBM/L3 latency behind compute) ----
    float nq = 0.f, nk = 0.f, nv = 0.f, nb = 0.f, na = 0.f;
    if (s + 1 < S_) {
      const float* nrow = qkv_raw + ((size_t)(b * S_ + s + 1)) * CC_;
      nq = nrow[cq]; nk = nrow[ck]; nv = nrow[cv];
      nb = bptr[(s + 1) * HV_]; na = aptr[(s + 1) * HV_];
    }

    // ---- conv (K=4) + silu ----
    float q_ = wq0 * hq0 + wq1 * hq1 + wq2 * hq2 + wq3 * xq;
    float k_ = wk0 * hk0 + wk1 * hk1 + wk2 * hk2 + wk3 * xk;
    float v_ = wv0 * hv0 + wv1 * hv1 + wv2 * hv2 + wv3 * xv;
    hq0 = hq1; hq1 = hq2; hq2 = xq;
    hk0 = hk1; hk1 = hk2; hk2 = xk;
    hv0 = hv1; hv1 = hv2; hv2 = xv;
    q_ = q_ / (1.f + __expf(-q_));
    k_ = k_ / (1.f + __expf(-k_));
    v_ = v_ / (1.f + __expf(-v_));

    sq[t] = q_; sk[t] = k_;
    // sum of squares for l2norm (block = 2 waves)
    float pq = q_ * q_, pk = k_ * k_;
    #pragma unroll
    for (int off = 32; off > 0; off >>= 1) {
      pq += __shfl_xor(pq, off);
      pk += __shfl_xor(pk, off);
    }
    if ((t & 63) == 0) { redA[t >> 6] = pq; redA[2 + (t >> 6)] = pk; }
    __syncthreads();
    const float rqn = rsqrtf(redA[0] + redA[1] + 1e-6f) * qscale;
    const float rkn = rsqrtf(redA[2] + redA[3] + 1e-6f);

    // ---- scalars beta, exp(g) ----
    const float beta = 1.f / (1.f + __expf(-bcur));
    float aval = acur + dtb;
    float sp = (aval > 20.f) ? aval : log1pf(__expf(aval));
    const float eg = __expf(negexpA * sp);

    // ---- kv_mem = eg * rkn * sum_k k_raw[k] * st[k] ----
    float a0 = 0.f, a1 = 0.f, a2 = 0.f, a3 = 0.f;
    #pragma unroll
    for (int k = 0; k < DK_; k += 4) {
      a0 += sk[k + 0] * st[k + 0];
      a1 += sk[k + 1] * st[k + 1];
      a2 += sk[k + 2] * st[k + 2];
      a3 += sk[k + 3] * st[k + 3];
    }
    const float kv = ((a0 + a1) + (a2 + a3)) * rkn * eg;
    const float delta = (v_ - kv) * beta;
    const float rkd = rkn * delta;

    // ---- state update + out reduction fused ----
    float o0 = 0.f, o1 = 0.f, o2 = 0.f, o3 = 0.f;
    #pragma unroll
    for (int k = 0; k < DK_; k += 4) {
      float s0 = st[k + 0] * eg + sk[k + 0] * rkd; st[k + 0] = s0; o0 += sq[k + 0] * s0;
      float s1 = st[k + 1] * eg + sk[k + 1] * rkd; st[k + 1] = s1; o1 += sq[k + 1] * s1;
      float s2 = st[k + 2] * eg + sk[k + 2] * rkd; st[k + 2] = s2; o2 += sq[k + 2] * s2;
      float s3 = st[k + 3] * eg + sk[k + 3] * rkd; st[k + 3] = s3; o3 += sq[k + 3] * s3;
    }
    const float outv = ((o0 + o1) + (o2 + o3)) * rqn;

    // ---- RMS norm over the 128 columns (threads) + gate ----
    float p = outv * outv;
    #pragma unroll
    for (int off = 32; off > 0; off >>= 1) p += __shfl_xor(p, off);
    if ((t & 63) == 0) redB[t >> 6] = p;
    __syncthreads();
    const float var = (redB[0] + redB[1]) * (1.0f / 128.0f);
    const float xn = outv * rsqrtf(var + 1e-6f) * nw;
    const size_t zi = ((size_t)(b * S_ + s)) * VALDIM_ + hv * DV_ + t;
    const float zv = z_gated[zi];
    z_gated[zi] = xn * (zv / (1.f + __expf(-zv)));
    __syncthreads();  // protect sq/sk/redA/redB for next iteration

    xq = nq; xk = nk; xv = nv; bcur = nb; acur = na;
  }

  #pragma unroll
  for (int k = 0; k < DK_; k++)
    final_state[((size_t)(b * HV_ + hv) * DK_ + k) * DV_ + t] = st[k];
}

// ---------------------------------------------------------------------------
extern "C" void kernel_launch(void* const* d_in, const int* in_sizes, int n_in,
                              void* d_out, int out_size, void* d_ws, size_t ws_size,
                              hipStream_t stream)
{
  const float* hs          = (const float*)d_in[0];
  const float* conv_state  = (const float*)d_in[1];
  const float* rec_state   = (const float*)d_in[2];
  const float* W_qkv       = (const float*)d_in[3];
  const float* W_z         = (const float*)d_in[4];
  const float* W_b         = (const float*)d_in[5];
  const float* W_a         = (const float*)d_in[6];
  const float* conv_w      = (const float*)d_in[7];
  const float* dt_bias     = (const float*)d_in[8];
  const float* A_log       = (const float*)d_in[9];
  const float* norm_weight = (const float*)d_in[10];
  const float* W_out       = (const float*)d_in[11];

  float* out       = (float*)d_out;                      // (B,S,H)
  float* out_conv  = out + (size_t)B_ * S_ * H_;         // (B,C,3)
  float* out_state = out_conv + (size_t)B_ * CC_ * 3;    // (B,HV,DK,DV)

  float* qkv_raw = (float*)d_ws;                          // (B,S,C)   64 MB
  float* z_gated = qkv_raw + (size_t)B_ * S_ * CC_;       // (B,S,4096) 32 MB
  float* b_act   = z_gated + (size_t)B_ * S_ * VALDIM_;   // (B,S,32)
  float* a_act   = b_act + (size_t)B_ * S_ * HV_;         // (B,S,32)

  const int M = B_ * S_;  // 2048

  // 1. mixed_qkv (stored (B,S,C))
  sgemm_nt<<<dim3(CC_ / 64, M / 64), 256, 0, stream>>>(hs, W_qkv, qkv_raw, M, CC_, H_);
  // 2. z
  sgemm_nt<<<dim3(VALDIM_ / 64, M / 64), 256, 0, stream>>>(hs, W_z, z_gated, M, VALDIM_, H_);
  // 3. b   4. a
  sgemm_nt<<<dim3(1, M / 64), 256, 0, stream>>>(hs, W_b, b_act, M, HV_, H_);
  sgemm_nt<<<dim3(1, M / 64), 256, 0, stream>>>(hs, W_a, a_act, M, HV_, H_);
  // 5. conv_state_new (just the last 3 pre-conv columns, transposed)
  convstate_kernel<<<(B_ * CC_ * 3 + 255) / 256, 256, 0, stream>>>(qkv_raw, out_conv);
  // 6. fused conv/silu/l2norm/scan/RMS/gate
  scan_kernel<<<B_ * HV_, 128, 0, stream>>>(qkv_raw, conv_state, conv_w, rec_state,
                                            b_act, a_act, A_log, dt_bias,
                                            norm_weight, z_gated, out_state);
  // 7. output GEMM
  sgemm_nt<<<dim3(H_ / 64, M / 64), 256, 0, stream>>>(z_gated, W_out, out, M, H_, VALDIM_);
}

// Round 3
// 6683.000 us; speedup vs baseline: 1.0808x; 1.0808x over previous
//
#include <hip/hip_runtime.h>
#include <cstdint>
#include <cstddef>

#define B_ 2
#define S_ 1024
#define H_ 2048
#define HV_ 32
#define HK_ 16
#define DK_ 128
#define DV_ 128
#define CC_ 8192
#define KEYDIM_ 2048
#define VALDIM_ 4096
#define NC_ 16          // chunks
#define CS_ 64          // chunk size

// ---------------------------------------------------------------------------
// Generic SGEMM: Out[m][n] = sum_k A[m*Kd + k] * W[n*Kd + k]
// ---------------------------------------------------------------------------
__global__ __launch_bounds__(256) void sgemm_nt(
    const float* __restrict__ A, const float* __restrict__ W,
    float* __restrict__ Out, int M, int N, int Kd)
{
  __shared__ float As[16][65];
  __shared__ float Bs[16][65];
  int bm = blockIdx.y, bn = blockIdx.x;
  int t = threadIdx.x;
  int tr = t >> 4, tc = t & 15;
  int lr = t >> 2, lc4 = (t & 3) << 2;

  float acc[4][4];
  #pragma unroll
  for (int i = 0; i < 4; i++)
    #pragma unroll
    for (int j = 0; j < 4; j++) acc[i][j] = 0.f;

  const float* aBase = A + (size_t)(bm * 64 + lr) * Kd + lc4;
  int n_load = bn * 64 + lr;
  const float* wBase = W + (size_t)n_load * Kd + lc4;

  for (int k0 = 0; k0 < Kd; k0 += 16) {
    float4 av = *(const float4*)(aBase + k0);
    float4 wv = make_float4(0.f, 0.f, 0.f, 0.f);
    if (n_load < N) wv = *(const float4*)(wBase + k0);
    As[lc4 + 0][lr] = av.x; As[lc4 + 1][lr] = av.y;
    As[lc4 + 2][lr] = av.z; As[lc4 + 3][lr] = av.w;
    Bs[lc4 + 0][lr] = wv.x; Bs[lc4 + 1][lr] = wv.y;
    Bs[lc4 + 2][lr] = wv.z; Bs[lc4 + 3][lr] = wv.w;
    __syncthreads();
    #pragma unroll
    for (int kk = 0; kk < 16; kk++) {
      float ar[4], br[4];
      #pragma unroll
      for (int i = 0; i < 4; i++) ar[i] = As[kk][tr * 4 + i];
      #pragma unroll
      for (int j = 0; j < 4; j++) br[j] = Bs[kk][tc * 4 + j];
      #pragma unroll
      for (int i = 0; i < 4; i++)
        #pragma unroll
        for (int j = 0; j < 4; j++)
          acc[i][j] += ar[i] * br[j];
    }
    __syncthreads();
  }

  #pragma unroll
  for (int i = 0; i < 4; i++) {
    int m = bm * 64 + tr * 4 + i;
    #pragma unroll
    for (int j = 0; j < 4; j++) {
      int n = bn * 64 + tc * 4 + j;
      if (n < N) Out[(size_t)m * N + n] = acc[i][j];
    }
  }
}

// ---------------------------------------------------------------------------
// conv_state_new[b][c][j] = mixed_qkv[b][S-3+j][c]
// ---------------------------------------------------------------------------
__global__ void convstate_kernel(const float* __restrict__ qkv_raw,
                                 float* __restrict__ out)
{
  int idx = blockIdx.x * blockDim.x + threadIdx.x;
  if (idx >= B_ * CC_ * 3) return;
  int j = idx % 3;
  int c = (idx / 3) % CC_;
  int b = idx / (3 * CC_);
  out[idx] = qkv_raw[((size_t)(b * S_ + (S_ - 3 + j))) * CC_ + c];
}

// ---------------------------------------------------------------------------
// prep_qkv: conv(K=4)+silu for all channels at one (b,s); l2norm q/k heads.
// ---------------------------------------------------------------------------
__global__ __launch_bounds__(128) void prep_qkv(
    const float* __restrict__ qkv_raw, const float* __restrict__ conv_state,
    const float* __restrict__ conv_w,
    float* __restrict__ Qn, float* __restrict__ Kn, float* __restrict__ Vb)
{
  int group = blockIdx.x, s = blockIdx.y, b = blockIdx.z;
  int t = threadIdx.x;
  int c = group * 128 + t;
  float acc = 0.f;
  #pragma unroll
  for (int kk = 0; kk < 4; kk++) {
    int sp = s - 3 + kk;
    float x = (sp < 0) ? conv_state[((size_t)(b * CC_ + c)) * 3 + (3 + sp)]
                       : qkv_raw[((size_t)(b * S_ + sp)) * CC_ + c];
    acc += conv_w[c * 4 + kk] * x;
  }
  float val = acc / (1.f + __expf(-acc));   // silu

  if (group < 32) {
    __shared__ float red2[2];
    float p = val * val;
    #pragma unroll
    for (int off = 32; off > 0; off >>= 1) p += __shfl_xor(p, off);
    if ((t & 63) == 0) red2[t >> 6] = p;
    __syncthreads();
    float r = rsqrtf(red2[0] + red2[1] + 1e-6f);
    if (group < 16) {
      r *= 0.08838834764831845f;  // 128^-0.5
      Qn[(((size_t)(b * HK_ + group)) * S_ + s) * DK_ + t] = val * r;
    } else {
      Kn[(((size_t)(b * HK_ + (group - 16))) * S_ + s) * DK_ + t] = val * r;
    }
  } else {
    Vb[(((size_t)(b * HV_ + (group - 32))) * S_ + s) * DV_ + t] = val;
  }
}

// ---------------------------------------------------------------------------
// prep_gb: g = -exp(A_log)*softplus(a+dt_bias), beta = sigmoid(b). (B,HV,S)
// ---------------------------------------------------------------------------
__global__ void prep_gb(const float* __restrict__ a_act, const float* __restrict__ b_act,
                        const float* __restrict__ A_log, const float* __restrict__ dt_bias,
                        float* __restrict__ g_buf, float* __restrict__ beta_buf)
{
  int idx = blockIdx.x * blockDim.x + threadIdx.x;
  if (idx >= B_ * HV_ * S_) return;
  int s = idx & (S_ - 1);
  int hv = (idx >> 10) & 31;
  int b = idx >> 15;
  float av = a_act[((size_t)(b * S_ + s)) * HV_ + hv];
  float bv = b_act[((size_t)(b * S_ + s)) * HV_ + hv];
  float x = av + dt_bias[hv];
  float sp = (x > 20.f) ? x : log1pf(__expf(x));
  g_buf[idx] = -__expf(A_log[hv]) * sp;
  beta_buf[idx] = 1.f / (1.f + __expf(-bv));
}

// ---------------------------------------------------------------------------
// cp_kernel: per (b,hv,chunk). G cumsum, M, A, Tinv (forward substitution),
// Kc = Tinv*diag(beta*e^G)*K, D0 = Tinv*diag(beta)*V.
// LDS = 64KB exactly: sK(64x128) + sX(32x128) + sT(64x64).
// sX lifetimes: Q-halves (M pass) -> sA -> tTw (Kc pass) -> tTb (D0 pass).
// R2 BUG FIXED: tTb no longer overlays sT; it is written into sX *after*
// the Kc pass, while T (sT) is still intact.
// ---------------------------------------------------------------------------
__device__ __forceinline__ int swf4(int r, int f) { return r * 32 + (f ^ (r & 31)); }
__device__ __forceinline__ int swf1(int r, int k) {
  return r * 128 + 4 * ((k >> 2) ^ (r & 31)) + (k & 3);
}

__global__ __launch_bounds__(256) void cp_kernel(
    const float* __restrict__ Qn, const float* __restrict__ Kn,
    const float* __restrict__ Vb,
    const float* __restrict__ g_buf, const float* __restrict__ beta_buf,
    float* __restrict__ G_buf, float* __restrict__ M_buf,
    float* __restrict__ Kc_buf, float* __restrict__ D0_buf)
{
  __shared__ float sK[64 * 128];   // K rows (swizzled); later V rows
  __shared__ float sX[32 * 128];   // Q halves -> sA -> tTw -> tTb
  __shared__ float sT[64 * 64];    // [0..127] alias sG,sBe early; then T
  float* sG  = sT;
  float* sBe = sT + 64;
  float* sA  = sX;
  float* tTw = sX;
  float* tTb = sX;
  float4* sK4 = (float4*)sK;
  float4* sX4 = (float4*)sX;

  const int ch = blockIdx.x;
  const int bh = ch / NC_, c = ch % NC_;
  const int b = bh >> 5, hv = bh & 31, hk = hv >> 1;
  const int s0 = c * CS_;
  const int t = threadIdx.x;
  const size_t gOff = (size_t)bh * S_ + s0;

  // ---- G scan (wave 0) + stash G/beta ----
  float Gw0 = 0.f, Bw0 = 0.f;
  if (t < 64) {
    float gi = g_buf[gOff + t];
    Gw0 = gi;
    #pragma unroll
    for (int off = 1; off < 64; off <<= 1) {
      float o = __shfl_up(Gw0, off);
      if (t >= off) Gw0 += o;
    }
    G_buf[gOff + t] = Gw0;
    sG[t] = Gw0;
    Bw0 = beta_buf[gOff + t];
    sBe[t] = Bw0;
  }
  // ---- stage K (swizzled) ----
  {
    const float4* src = (const float4*)(Kn + ((size_t)(b * HK_ + hk) * S_ + s0) * DK_);
    #pragma unroll
    for (int u = 0; u < 8; u++) {
      int idx = u * 256 + t;
      sK4[swf4(idx >> 5, idx & 31)] = src[idx];
    }
  }
  __syncthreads();

  // ---- M = e^{Gi-Gj} (q_i . k_j), j<=i : two halves of Q rows ----
  const float4* qsrc = (const float4*)(Qn + ((size_t)(b * HK_ + hk) * S_ + s0) * DK_);
  {
    int ti2 = t >> 4, tj = t & 15;
    for (int h = 0; h < 2; h++) {
      #pragma unroll
      for (int u = 0; u < 4; u++) {
        int idx = u * 256 + t;
        sX4[swf4(idx >> 5, idx & 31)] = qsrc[h * 1024 + idx];
      }
      __syncthreads();
      float accM[2][4];
      #pragma unroll
      for (int a = 0; a < 2; a++)
        #pragma unroll
        for (int e = 0; e < 4; e++) accM[a][e] = 0.f;
      for (int k4 = 0; k4 < 32; k4++) {
        float4 qv[2], kv[4];
        qv[0] = sX4[swf4(ti2, k4)];
        qv[1] = sX4[swf4(ti2 + 16, k4)];
        #pragma unroll
        for (int e = 0; e < 4; e++) kv[e] = sK4[swf4(tj + 16 * e, k4)];
        #pragma unroll
        for (int a = 0; a < 2; a++)
          #pragma unroll
          for (int e = 0; e < 4; e++)
            accM[a][e] += qv[a].x * kv[e].x + qv[a].y * kv[e].y +
                          qv[a].z * kv[e].z + qv[a].w * kv[e].w;
      }
      #pragma unroll
      for (int a = 0; a < 2; a++) {
        int iG = h * 32 + ti2 + 16 * a;
        float Gi = sG[iG];
        #pragma unroll
        for (int e = 0; e < 4; e++) {
          int j = tj + 16 * e;
          float m = (j <= iG) ? __expf(Gi - sG[j]) * accM[a][e] : 0.f;
          M_buf[(size_t)ch * 4096 + iG * 64 + j] = m;
        }
      }
      __syncthreads();
    }
  }

  // ---- A = beta_i e^{Gi-Gj} (k_i . k_j), j<i  -> sA (in sX) ----
  {
    int ti = t >> 4, tj = t & 15;
    float accA[4][4];
    #pragma unroll
    for (int a = 0; a < 4; a++)
      #pragma unroll
      for (int e = 0; e < 4; e++) accA[a][e] = 0.f;
    for (int k4 = 0; k4 < 32; k4++) {
      float4 ki[4], kj[4];
      #pragma unroll
      for (int e = 0; e < 4; e++) {
        ki[e] = sK4[swf4(ti + 16 * e, k4)];
        kj[e] = sK4[swf4(tj + 16 * e, k4)];
      }
      #pragma unroll
      for (int a = 0; a < 4; a++)
        #pragma unroll
        for (int e = 0; e < 4; e++)
          accA[a][e] += ki[a].x * kj[e].x + ki[a].y * kj[e].y +
                        ki[a].z * kj[e].z + ki[a].w * kj[e].w;
    }
    float resA[4][4];
    #pragma unroll
    for (int a = 0; a < 4; a++) {
      int i = ti + 16 * a;
      float Gi = sG[i], Bi = sBe[i];
      #pragma unroll
      for (int e = 0; e < 4; e++) {
        int j = tj + 16 * e;
        resA[a][e] = (j < i) ? Bi * __expf(Gi - sG[j]) * accA[a][e] : 0.f;
      }
    }
    __syncthreads();  // everyone done reading sX (M pass) and sG/sBe
    #pragma unroll
    for (int a = 0; a < 4; a++)
      #pragma unroll
      for (int e = 0; e < 4; e++)
        sA[(ti + 16 * a) * 64 + (tj + 16 * e)] = resA[a][e];
  }
  __syncthreads();

  // ---- Tinv by forward substitution (wave 0); T kept in sT; tTw into sX
  if (t < 64) {
    sT[t] = (t == 0) ? 1.f : 0.f;   // row 0 (overwrites sG/sBe: both dead)
    for (int i = 1; i < 64; i++) {
      float acc = 0.f;
      for (int j = 0; j < i; j++) acc += sA[i * 64 + j] * sT[j * 64 + t];
      sT[i * 64 + t] = ((t == i) ? 1.f : 0.f) - acc;
    }
    float w = Bw0 * __expf(Gw0);
    for (int j = 0; j < 64; j++) {
      float wj = __shfl(w, j);
      tTw[j * 64 + t] = sT[t * 64 + j] * wj;  // tTw[j][i] = Tinv[i][j]*w_j
    }
  }
  __syncthreads();

  // ---- Kc[i][k] = sum_j tTw[j][i] * K[j][k] ----
  {
    int i04 = t >> 4, tk = t & 15;
    float accK[4][8];
    #pragma unroll
    for (int r = 0; r < 4; r++)
      #pragma unroll
      for (int u = 0; u < 8; u++) accK[r][u] = 0.f;
    for (int j = 0; j < 64; j++) {
      float4 tw = ((float4*)tTw)[j * 16 + i04];
      #pragma unroll
      for (int u = 0; u < 8; u++) {
        float kv = sK[swf1(j, tk + 16 * u)];
        accK[0][u] += tw.x * kv; accK[1][u] += tw.y * kv;
        accK[2][u] += tw.z * kv; accK[3][u] += tw.w * kv;
      }
    }
    size_t base = (size_t)ch * 8192;
    #pragma unroll
    for (int r = 0; r < 4; r++)
      #pragma unroll
      for (int u = 0; u < 8; u++)
        Kc_buf[base + (i04 * 4 + r) * 128 + tk + 16 * u] = accK[r][u];
  }
  __syncthreads();  // done reading tTw (sX) and sK (K data)

  // ---- wave 0: tTb over sX (T in sT intact); all: restage V over sK ----
  if (t < 64) {
    for (int j = 0; j < 64; j++) {
      float bj = __shfl(Bw0, j);
      tTb[j * 64 + t] = sT[t * 64 + j] * bj;  // tTb[j][i] = Tinv[i][j]*beta_j
    }
  }
  {
    const float4* src = (const float4*)(Vb + ((size_t)bh * S_ + s0) * DV_);
    #pragma unroll
    for (int u = 0; u < 8; u++) {
      int idx = u * 256 + t;
      sK4[swf4(idx >> 5, idx & 31)] = src[idx];
    }
  }
  __syncthreads();

  // ---- D0[i][v] = sum_j tTb[j][i] * V[j][v] ----
  {
    int i04 = t >> 4, tv_ = t & 15;
    float accD[4][8];
    #pragma unroll
    for (int r = 0; r < 4; r++)
      #pragma unroll
      for (int u = 0; u < 8; u++) accD[r][u] = 0.f;
    for (int j = 0; j < 64; j++) {
      float4 tb = ((float4*)tTb)[j * 16 + i04];
      #pragma unroll
      for (int u = 0; u < 8; u++) {
        float vv = sK[swf1(j, tv_ + 16 * u)];
        accD[0][u] += tb.x * vv; accD[1][u] += tb.y * vv;
        accD[2][u] += tb.z * vv; accD[3][u] += tb.w * vv;
      }
    }
    size_t base = (size_t)ch * 8192;
    #pragma unroll
    for (int r = 0; r < 4; r++)
      #pragma unroll
      for (int u = 0; u < 8; u++)
        D0_buf[base + (i04 * 4 + r) * 128 + tv_ + 16 * u] = accD[r][u];
  }
}

// ---------------------------------------------------------------------------
// phaseb: sequential over 16 chunks. ONE block per (b,hv) head (grid 64),
// 128 threads = 2 waves; thread v owns output column v; state column (128 k)
// in VGPRs. D = D0 - Kc*S0 ; Oq = diag(e^G) Q * S0 ; S <- e^{GC} S0 + Kd^T D.
// Sole ownership of the head's Kc region makes the D-over-Kc write safe
// (R2 had a cross-block race here).
// ---------------------------------------------------------------------------
__global__ __launch_bounds__(128) void phaseb_kernel(
    const float* __restrict__ rec_state, const float* __restrict__ Qn,
    const float* __restrict__ Kn, const float* __restrict__ G_buf,
    float* __restrict__ KcD, float* __restrict__ D0Oq,
    float* __restrict__ final_state)
{
  __shared__ float sKc[64 * 128];  // Kc, then Kd
  __shared__ float sQb[64 * 128];  // e^{Gi}-scaled Q rows
  __shared__ float sD[64 * 128];   // D (own column stash; 2 waves != lockstep)

  int bh = blockIdx.x;             // 0..63
  int b = bh >> 5, hv = bh & 31, hk = hv >> 1;
  int v = threadIdx.x;             // 0..127: output column

  float S0r[128];
  #pragma unroll
  for (int k = 0; k < 128; k++)
    S0r[k] = rec_state[((size_t)bh * 128 + k) * 128 + v];

  for (int c = 0; c < NC_; c++) {
    size_t ch = (size_t)bh * NC_ + c;
    int s0 = c * CS_;
    float GC = G_buf[(size_t)bh * S_ + s0 + 63];
    float eGC = __expf(GC);
    int row = v >> 1, half = v & 1;
    float Grow = G_buf[(size_t)bh * S_ + s0 + row];

    // stage Kc (flat)
    {
      const float4* src = (const float4*)(KcD + ch * 8192);
      float4* dst = (float4*)sKc;
      #pragma unroll 4
      for (int u = 0; u < 16; u++) dst[u * 128 + v] = src[u * 128 + v];
    }
    // stage Qb = e^{Gi} * Q row (2 threads per row)
    {
      float sc = __expf(Grow);
      const float4* qs = (const float4*)(Qn + ((size_t)(b * HK_ + hk) * S_ + s0 + row) * DK_) + half * 16;
      float4* qd = (float4*)(sQb + row * 128) + half * 16;
      #pragma unroll 4
      for (int u = 0; u < 16; u++) {
        float4 x = qs[u];
        x.x *= sc; x.y *= sc; x.z *= sc; x.w *= sc;
        qd[u] = x;
      }
    }
    __syncthreads();

    // D-loop (also Oq)
    for (int i = 0; i < 64; i++) {
      float d = D0Oq[ch * 8192 + i * 128 + v];
      float oq = 0.f;
      const float4* kr = (const float4*)(sKc + i * 128);
      const float4* qr = (const float4*)(sQb + i * 128);
      #pragma unroll
      for (int k4 = 0; k4 < 32; k4++) {
        float4 a = kr[k4], q = qr[k4];
        d  -= a.x * S0r[4 * k4] + a.y * S0r[4 * k4 + 1] +
              a.z * S0r[4 * k4 + 2] + a.w * S0r[4 * k4 + 3];
        oq += q.x * S0r[4 * k4] + q.y * S0r[4 * k4 + 1] +
              q.z * S0r[4 * k4 + 2] + q.w * S0r[4 * k4 + 3];
      }
      KcD[ch * 8192 + i * 128 + v] = d;   // safe: sole owner of this head
      D0Oq[ch * 8192 + i * 128 + v] = oq;
      sD[i * 128 + v] = d;
    }
    __syncthreads();  // both waves done reading sKc (Kc)

    // stage Kd = e^{GC-Gi} * K row over sKc
    {
      float sc = __expf(GC - Grow);
      const float4* ks = (const float4*)(Kn + ((size_t)(b * HK_ + hk) * S_ + s0 + row) * DK_) + half * 16;
      float4* kd = (float4*)(sKc + row * 128) + half * 16;
      #pragma unroll 4
      for (int u = 0; u < 16; u++) {
        float4 x = ks[u];
        x.x *= sc; x.y *= sc; x.z *= sc; x.w *= sc;
        kd[u] = x;
      }
    }
    __syncthreads();

    // state update
    #pragma unroll
    for (int k = 0; k < 128; k++) S0r[k] *= eGC;
    for (int i = 0; i < 64; i++) {
      float d = sD[i * 128 + v];
      const float4* kr = (const float4*)(sKc + i * 128);
      #pragma unroll
      for (int k4 = 0; k4 < 32; k4++) {
        float4 a = kr[k4];
        S0r[4 * k4]     += a.x * d;
        S0r[4 * k4 + 1] += a.y * d;
        S0r[4 * k4 + 2] += a.z * d;
        S0r[4 * k4 + 3] += a.w * d;
      }
    }
    __syncthreads();  // before next chunk's staging overwrites sKc/sQb
  }
  #pragma unroll
  for (int k = 0; k < 128; k++)
    final_state[((size_t)bh * 128 + k) * 128 + v] = S0r[k];
}

// ---------------------------------------------------------------------------
// phasec: O = Oq + M*D, then RMS-norm + norm_weight + silu(z) gate -> z_gated
// ---------------------------------------------------------------------------
__global__ __launch_bounds__(128) void phasec_kernel(
    const float* __restrict__ KcD, const float* __restrict__ D0Oq,
    const float* __restrict__ M_buf, const float* __restrict__ norm_weight,
    float* __restrict__ z_gated)
{
  __shared__ float sM[4096];
  __shared__ float red[2][2];
  int ch = blockIdx.x;
  int bh = ch / NC_, c = ch % NC_;
  int b = bh >> 5, hv = bh & 31;
  int s0 = c * CS_;
  int v = threadIdx.x;

  float Dr[64];
  #pragma unroll
  for (int j = 0; j < 64; j++) Dr[j] = KcD[(size_t)ch * 8192 + j * 128 + v];
  {
    const float4* src = (const float4*)(M_buf + (size_t)ch * 4096);
    #pragma unroll
    for (int u = 0; u < 8; u++) ((float4*)sM)[u * 128 + v] = src[u * 128 + v];
  }
  __syncthreads();
  float nw = norm_weight[v];

  for (int i = 0; i < 64; i++) {
    float o = D0Oq[(size_t)ch * 8192 + i * 128 + v];
    const float4* mr = (const float4*)(sM + i * 64);
    #pragma unroll
    for (int j4 = 0; j4 < 16; j4++) {
      float4 m = mr[j4];
      o += m.x * Dr[4 * j4] + m.y * Dr[4 * j4 + 1] +
           m.z * Dr[4 * j4 + 2] + m.w * Dr[4 * j4 + 3];
    }
    float p = o * o;
    #pragma unroll
    for (int off = 32; off > 0; off >>= 1) p += __shfl_xor(p, off);
    if ((v & 63) == 0) red[i & 1][v >> 6] = p;
    __syncthreads();
    float var = (red[i & 1][0] + red[i & 1][1]) * (1.f / 128.f);
    float xn = o * rsqrtf(var + 1e-6f) * nw;
    size_t zi = ((size_t)(b * S_ + s0 + i)) * VALDIM_ + hv * DV_ + v;
    float zv = z_gated[zi];
    z_gated[zi] = xn * (zv / (1.f + __expf(-zv)));
  }
}

// ---------------------------------------------------------------------------
extern "C" void kernel_launch(void* const* d_in, const int* in_sizes, int n_in,
                              void* d_out, int out_size, void* d_ws, size_t ws_size,
                              hipStream_t stream)
{
  const float* hs          = (const float*)d_in[0];
  const float* conv_state  = (const float*)d_in[1];
  const float* rec_state   = (const float*)d_in[2];
  const float* W_qkv       = (const float*)d_in[3];
  const float* W_z         = (const float*)d_in[4];
  const float* W_b         = (const float*)d_in[5];
  const float* W_a         = (const float*)d_in[6];
  const float* conv_w      = (const float*)d_in[7];
  const float* dt_bias     = (const float*)d_in[8];
  const float* A_log       = (const float*)d_in[9];
  const float* norm_weight = (const float*)d_in[10];
  const float* W_out       = (const float*)d_in[11];

  float* out       = (float*)d_out;                      // (B,S,H)
  float* out_conv  = out + (size_t)B_ * S_ * H_;         // (B,C,3)
  float* out_state = out_conv + (size_t)B_ * CC_ * 3;    // (B,HV,DK,DV)

  float* ws = (float*)d_ws;
  float* qkv_raw  = ws;                                  // 16,777,216
  float* Kc_buf   = ws;                                  // alias (qkv dead): 8,388,608
  float* M_buf    = ws + 8388608;                        // 4,194,304
  float* z_gated  = ws + 16777216;                       // 8,388,608
  float* b_act    = ws + 25165824;                       // 65,536
  float* a_act    = ws + 25231360;                       // 65,536
  float* Qn       = ws + 25296896;                       // 4,194,304
  float* Kn       = ws + 29491200;                       // 4,194,304
  float* Vb       = ws + 33685504;                       // 8,388,608
  float* g_buf    = ws + 42074112;                       // 65,536
  float* beta_buf = ws + 42139648;                       // 65,536
  float* G_buf    = ws + 42205184;                       // 65,536
  float* D0_buf   = ws + 42270720;                       // 8,388,608 (end 50,659,328)

  const int M = B_ * S_;  // 2048

  // 1. big GEMMs
  sgemm_nt<<<dim3(CC_ / 64, M / 64), 256, 0, stream>>>(hs, W_qkv, qkv_raw, M, CC_, H_);
  sgemm_nt<<<dim3(VALDIM_ / 64, M / 64), 256, 0, stream>>>(hs, W_z, z_gated, M, VALDIM_, H_);
  sgemm_nt<<<dim3(1, M / 64), 256, 0, stream>>>(hs, W_b, b_act, M, HV_, H_);
  sgemm_nt<<<dim3(1, M / 64), 256, 0, stream>>>(hs, W_a, a_act, M, HV_, H_);
  // 2. conv_state_new output
  convstate_kernel<<<(B_ * CC_ * 3 + 255) / 256, 256, 0, stream>>>(qkv_raw, out_conv);
  // 3. conv+silu+l2norm -> Qn,Kn,V ; gates
  prep_qkv<<<dim3(64, S_, B_), 128, 0, stream>>>(qkv_raw, conv_state, conv_w, Qn, Kn, Vb);
  prep_gb<<<(B_ * HV_ * S_ + 255) / 256, 256, 0, stream>>>(a_act, b_act, A_log, dt_bias, g_buf, beta_buf);
  // 4. per-chunk matrices (qkv_raw dead; Kc/M alias it)
  cp_kernel<<<B_ * HV_ * NC_, 256, 0, stream>>>(Qn, Kn, Vb, g_buf, beta_buf,
                                                G_buf, M_buf, Kc_buf, D0_buf);
  // 5. sequential chunk recurrence (one block per head)
  phaseb_kernel<<<B_ * HV_, 128, 0, stream>>>(rec_state, Qn, Kn, G_buf,
                                              Kc_buf, D0_buf, out_state);
  // 6. intra-chunk output + RMS + gate (into z_gated)
  phasec_kernel<<<B_ * HV_ * NC_, 128, 0, stream>>>(Kc_buf, D0_buf, M_buf,
                                                    norm_weight, z_gated);
  // 7. output GEMM
  sgemm_nt<<<dim3(H_ / 64, M / 64), 256, 0, stream>>>(z_gated, W_out, out, M, H_, VALDIM_);
}

// Round 4
// 1308.404 us; speedup vs baseline: 5.5204x; 5.1078x over previous
//
#include <hip/hip_runtime.h>
#include <cstdint>
#include <cstddef>

#define B_ 2
#define S_ 1024
#define H_ 2048
#define HV_ 32
#define HK_ 16
#define DK_ 128
#define DV_ 128
#define CC_ 8192
#define KEYDIM_ 2048
#define VALDIM_ 4096
#define NC_ 16          // chunks
#define CS_ 64          // chunk size

typedef __attribute__((ext_vector_type(8))) short bf16x8;
typedef __attribute__((ext_vector_type(4))) float f32x4;

__device__ __forceinline__ ushort f2bf_rne(float x) {
  union { float f; uint32_t u; } c; c.f = x;
  uint32_t u = c.u + 0x7FFFu + ((c.u >> 16) & 1u);
  return (ushort)(u >> 16);
}

// ---------------------------------------------------------------------------
// fp32 -> bf16 convert (n multiple of 1024)
// ---------------------------------------------------------------------------
__global__ void f2bf_kernel(const float* __restrict__ in, ushort* __restrict__ out, int n) {
  int i = (blockIdx.x * 256 + threadIdx.x) * 4;
  if (i >= n) return;
  float4 v = *(const float4*)(in + i);
  ushort4 o;
  o.x = f2bf_rne(v.x); o.y = f2bf_rne(v.y);
  o.z = f2bf_rne(v.z); o.w = f2bf_rne(v.w);
  *(ushort4*)(out + i) = o;
}

// ---------------------------------------------------------------------------
// bf16 MFMA GEMM (NT): C[m][n] = sum_k A[m][k]*B[n][k]. M,N,K % 128 == 0.
// 128x128 tile, BK=32, 256 threads = 2x2 waves, each wave 4x4 16x16 tiles.
// ---------------------------------------------------------------------------
__global__ __launch_bounds__(256) void gemm_bf16_nt(
    const ushort* __restrict__ A, const ushort* __restrict__ B,
    float* __restrict__ C, int M, int N, int K)
{
  __shared__ ushort sA[128][40];   // 32 + 8 pad
  __shared__ ushort sB[128][40];
  int t = threadIdx.x;
  int wave = t >> 6, lane = t & 63;
  int wm = wave >> 1, wn = wave & 1;
  int lrow = lane & 15, quad = lane >> 4;

  f32x4 acc[4][4];
  #pragma unroll
  for (int i = 0; i < 4; i++)
    #pragma unroll
    for (int j = 0; j < 4; j++)
      #pragma unroll
      for (int r = 0; r < 4; r++) acc[i][j][r] = 0.f;

  int r = t >> 1, h = t & 1;       // staging: row r, 16-elem half h
  const ushort* aSrc = A + (size_t)(blockIdx.y * 128 + r) * K + h * 16;
  const ushort* bSrc = B + (size_t)(blockIdx.x * 128 + r) * K + h * 16;

  for (int k0 = 0; k0 < K; k0 += 32) {
    uint4 a0 = *(const uint4*)(aSrc + k0);
    uint4 a1 = *(const uint4*)(aSrc + k0 + 8);
    uint4 b0 = *(const uint4*)(bSrc + k0);
    uint4 b1 = *(const uint4*)(bSrc + k0 + 8);
    *(uint4*)(&sA[r][h * 16])     = a0;
    *(uint4*)(&sA[r][h * 16 + 8]) = a1;
    *(uint4*)(&sB[r][h * 16])     = b0;
    *(uint4*)(&sB[r][h * 16 + 8]) = b1;
    __syncthreads();
    bf16x8 af[4], bfr[4];
    #pragma unroll
    for (int i = 0; i < 4; i++)
      af[i] = *(const bf16x8*)(&sA[wm * 64 + i * 16 + lrow][quad * 8]);
    #pragma unroll
    for (int j = 0; j < 4; j++)
      bfr[j] = *(const bf16x8*)(&sB[wn * 64 + j * 16 + lrow][quad * 8]);
    #pragma unroll
    for (int i = 0; i < 4; i++)
      #pragma unroll
      for (int j = 0; j < 4; j++)
        acc[i][j] = __builtin_amdgcn_mfma_f32_16x16x32_bf16(af[i], bfr[j], acc[i][j], 0, 0, 0);
    __syncthreads();
  }

  #pragma unroll
  for (int i = 0; i < 4; i++) {
    int m_base = blockIdx.y * 128 + wm * 64 + i * 16 + quad * 4;
    #pragma unroll
    for (int j = 0; j < 4; j++) {
      int n = blockIdx.x * 128 + wn * 64 + j * 16 + lrow;
      #pragma unroll
      for (int rr = 0; rr < 4; rr++)
        C[(size_t)(m_base + rr) * N + n] = acc[i][j][rr];
    }
  }
}

// ---------------------------------------------------------------------------
// Generic fp32 SGEMM (kept for the tiny b/a projections, N=32)
// ---------------------------------------------------------------------------
__global__ __launch_bounds__(256) void sgemm_nt(
    const float* __restrict__ A, const float* __restrict__ W,
    float* __restrict__ Out, int M, int N, int Kd)
{
  __shared__ float As[16][65];
  __shared__ float Bs[16][65];
  int bm = blockIdx.y, bn = blockIdx.x;
  int t = threadIdx.x;
  int tr = t >> 4, tc = t & 15;
  int lr = t >> 2, lc4 = (t & 3) << 2;

  float acc[4][4];
  #pragma unroll
  for (int i = 0; i < 4; i++)
    #pragma unroll
    for (int j = 0; j < 4; j++) acc[i][j] = 0.f;

  const float* aBase = A + (size_t)(bm * 64 + lr) * Kd + lc4;
  int n_load = bn * 64 + lr;
  const float* wBase = W + (size_t)n_load * Kd + lc4;

  for (int k0 = 0; k0 < Kd; k0 += 16) {
    float4 av = *(const float4*)(aBase + k0);
    float4 wv = make_float4(0.f, 0.f, 0.f, 0.f);
    if (n_load < N) wv = *(const float4*)(wBase + k0);
    As[lc4 + 0][lr] = av.x; As[lc4 + 1][lr] = av.y;
    As[lc4 + 2][lr] = av.z; As[lc4 + 3][lr] = av.w;
    Bs[lc4 + 0][lr] = wv.x; Bs[lc4 + 1][lr] = wv.y;
    Bs[lc4 + 2][lr] = wv.z; Bs[lc4 + 3][lr] = wv.w;
    __syncthreads();
    #pragma unroll
    for (int kk = 0; kk < 16; kk++) {
      float ar[4], br[4];
      #pragma unroll
      for (int i = 0; i < 4; i++) ar[i] = As[kk][tr * 4 + i];
      #pragma unroll
      for (int j = 0; j < 4; j++) br[j] = Bs[kk][tc * 4 + j];
      #pragma unroll
      for (int i = 0; i < 4; i++)
        #pragma unroll
        for (int j = 0; j < 4; j++)
          acc[i][j] += ar[i] * br[j];
    }
    __syncthreads();
  }

  #pragma unroll
  for (int i = 0; i < 4; i++) {
    int m = bm * 64 + tr * 4 + i;
    #pragma unroll
    for (int j = 0; j < 4; j++) {
      int n = bn * 64 + tc * 4 + j;
      if (n < N) Out[(size_t)m * N + n] = acc[i][j];
    }
  }
}

// ---------------------------------------------------------------------------
// conv_state_new[b][c][j] = mixed_qkv[b][S-3+j][c]
// ---------------------------------------------------------------------------
__global__ void convstate_kernel(const float* __restrict__ qkv_raw,
                                 float* __restrict__ out)
{
  int idx = blockIdx.x * blockDim.x + threadIdx.x;
  if (idx >= B_ * CC_ * 3) return;
  int j = idx % 3;
  int c = (idx / 3) % CC_;
  int b = idx / (3 * CC_);
  out[idx] = qkv_raw[((size_t)(b * S_ + (S_ - 3 + j))) * CC_ + c];
}

// ---------------------------------------------------------------------------
// prep_qkv: conv(K=4)+silu; l2norm q/k heads.
// ---------------------------------------------------------------------------
__global__ __launch_bounds__(128) void prep_qkv(
    const float* __restrict__ qkv_raw, const float* __restrict__ conv_state,
    const float* __restrict__ conv_w,
    float* __restrict__ Qn, float* __restrict__ Kn, float* __restrict__ Vb)
{
  int group = blockIdx.x, s = blockIdx.y, b = blockIdx.z;
  int t = threadIdx.x;
  int c = group * 128 + t;
  float acc = 0.f;
  #pragma unroll
  for (int kk = 0; kk < 4; kk++) {
    int sp = s - 3 + kk;
    float x = (sp < 0) ? conv_state[((size_t)(b * CC_ + c)) * 3 + (3 + sp)]
                       : qkv_raw[((size_t)(b * S_ + sp)) * CC_ + c];
    acc += conv_w[c * 4 + kk] * x;
  }
  float val = acc / (1.f + __expf(-acc));   // silu

  if (group < 32) {
    __shared__ float red2[2];
    float p = val * val;
    #pragma unroll
    for (int off = 32; off > 0; off >>= 1) p += __shfl_xor(p, off);
    if ((t & 63) == 0) red2[t >> 6] = p;
    __syncthreads();
    float r = rsqrtf(red2[0] + red2[1] + 1e-6f);
    if (group < 16) {
      r *= 0.08838834764831845f;  // 128^-0.5
      Qn[(((size_t)(b * HK_ + group)) * S_ + s) * DK_ + t] = val * r;
    } else {
      Kn[(((size_t)(b * HK_ + (group - 16))) * S_ + s) * DK_ + t] = val * r;
    }
  } else {
    Vb[(((size_t)(b * HV_ + (group - 32))) * S_ + s) * DV_ + t] = val;
  }
}

// ---------------------------------------------------------------------------
// prep_gb: g = -exp(A_log)*softplus(a+dt_bias), beta = sigmoid(b). (B,HV,S)
// ---------------------------------------------------------------------------
__global__ void prep_gb(const float* __restrict__ a_act, const float* __restrict__ b_act,
                        const float* __restrict__ A_log, const float* __restrict__ dt_bias,
                        float* __restrict__ g_buf, float* __restrict__ beta_buf)
{
  int idx = blockIdx.x * blockDim.x + threadIdx.x;
  if (idx >= B_ * HV_ * S_) return;
  int s = idx & (S_ - 1);
  int hv = (idx >> 10) & 31;
  int b = idx >> 15;
  float av = a_act[((size_t)(b * S_ + s)) * HV_ + hv];
  float bv = b_act[((size_t)(b * S_ + s)) * HV_ + hv];
  float x = av + dt_bias[hv];
  float sp = (x > 20.f) ? x : log1pf(__expf(x));
  g_buf[idx] = -__expf(A_log[hv]) * sp;
  beta_buf[idx] = 1.f / (1.f + __expf(-bv));
}

// ---------------------------------------------------------------------------
// cp_kernel: per (b,hv,chunk). G cumsum, M, A, Tinv (forward substitution),
// Kc = Tinv*diag(beta*e^G)*K, D0 = Tinv*diag(beta)*V.  (unchanged from R3)
// ---------------------------------------------------------------------------
__device__ __forceinline__ int swf4(int r, int f) { return r * 32 + (f ^ (r & 31)); }
__device__ __forceinline__ int swf1(int r, int k) {
  return r * 128 + 4 * ((k >> 2) ^ (r & 31)) + (k & 3);
}

__global__ __launch_bounds__(256) void cp_kernel(
    const float* __restrict__ Qn, const float* __restrict__ Kn,
    const float* __restrict__ Vb,
    const float* __restrict__ g_buf, const float* __restrict__ beta_buf,
    float* __restrict__ G_buf, float* __restrict__ M_buf,
    float* __restrict__ Kc_buf, float* __restrict__ D0_buf)
{
  __shared__ float sK[64 * 128];
  __shared__ float sX[32 * 128];
  __shared__ float sT[64 * 64];
  float* sG  = sT;
  float* sBe = sT + 64;
  float* sA  = sX;
  float* tTw = sX;
  float* tTb = sX;
  float4* sK4 = (float4*)sK;
  float4* sX4 = (float4*)sX;

  const int ch = blockIdx.x;
  const int bh = ch / NC_, c = ch % NC_;
  const int b = bh >> 5, hv = bh & 31, hk = hv >> 1;
  const int s0 = c * CS_;
  const int t = threadIdx.x;
  const size_t gOff = (size_t)bh * S_ + s0;

  float Gw0 = 0.f, Bw0 = 0.f;
  if (t < 64) {
    float gi = g_buf[gOff + t];
    Gw0 = gi;
    #pragma unroll
    for (int off = 1; off < 64; off <<= 1) {
      float o = __shfl_up(Gw0, off);
      if (t >= off) Gw0 += o;
    }
    G_buf[gOff + t] = Gw0;
    sG[t] = Gw0;
    Bw0 = beta_buf[gOff + t];
    sBe[t] = Bw0;
  }
  {
    const float4* src = (const float4*)(Kn + ((size_t)(b * HK_ + hk) * S_ + s0) * DK_);
    #pragma unroll
    for (int u = 0; u < 8; u++) {
      int idx = u * 256 + t;
      sK4[swf4(idx >> 5, idx & 31)] = src[idx];
    }
  }
  __syncthreads();

  const float4* qsrc = (const float4*)(Qn + ((size_t)(b * HK_ + hk) * S_ + s0) * DK_);
  {
    int ti2 = t >> 4, tj = t & 15;
    for (int h = 0; h < 2; h++) {
      #pragma unroll
      for (int u = 0; u < 4; u++) {
        int idx = u * 256 + t;
        sX4[swf4(idx >> 5, idx & 31)] = qsrc[h * 1024 + idx];
      }
      __syncthreads();
      float accM[2][4];
      #pragma unroll
      for (int a = 0; a < 2; a++)
        #pragma unroll
        for (int e = 0; e < 4; e++) accM[a][e] = 0.f;
      for (int k4 = 0; k4 < 32; k4++) {
        float4 qv[2], kv[4];
        qv[0] = sX4[swf4(ti2, k4)];
        qv[1] = sX4[swf4(ti2 + 16, k4)];
        #pragma unroll
        for (int e = 0; e < 4; e++) kv[e] = sK4[swf4(tj + 16 * e, k4)];
        #pragma unroll
        for (int a = 0; a < 2; a++)
          #pragma unroll
          for (int e = 0; e < 4; e++)
            accM[a][e] += qv[a].x * kv[e].x + qv[a].y * kv[e].y +
                          qv[a].z * kv[e].z + qv[a].w * kv[e].w;
      }
      #pragma unroll
      for (int a = 0; a < 2; a++) {
        int iG = h * 32 + ti2 + 16 * a;
        float Gi = sG[iG];
        #pragma unroll
        for (int e = 0; e < 4; e++) {
          int j = tj + 16 * e;
          float m = (j <= iG) ? __expf(Gi - sG[j]) * accM[a][e] : 0.f;
          M_buf[(size_t)ch * 4096 + iG * 64 + j] = m;
        }
      }
      __syncthreads();
    }
  }

  {
    int ti = t >> 4, tj = t & 15;
    float accA[4][4];
    #pragma unroll
    for (int a = 0; a < 4; a++)
      #pragma unroll
      for (int e = 0; e < 4; e++) accA[a][e] = 0.f;
    for (int k4 = 0; k4 < 32; k4++) {
      float4 ki[4], kj[4];
      #pragma unroll
      for (int e = 0; e < 4; e++) {
        ki[e] = sK4[swf4(ti + 16 * e, k4)];
        kj[e] = sK4[swf4(tj + 16 * e, k4)];
      }
      #pragma unroll
      for (int a = 0; a < 4; a++)
        #pragma unroll
        for (int e = 0; e < 4; e++)
          accA[a][e] += ki[a].x * kj[e].x + ki[a].y * kj[e].y +
                        ki[a].z * kj[e].z + ki[a].w * kj[e].w;
    }
    float resA[4][4];
    #pragma unroll
    for (int a = 0; a < 4; a++) {
      int i = ti + 16 * a;
      float Gi = sG[i], Bi = sBe[i];
      #pragma unroll
      for (int e = 0; e < 4; e++) {
        int j = tj + 16 * e;
        resA[a][e] = (j < i) ? Bi * __expf(Gi - sG[j]) * accA[a][e] : 0.f;
      }
    }
    __syncthreads();
    #pragma unroll
    for (int a = 0; a < 4; a++)
      #pragma unroll
      for (int e = 0; e < 4; e++)
        sA[(ti + 16 * a) * 64 + (tj + 16 * e)] = resA[a][e];
  }
  __syncthreads();

  if (t < 64) {
    sT[t] = (t == 0) ? 1.f : 0.f;
    for (int i = 1; i < 64; i++) {
      float acc = 0.f;
      for (int j = 0; j < i; j++) acc += sA[i * 64 + j] * sT[j * 64 + t];
      sT[i * 64 + t] = ((t == i) ? 1.f : 0.f) - acc;
    }
    float w = Bw0 * __expf(Gw0);
    for (int j = 0; j < 64; j++) {
      float wj = __shfl(w, j);
      tTw[j * 64 + t] = sT[t * 64 + j] * wj;
    }
  }
  __syncthreads();

  {
    int i04 = t >> 4, tk = t & 15;
    float accK[4][8];
    #pragma unroll
    for (int r = 0; r < 4; r++)
      #pragma unroll
      for (int u = 0; u < 8; u++) accK[r][u] = 0.f;
    for (int j = 0; j < 64; j++) {
      float4 tw = ((float4*)tTw)[j * 16 + i04];
      #pragma unroll
      for (int u = 0; u < 8; u++) {
        float kv = sK[swf1(j, tk + 16 * u)];
        accK[0][u] += tw.x * kv; accK[1][u] += tw.y * kv;
        accK[2][u] += tw.z * kv; accK[3][u] += tw.w * kv;
      }
    }
    size_t base = (size_t)ch * 8192;
    #pragma unroll
    for (int r = 0; r < 4; r++)
      #pragma unroll
      for (int u = 0; u < 8; u++)
        Kc_buf[base + (i04 * 4 + r) * 128 + tk + 16 * u] = accK[r][u];
  }
  __syncthreads();

  if (t < 64) {
    for (int j = 0; j < 64; j++) {
      float bj = __shfl(Bw0, j);
      tTb[j * 64 + t] = sT[t * 64 + j] * bj;
    }
  }
  {
    const float4* src = (const float4*)(Vb + ((size_t)bh * S_ + s0) * DV_);
    #pragma unroll
    for (int u = 0; u < 8; u++) {
      int idx = u * 256 + t;
      sK4[swf4(idx >> 5, idx & 31)] = src[idx];
    }
  }
  __syncthreads();

  {
    int i04 = t >> 4, tv_ = t & 15;
    float accD[4][8];
    #pragma unroll
    for (int r = 0; r < 4; r++)
      #pragma unroll
      for (int u = 0; u < 8; u++) accD[r][u] = 0.f;
    for (int j = 0; j < 64; j++) {
      float4 tb = ((float4*)tTb)[j * 16 + i04];
      #pragma unroll
      for (int u = 0; u < 8; u++) {
        float vv = sK[swf1(j, tv_ + 16 * u)];
        accD[0][u] += tb.x * vv; accD[1][u] += tb.y * vv;
        accD[2][u] += tb.z * vv; accD[3][u] += tb.w * vv;
      }
    }
    size_t base = (size_t)ch * 8192;
    #pragma unroll
    for (int r = 0; r < 4; r++)
      #pragma unroll
      for (int u = 0; u < 8; u++)
        D0_buf[base + (i04 * 4 + r) * 128 + tv_ + 16 * u] = accD[r][u];
  }
}

// ---------------------------------------------------------------------------
// phaseb v2: 128 blocks = (head bh, v-half vh), 256 threads, state in LDS.
// Per chunk: D = D0 - Kc*S0 ; Oq = diag(e^G) Q * S0 ; S <- e^{GC} S0 + Kd^T D.
// D overwrites D0 in global (read-once per element by the owner thread).
// ---------------------------------------------------------------------------
__global__ __launch_bounds__(256) void phaseb_kernel(
    const float* __restrict__ rec_state, const float* __restrict__ Qn,
    const float* __restrict__ Kn, const float* __restrict__ Kc_buf,
    const float* __restrict__ G_buf,
    float* __restrict__ D_io, float* __restrict__ Oq_buf,
    float* __restrict__ final_state)
{
  __shared__ float sS[128 * 64];    // state [k][v]   32 KB
  __shared__ float sKT[128 * 64];   // Kc^T [k][i], then Kd [i][k] (same bytes)
  __shared__ float sQT[128 * 64];   // Qb^T [k][i]
  __shared__ float sD[64 * 64];     // D [i][v]       16 KB

  const int blk = blockIdx.x;
  const int bh = blk >> 1, vh = blk & 1;
  const int b = bh >> 5, hv = bh & 31, hk = hv >> 1;
  const int t = threadIdx.x;
  const float* gG = G_buf + (size_t)bh * S_;

  // load state half: sS[k][vl] = rec_state[bh][k][vh*64+vl]
  #pragma unroll
  for (int u = 0; u < 8; u++) {
    int idx = u * 256 + t;            // float4 index, 0..2047
    int k = idx >> 4;
    int v4 = (idx & 15) * 4;
    *(float4*)(&sS[k * 64 + v4]) =
        *(const float4*)(&rec_state[((size_t)bh * 128 + k) * 128 + vh * 64 + v4]);
  }
  __syncthreads();

  const int si = t & 63, skq = t >> 6;         // staging: row si, k-quarter skq
  const int ti = t >> 4, tv = t & 15;          // D/Oq tiling: 4i x 4v
  const int tk = t >> 4;                       // update tiling: 8k x 4v

  for (int c = 0; c < NC_; c++) {
    const size_t ch = (size_t)bh * NC_ + c;
    const int s0 = c * CS_;
    const float GC = gG[s0 + 63];
    const float eGC = __expf(GC);

    // ---- stage Kc^T and Qb^T = e^{G_i} Q^T ----
    {
      float eGi = __expf(gG[s0 + si]);
      const float* kcRow = Kc_buf + ch * 8192 + si * 128 + skq * 32;
      const float* qRow  = Qn + ((size_t)(b * HK_ + hk) * S_ + s0 + si) * DK_ + skq * 32;
      #pragma unroll
      for (int u = 0; u < 8; u++) {
        float4 kc = *(const float4*)(kcRow + u * 4);
        float4 qv = *(const float4*)(qRow + u * 4);
        int kk = skq * 32 + u * 4;
        sKT[(kk + 0) * 64 + si] = kc.x; sKT[(kk + 1) * 64 + si] = kc.y;
        sKT[(kk + 2) * 64 + si] = kc.z; sKT[(kk + 3) * 64 + si] = kc.w;
        sQT[(kk + 0) * 64 + si] = qv.x * eGi; sQT[(kk + 1) * 64 + si] = qv.y * eGi;
        sQT[(kk + 2) * 64 + si] = qv.z * eGi; sQT[(kk + 3) * 64 + si] = qv.w * eGi;
      }
    }
    __syncthreads();

    // ---- D = D0 - Kc*S0 ; Oq = Qb*S0 (4x4 tiles) ----
    {
      float accD[4][4], accO[4][4];
      #pragma unroll
      for (int r = 0; r < 4; r++) {
        float4 d0 = *(const float4*)(&D_io[ch * 8192 + (size_t)(ti * 4 + r) * 128 + vh * 64 + tv * 4]);
        accD[r][0] = d0.x; accD[r][1] = d0.y; accD[r][2] = d0.z; accD[r][3] = d0.w;
        accO[r][0] = accO[r][1] = accO[r][2] = accO[r][3] = 0.f;
      }
      for (int k = 0; k < 128; k++) {
        float4 kc = *(const float4*)(&sKT[k * 64 + ti * 4]);
        float4 qb = *(const float4*)(&sQT[k * 64 + ti * 4]);
        float4 sv = *(const float4*)(&sS[k * 64 + tv * 4]);
        #pragma unroll
        for (int r = 0; r < 4; r++) {
          float kcr = (r == 0) ? kc.x : (r == 1) ? kc.y : (r == 2) ? kc.z : kc.w;
          float qbr = (r == 0) ? qb.x : (r == 1) ? qb.y : (r == 2) ? qb.z : qb.w;
          accD[r][0] -= kcr * sv.x; accD[r][1] -= kcr * sv.y;
          accD[r][2] -= kcr * sv.z; accD[r][3] -= kcr * sv.w;
          accO[r][0] += qbr * sv.x; accO[r][1] += qbr * sv.y;
          accO[r][2] += qbr * sv.z; accO[r][3] += qbr * sv.w;
        }
      }
      #pragma unroll
      for (int r = 0; r < 4; r++) {
        int i = ti * 4 + r;
        float4 dv = make_float4(accD[r][0], accD[r][1], accD[r][2], accD[r][3]);
        float4 ov = make_float4(accO[r][0], accO[r][1], accO[r][2], accO[r][3]);
        *(float4*)(&sD[i * 64 + tv * 4]) = dv;
        *(float4*)(&D_io[ch * 8192 + (size_t)i * 128 + vh * 64 + tv * 4]) = dv;
        *(float4*)(&Oq_buf[ch * 8192 + (size_t)i * 128 + vh * 64 + tv * 4]) = ov;
      }
    }
    __syncthreads();

    // ---- stage Kd[i][k] = e^{GC-G_i} K[i][k] over sKT ----
    {
      float sc = __expf(GC - gG[s0 + si]);
      const float* kRow = Kn + ((size_t)(b * HK_ + hk) * S_ + s0 + si) * DK_ + skq * 32;
      float4* dst = (float4*)(&sKT[si * 128 + skq * 32]);
      #pragma unroll
      for (int u = 0; u < 8; u++) {
        float4 x = *(const float4*)(kRow + u * 4);
        x.x *= sc; x.y *= sc; x.z *= sc; x.w *= sc;
        dst[u] = x;
      }
    }
    __syncthreads();

    // ---- S <- e^{GC} S + Kd^T D  (8k x 4v tiles) ----
    {
      float acc[8][4];
      #pragma unroll
      for (int r = 0; r < 8; r++)
        acc[r][0] = acc[r][1] = acc[r][2] = acc[r][3] = 0.f;
      for (int i = 0; i < 64; i++) {
        float4 d  = *(const float4*)(&sD[i * 64 + tv * 4]);
        float4 ka = *(const float4*)(&sKT[i * 128 + tk * 8]);
        float4 kb = *(const float4*)(&sKT[i * 128 + tk * 8 + 4]);
        float kr[8] = {ka.x, ka.y, ka.z, ka.w, kb.x, kb.y, kb.z, kb.w};
        #pragma unroll
        for (int r = 0; r < 8; r++) {
          acc[r][0] += kr[r] * d.x; acc[r][1] += kr[r] * d.y;
          acc[r][2] += kr[r] * d.z; acc[r][3] += kr[r] * d.w;
        }
      }
      #pragma unroll
      for (int r = 0; r < 8; r++) {
        int k = tk * 8 + r;
        float4 s = *(const float4*)(&sS[k * 64 + tv * 4]);
        s.x = s.x * eGC + acc[r][0]; s.y = s.y * eGC + acc[r][1];
        s.z = s.z * eGC + acc[r][2]; s.w = s.w * eGC + acc[r][3];
        *(float4*)(&sS[k * 64 + tv * 4]) = s;
      }
    }
    __syncthreads();
  }

  // final state
  #pragma unroll
  for (int u = 0; u < 8; u++) {
    int idx = u * 256 + t;
    int k = idx >> 4;
    int v4 = (idx & 15) * 4;
    *(float4*)(&final_state[((size_t)bh * 128 + k) * 128 + vh * 64 + v4]) =
        *(const float4*)(&sS[k * 64 + v4]);
  }
}

// ---------------------------------------------------------------------------
// phasec: O = Oq + M*D, RMS-norm + weight + silu(z) gate -> bf16 zg
// ---------------------------------------------------------------------------
__global__ __launch_bounds__(128) void phasec_kernel(
    const float* __restrict__ D_buf, const float* __restrict__ Oq_buf,
    const float* __restrict__ M_buf, const float* __restrict__ norm_weight,
    const float* __restrict__ z_gated, ushort* __restrict__ zg_bf)
{
  __shared__ float sM[4096];
  __shared__ float red[2][2];
  int ch = blockIdx.x;
  int bh = ch / NC_, c = ch % NC_;
  int b = bh >> 5, hv = bh & 31;
  int s0 = c * CS_;
  int v = threadIdx.x;

  float Dr[64];
  #pragma unroll
  for (int j = 0; j < 64; j++) Dr[j] = D_buf[(size_t)ch * 8192 + j * 128 + v];
  {
    const float4* src = (const float4*)(M_buf + (size_t)ch * 4096);
    #pragma unroll
    for (int u = 0; u < 8; u++) ((float4*)sM)[u * 128 + v] = src[u * 128 + v];
  }
  __syncthreads();
  float nw = norm_weight[v];

  for (int i = 0; i < 64; i++) {
    float o = Oq_buf[(size_t)ch * 8192 + i * 128 + v];
    const float4* mr = (const float4*)(sM + i * 64);
    #pragma unroll
    for (int j4 = 0; j4 < 16; j4++) {
      float4 m = mr[j4];
      o += m.x * Dr[4 * j4] + m.y * Dr[4 * j4 + 1] +
           m.z * Dr[4 * j4 + 2] + m.w * Dr[4 * j4 + 3];
    }
    float p = o * o;
    #pragma unroll
    for (int off = 32; off > 0; off >>= 1) p += __shfl_xor(p, off);
    if ((v & 63) == 0) red[i & 1][v >> 6] = p;
    __syncthreads();
    float var = (red[i & 1][0] + red[i & 1][1]) * (1.f / 128.f);
    float xn = o * rsqrtf(var + 1e-6f) * nw;
    size_t zi = ((size_t)(b * S_ + s0 + i)) * VALDIM_ + hv * DV_ + v;
    float zv = z_gated[zi];
    zg_bf[zi] = f2bf_rne(xn * (zv / (1.f + __expf(-zv))));
  }
}

// ---------------------------------------------------------------------------
extern "C" void kernel_launch(void* const* d_in, const int* in_sizes, int n_in,
                              void* d_out, int out_size, void* d_ws, size_t ws_size,
                              hipStream_t stream)
{
  const float* hs          = (const float*)d_in[0];
  const float* conv_state  = (const float*)d_in[1];
  const float* rec_state   = (const float*)d_in[2];
  const float* W_qkv       = (const float*)d_in[3];
  const float* W_z         = (const float*)d_in[4];
  const float* W_b         = (const float*)d_in[5];
  const float* W_a         = (const float*)d_in[6];
  const float* conv_w      = (const float*)d_in[7];
  const float* dt_bias     = (const float*)d_in[8];
  const float* A_log       = (const float*)d_in[9];
  const float* norm_weight = (const float*)d_in[10];
  const float* W_out       = (const float*)d_in[11];

  float* out       = (float*)d_out;                      // (B,S,H)
  float* out_conv  = out + (size_t)B_ * S_ * H_;         // (B,C,3)
  float* out_state = out_conv + (size_t)B_ * CC_ * 3;    // (B,HV,DK,DV)

  float* ws = (float*)d_ws;
  // fp32 regions (offsets in floats) — same 203 MB footprint as R3:
  float* qkv_raw  = ws;                       // 0 .. 16.7M (dead after prep)
  float* Kc_buf   = ws;                       // 0 .. 8.4M   (post-qkv alias)
  float* M_buf    = ws + 8388608;             // 8.4M .. 12.6M
  float* z_gated  = ws + 16777216;            // 16.7M .. 25.2M (fp32 z)
  float* b_act    = ws + 25165824;
  float* a_act    = ws + 25231360;
  float* Qn       = ws + 25296896;            // 4.2M
  float* Kn       = ws + 29491200;            // 4.2M
  float* Vb       = ws + 33685504;            // 8.4M (dead after cp -> Oq)
  float* g_buf    = ws + 42074112;
  float* beta_buf = ws + 42139648;
  float* G_buf    = ws + 42205184;
  float* D0_buf   = ws + 42270720;            // 8.4M  (D in-place)
  float* Oq_buf   = Vb;                       // alias

  // bf16 regions aliasing dead fp32 regions (time-ordered, see launches):
  ushort* Wqkv_bf = (ushort*)z_gated;         // used before z GEMM writes z
  ushort* Wz_bf   = (ushort*)Qn;              // used before prep writes Qn
  ushort* hs_bf   = (ushort*)Kn;              // used before prep writes Kn
  ushort* zg_bf   = (ushort*)(ws);            // after phaseb (Kc dead): 0..4.2M
  ushort* Wout_bf = (ushort*)(ws + 4194304);  // after phaseb: 4.2M..8.4M

  const int M = B_ * S_;  // 2048

  // 0. fp32 -> bf16 converts (activations + weights used by bf16 GEMMs)
  f2bf_kernel<<<(M * H_) / 1024, 256, 0, stream>>>(hs, hs_bf, M * H_);
  f2bf_kernel<<<(CC_ * H_) / 1024, 256, 0, stream>>>(W_qkv, Wqkv_bf, CC_ * H_);
  // 1. qkv GEMM (bf16 MFMA) -> fp32 qkv_raw
  gemm_bf16_nt<<<dim3(CC_ / 128, M / 128), 256, 0, stream>>>(hs_bf, Wqkv_bf, qkv_raw, M, CC_, H_);
  // 2. z GEMM (bf16 MFMA) -> fp32 z_gated (overwrites Wqkv_bf, now dead)
  f2bf_kernel<<<(VALDIM_ * H_) / 1024, 256, 0, stream>>>(W_z, Wz_bf, VALDIM_ * H_);
  gemm_bf16_nt<<<dim3(VALDIM_ / 128, M / 128), 256, 0, stream>>>(hs_bf, Wz_bf, z_gated, M, VALDIM_, H_);
  // 3. tiny b/a projections (fp32)
  sgemm_nt<<<dim3(1, M / 64), 256, 0, stream>>>(hs, W_b, b_act, M, HV_, H_);
  sgemm_nt<<<dim3(1, M / 64), 256, 0, stream>>>(hs, W_a, a_act, M, HV_, H_);
  // 4. conv_state_new output
  convstate_kernel<<<(B_ * CC_ * 3 + 255) / 256, 256, 0, stream>>>(qkv_raw, out_conv);
  // 5. conv+silu+l2norm -> Qn,Kn,Vb (overwrites Wz_bf/hs_bf, now dead)
  prep_qkv<<<dim3(64, S_, B_), 128, 0, stream>>>(qkv_raw, conv_state, conv_w, Qn, Kn, Vb);
  prep_gb<<<(B_ * HV_ * S_ + 255) / 256, 256, 0, stream>>>(a_act, b_act, A_log, dt_bias, g_buf, beta_buf);
  // 6. per-chunk matrices
  cp_kernel<<<B_ * HV_ * NC_, 256, 0, stream>>>(Qn, Kn, Vb, g_buf, beta_buf,
                                                G_buf, M_buf, Kc_buf, D0_buf);
  // 7. sequential chunk recurrence (state in LDS, 128 blocks)
  phaseb_kernel<<<B_ * HV_ * 2, 256, 0, stream>>>(rec_state, Qn, Kn, Kc_buf, G_buf,
                                                  D0_buf, Oq_buf, out_state);
  // 8. intra-chunk output + RMS + gate -> bf16 zg (Kc region, now dead)
  phasec_kernel<<<B_ * HV_ * NC_, 128, 0, stream>>>(D0_buf, Oq_buf, M_buf,
                                                    norm_weight, z_gated, zg_bf);
  // 9. output GEMM (bf16 MFMA)
  f2bf_kernel<<<(H_ * VALDIM_) / 1024, 256, 0, stream>>>(W_out, Wout_bf, H_ * VALDIM_);
  gemm_bf16_nt<<<dim3(H_ / 128, M / 128), 256, 0, stream>>>(zg_bf, Wout_bf, out, M, H_, VALDIM_);
}

// Round 5
// 1109.536 us; speedup vs baseline: 6.5098x; 1.1792x over previous
//
#include <hip/hip_runtime.h>
#include <cstdint>
#include <cstddef>

#define B_ 2
#define S_ 1024
#define H_ 2048
#define HV_ 32
#define HK_ 16
#define DK_ 128
#define DV_ 128
#define CC_ 8192
#define KEYDIM_ 2048
#define VALDIM_ 4096
#define NC_ 16          // chunks
#define CS_ 64          // chunk size

typedef __attribute__((ext_vector_type(8))) short bf16x8;
typedef __attribute__((ext_vector_type(4))) float f32x4;

__device__ __forceinline__ ushort f2bf_rne(float x) {
  union { float f; uint32_t u; } c; c.f = x;
  uint32_t u = c.u + 0x7FFFu + ((c.u >> 16) & 1u);
  return (ushort)(u >> 16);
}

// async 16B global->LDS (DMA; LDS dest = wave-uniform base + lane*16)
__device__ __forceinline__ void gld16(const void* g, void* l) {
  __builtin_amdgcn_global_load_lds(
      (const __attribute__((address_space(1))) void*)g,
      (__attribute__((address_space(3))) void*)l, 16, 0, 0);
}

// ---------------------------------------------------------------------------
// fp32 -> bf16 convert (n multiple of 1024)
// ---------------------------------------------------------------------------
__global__ void f2bf_kernel(const float* __restrict__ in, ushort* __restrict__ out, int n) {
  int i = (blockIdx.x * 256 + threadIdx.x) * 4;
  if (i >= n) return;
  float4 v = *(const float4*)(in + i);
  ushort4 o;
  o.x = f2bf_rne(v.x); o.y = f2bf_rne(v.y);
  o.z = f2bf_rne(v.z); o.w = f2bf_rne(v.w);
  *(ushort4*)(out + i) = o;
}

// ---------------------------------------------------------------------------
// bf16 MFMA GEMM (NT): C[m][n] = sum_k A[m][k]*B[n][k]. M,N,K % 128 == 0.
// 128x128 tile, BK=32, 4 waves (2x2), global_load_lds width-16 staging into
// fragment-ordered LDS: segment s (=16 rows) holds (quad,row) at s*1024 +
// quad*256 + row*16 bytes == s*1024 + lane*16 for lane = quad*16+row.
// Fragment read is then a linear 1KB ds_read_b128 per 16x16 tile.
// ---------------------------------------------------------------------------
__global__ __launch_bounds__(256) void gemm_bf16_nt(
    const ushort* __restrict__ A, const ushort* __restrict__ B,
    float* __restrict__ C, int M, int N, int K)
{
  __shared__ ushort sA[8192];   // 8 segments x 512 ushorts (16 KB)
  __shared__ ushort sB[8192];
  int t = threadIdx.x;
  int wave = t >> 6, lane = t & 63;
  int wm = wave >> 1, wn = wave & 1;
  int lrow = lane & 15, quad = lane >> 4;

  f32x4 acc[4][4];
  #pragma unroll
  for (int i = 0; i < 4; i++)
    #pragma unroll
    for (int j = 0; j < 4; j++)
      #pragma unroll
      for (int r = 0; r < 4; r++) acc[i][j][r] = 0.f;

  // staging: wave w stages A segments {2w,2w+1} and B segments {2w,2w+1}
  int seg0 = wave * 2, seg1 = wave * 2 + 1;
  const ushort* aSrc0 = A + (size_t)(blockIdx.y * 128 + seg0 * 16 + lrow) * K + quad * 8;
  const ushort* aSrc1 = A + (size_t)(blockIdx.y * 128 + seg1 * 16 + lrow) * K + quad * 8;
  const ushort* bSrc0 = B + (size_t)(blockIdx.x * 128 + seg0 * 16 + lrow) * K + quad * 8;
  const ushort* bSrc1 = B + (size_t)(blockIdx.x * 128 + seg1 * 16 + lrow) * K + quad * 8;
  ushort* ldsA0 = sA + seg0 * 512;
  ushort* ldsA1 = sA + seg1 * 512;
  ushort* ldsB0 = sB + seg0 * 512;
  ushort* ldsB1 = sB + seg1 * 512;

  for (int k0 = 0; k0 < K; k0 += 32) {
    gld16(aSrc0 + k0, ldsA0);
    gld16(aSrc1 + k0, ldsA1);
    gld16(bSrc0 + k0, ldsB0);
    gld16(bSrc1 + k0, ldsB1);
    __syncthreads();
    bf16x8 af[4], bfr[4];
    #pragma unroll
    for (int i = 0; i < 4; i++)
      af[i] = *(const bf16x8*)(sA + (wm * 4 + i) * 512 + lane * 8);
    #pragma unroll
    for (int j = 0; j < 4; j++)
      bfr[j] = *(const bf16x8*)(sB + (wn * 4 + j) * 512 + lane * 8);
    #pragma unroll
    for (int i = 0; i < 4; i++)
      #pragma unroll
      for (int j = 0; j < 4; j++)
        acc[i][j] = __builtin_amdgcn_mfma_f32_16x16x32_bf16(af[i], bfr[j], acc[i][j], 0, 0, 0);
    __syncthreads();
  }

  #pragma unroll
  for (int i = 0; i < 4; i++) {
    int m_base = blockIdx.y * 128 + wm * 64 + i * 16 + quad * 4;
    #pragma unroll
    for (int j = 0; j < 4; j++) {
      int n = blockIdx.x * 128 + wn * 64 + j * 16 + lrow;
      #pragma unroll
      for (int rr = 0; rr < 4; rr++)
        C[(size_t)(m_base + rr) * N + n] = acc[i][j][rr];
    }
  }
}

// ---------------------------------------------------------------------------
// ba_kernel: fused b/a projections. Out: b_act,a_act (M,32) fp32.
// grid M/16 blocks, 256 threads; K tiled by 128; weight tile transposed.
// ---------------------------------------------------------------------------
__global__ __launch_bounds__(256) void ba_kernel(
    const float* __restrict__ hs, const float* __restrict__ W_b,
    const float* __restrict__ W_a, float* __restrict__ b_act,
    float* __restrict__ a_act)
{
  __shared__ float sH[16 * 132];   // [r][k], pad 132
  __shared__ float sW[128 * 68];   // [k][o], pad 68
  int m0 = blockIdx.x * 16;
  int t = threadIdx.x;
  int r = t >> 4, og = t & 15;
  float acc0 = 0.f, acc1 = 0.f, acc2 = 0.f, acc3 = 0.f;

  for (int kt = 0; kt < 16; kt++) {
    #pragma unroll
    for (int u = 0; u < 2; u++) {
      int idx = u * 256 + t;               // 0..511
      int rr = idx >> 5, k4 = (idx & 31) * 4;
      *(float4*)&sH[rr * 132 + k4] =
          *(const float4*)&hs[(size_t)(m0 + rr) * H_ + kt * 128 + k4];
    }
    #pragma unroll
    for (int u = 0; u < 8; u++) {
      int idx = u * 256 + t;               // 0..2047
      int o = idx >> 5, k4 = (idx & 31) * 4;
      const float* wr = (o < 32) ? &W_b[(size_t)o * H_ + kt * 128 + k4]
                                 : &W_a[(size_t)(o - 32) * H_ + kt * 128 + k4];
      float4 w = *(const float4*)wr;
      sW[(k4 + 0) * 68 + o] = w.x; sW[(k4 + 1) * 68 + o] = w.y;
      sW[(k4 + 2) * 68 + o] = w.z; sW[(k4 + 3) * 68 + o] = w.w;
    }
    __syncthreads();
    #pragma unroll 4
    for (int k = 0; k < 128; k++) {
      float h = sH[r * 132 + k];
      float4 w = *(const float4*)&sW[k * 68 + og * 4];
      acc0 += h * w.x; acc1 += h * w.y; acc2 += h * w.z; acc3 += h * w.w;
    }
    __syncthreads();
  }
  int o4 = og * 4;
  float4 res = make_float4(acc0, acc1, acc2, acc3);
  if (o4 < 32) *(float4*)&b_act[(size_t)(m0 + r) * 32 + o4] = res;
  else         *(float4*)&a_act[(size_t)(m0 + r) * 32 + (o4 - 32)] = res;
}

// ---------------------------------------------------------------------------
// conv_state_new[b][c][j] = mixed_qkv[b][S-3+j][c]
// ---------------------------------------------------------------------------
__global__ void convstate_kernel(const float* __restrict__ qkv_raw,
                                 float* __restrict__ out)
{
  int idx = blockIdx.x * blockDim.x + threadIdx.x;
  if (idx >= B_ * CC_ * 3) return;
  int j = idx % 3;
  int c = (idx / 3) % CC_;
  int b = idx / (3 * CC_);
  out[idx] = qkv_raw[((size_t)(b * S_ + (S_ - 3 + j))) * CC_ + c];
}

// ---------------------------------------------------------------------------
// prep_qkv: conv(K=4)+silu; l2norm q/k heads.
// ---------------------------------------------------------------------------
__global__ __launch_bounds__(128) void prep_qkv(
    const float* __restrict__ qkv_raw, const float* __restrict__ conv_state,
    const float* __restrict__ conv_w,
    float* __restrict__ Qn, float* __restrict__ Kn, float* __restrict__ Vb)
{
  int group = blockIdx.x, s = blockIdx.y, b = blockIdx.z;
  int t = threadIdx.x;
  int c = group * 128 + t;
  float acc = 0.f;
  #pragma unroll
  for (int kk = 0; kk < 4; kk++) {
    int sp = s - 3 + kk;
    float x = (sp < 0) ? conv_state[((size_t)(b * CC_ + c)) * 3 + (3 + sp)]
                       : qkv_raw[((size_t)(b * S_ + sp)) * CC_ + c];
    acc += conv_w[c * 4 + kk] * x;
  }
  float val = acc / (1.f + __expf(-acc));   // silu

  if (group < 32) {
    __shared__ float red2[2];
    float p = val * val;
    #pragma unroll
    for (int off = 32; off > 0; off >>= 1) p += __shfl_xor(p, off);
    if ((t & 63) == 0) red2[t >> 6] = p;
    __syncthreads();
    float r = rsqrtf(red2[0] + red2[1] + 1e-6f);
    if (group < 16) {
      r *= 0.08838834764831845f;  // 128^-0.5
      Qn[(((size_t)(b * HK_ + group)) * S_ + s) * DK_ + t] = val * r;
    } else {
      Kn[(((size_t)(b * HK_ + (group - 16))) * S_ + s) * DK_ + t] = val * r;
    }
  } else {
    Vb[(((size_t)(b * HV_ + (group - 32))) * S_ + s) * DV_ + t] = val;
  }
}

// ---------------------------------------------------------------------------
// prep_gb: g = -exp(A_log)*softplus(a+dt_bias), beta = sigmoid(b). (B,HV,S)
// ---------------------------------------------------------------------------
__global__ void prep_gb(const float* __restrict__ a_act, const float* __restrict__ b_act,
                        const float* __restrict__ A_log, const float* __restrict__ dt_bias,
                        float* __restrict__ g_buf, float* __restrict__ beta_buf)
{
  int idx = blockIdx.x * blockDim.x + threadIdx.x;
  if (idx >= B_ * HV_ * S_) return;
  int s = idx & (S_ - 1);
  int hv = (idx >> 10) & 31;
  int b = idx >> 15;
  float av = a_act[((size_t)(b * S_ + s)) * HV_ + hv];
  float bv = b_act[((size_t)(b * S_ + s)) * HV_ + hv];
  float x = av + dt_bias[hv];
  float sp = (x > 20.f) ? x : log1pf(__expf(x));
  g_buf[idx] = -__expf(A_log[hv]) * sp;
  beta_buf[idx] = 1.f / (1.f + __expf(-bv));
}

// ---------------------------------------------------------------------------
// cp_kernel: per (b,hv,chunk). G cumsum, M, A, Tinv (forward substitution),
// Kc = Tinv*diag(beta*e^G)*K, D0 = Tinv*diag(beta)*V.  (unchanged from R4)
// ---------------------------------------------------------------------------
__device__ __forceinline__ int swf4(int r, int f) { return r * 32 + (f ^ (r & 31)); }
__device__ __forceinline__ int swf1(int r, int k) {
  return r * 128 + 4 * ((k >> 2) ^ (r & 31)) + (k & 3);
}

__global__ __launch_bounds__(256) void cp_kernel(
    const float* __restrict__ Qn, const float* __restrict__ Kn,
    const float* __restrict__ Vb,
    const float* __restrict__ g_buf, const float* __restrict__ beta_buf,
    float* __restrict__ G_buf, float* __restrict__ M_buf,
    float* __restrict__ Kc_buf, float* __restrict__ D0_buf)
{
  __shared__ float sK[64 * 128];
  __shared__ float sX[32 * 128];
  __shared__ float sT[64 * 64];
  float* sG  = sT;
  float* sBe = sT + 64;
  float* sA  = sX;
  float* tTw = sX;
  float* tTb = sX;
  float4* sK4 = (float4*)sK;
  float4* sX4 = (float4*)sX;

  const int ch = blockIdx.x;
  const int bh = ch / NC_, c = ch % NC_;
  const int b = bh >> 5, hv = bh & 31, hk = hv >> 1;
  const int s0 = c * CS_;
  const int t = threadIdx.x;
  const size_t gOff = (size_t)bh * S_ + s0;

  float Gw0 = 0.f, Bw0 = 0.f;
  if (t < 64) {
    float gi = g_buf[gOff + t];
    Gw0 = gi;
    #pragma unroll
    for (int off = 1; off < 64; off <<= 1) {
      float o = __shfl_up(Gw0, off);
      if (t >= off) Gw0 += o;
    }
    G_buf[gOff + t] = Gw0;
    sG[t] = Gw0;
    Bw0 = beta_buf[gOff + t];
    sBe[t] = Bw0;
  }
  {
    const float4* src = (const float4*)(Kn + ((size_t)(b * HK_ + hk) * S_ + s0) * DK_);
    #pragma unroll
    for (int u = 0; u < 8; u++) {
      int idx = u * 256 + t;
      sK4[swf4(idx >> 5, idx & 31)] = src[idx];
    }
  }
  __syncthreads();

  const float4* qsrc = (const float4*)(Qn + ((size_t)(b * HK_ + hk) * S_ + s0) * DK_);
  {
    int ti2 = t >> 4, tj = t & 15;
    for (int h = 0; h < 2; h++) {
      #pragma unroll
      for (int u = 0; u < 4; u++) {
        int idx = u * 256 + t;
        sX4[swf4(idx >> 5, idx & 31)] = qsrc[h * 1024 + idx];
      }
      __syncthreads();
      float accM[2][4];
      #pragma unroll
      for (int a = 0; a < 2; a++)
        #pragma unroll
        for (int e = 0; e < 4; e++) accM[a][e] = 0.f;
      for (int k4 = 0; k4 < 32; k4++) {
        float4 qv[2], kv[4];
        qv[0] = sX4[swf4(ti2, k4)];
        qv[1] = sX4[swf4(ti2 + 16, k4)];
        #pragma unroll
        for (int e = 0; e < 4; e++) kv[e] = sK4[swf4(tj + 16 * e, k4)];
        #pragma unroll
        for (int a = 0; a < 2; a++)
          #pragma unroll
          for (int e = 0; e < 4; e++)
            accM[a][e] += qv[a].x * kv[e].x + qv[a].y * kv[e].y +
                          qv[a].z * kv[e].z + qv[a].w * kv[e].w;
      }
      #pragma unroll
      for (int a = 0; a < 2; a++) {
        int iG = h * 32 + ti2 + 16 * a;
        float Gi = sG[iG];
        #pragma unroll
        for (int e = 0; e < 4; e++) {
          int j = tj + 16 * e;
          float m = (j <= iG) ? __expf(Gi - sG[j]) * accM[a][e] : 0.f;
          M_buf[(size_t)ch * 4096 + iG * 64 + j] = m;
        }
      }
      __syncthreads();
    }
  }

  {
    int ti = t >> 4, tj = t & 15;
    float accA[4][4];
    #pragma unroll
    for (int a = 0; a < 4; a++)
      #pragma unroll
      for (int e = 0; e < 4; e++) accA[a][e] = 0.f;
    for (int k4 = 0; k4 < 32; k4++) {
      float4 ki[4], kj[4];
      #pragma unroll
      for (int e = 0; e < 4; e++) {
        ki[e] = sK4[swf4(ti + 16 * e, k4)];
        kj[e] = sK4[swf4(tj + 16 * e, k4)];
      }
      #pragma unroll
      for (int a = 0; a < 4; a++)
        #pragma unroll
        for (int e = 0; e < 4; e++)
          accA[a][e] += ki[a].x * kj[e].x + ki[a].y * kj[e].y +
                        ki[a].z * kj[e].z + ki[a].w * kj[e].w;
    }
    float resA[4][4];
    #pragma unroll
    for (int a = 0; a < 4; a++) {
      int i = ti + 16 * a;
      float Gi = sG[i], Bi = sBe[i];
      #pragma unroll
      for (int e = 0; e < 4; e++) {
        int j = tj + 16 * e;
        resA[a][e] = (j < i) ? Bi * __expf(Gi - sG[j]) * accA[a][e] : 0.f;
      }
    }
    __syncthreads();
    #pragma unroll
    for (int a = 0; a < 4; a++)
      #pragma unroll
      for (int e = 0; e < 4; e++)
        sA[(ti + 16 * a) * 64 + (tj + 16 * e)] = resA[a][e];
  }
  __syncthreads();

  if (t < 64) {
    sT[t] = (t == 0) ? 1.f : 0.f;
    for (int i = 1; i < 64; i++) {
      float acc = 0.f;
      for (int j = 0; j < i; j++) acc += sA[i * 64 + j] * sT[j * 64 + t];
      sT[i * 64 + t] = ((t == i) ? 1.f : 0.f) - acc;
    }
    float w = Bw0 * __expf(Gw0);
    for (int j = 0; j < 64; j++) {
      float wj = __shfl(w, j);
      tTw[j * 64 + t] = sT[t * 64 + j] * wj;
    }
  }
  __syncthreads();

  {
    int i04 = t >> 4, tk = t & 15;
    float accK[4][8];
    #pragma unroll
    for (int r = 0; r < 4; r++)
      #pragma unroll
      for (int u = 0; u < 8; u++) accK[r][u] = 0.f;
    for (int j = 0; j < 64; j++) {
      float4 tw = ((float4*)tTw)[j * 16 + i04];
      #pragma unroll
      for (int u = 0; u < 8; u++) {
        float kv = sK[swf1(j, tk + 16 * u)];
        accK[0][u] += tw.x * kv; accK[1][u] += tw.y * kv;
        accK[2][u] += tw.z * kv; accK[3][u] += tw.w * kv;
      }
    }
    size_t base = (size_t)ch * 8192;
    #pragma unroll
    for (int r = 0; r < 4; r++)
      #pragma unroll
      for (int u = 0; u < 8; u++)
        Kc_buf[base + (i04 * 4 + r) * 128 + tk + 16 * u] = accK[r][u];
  }
  __syncthreads();

  if (t < 64) {
    for (int j = 0; j < 64; j++) {
      float bj = __shfl(Bw0, j);
      tTb[j * 64 + t] = sT[t * 64 + j] * bj;
    }
  }
  {
    const float4* src = (const float4*)(Vb + ((size_t)bh * S_ + s0) * DV_);
    #pragma unroll
    for (int u = 0; u < 8; u++) {
      int idx = u * 256 + t;
      sK4[swf4(idx >> 5, idx & 31)] = src[idx];
    }
  }
  __syncthreads();

  {
    int i04 = t >> 4, tv_ = t & 15;
    float accD[4][8];
    #pragma unroll
    for (int r = 0; r < 4; r++)
      #pragma unroll
      for (int u = 0; u < 8; u++) accD[r][u] = 0.f;
    for (int j = 0; j < 64; j++) {
      float4 tb = ((float4*)tTb)[j * 16 + i04];
      #pragma unroll
      for (int u = 0; u < 8; u++) {
        float vv = sK[swf1(j, tv_ + 16 * u)];
        accD[0][u] += tb.x * vv; accD[1][u] += tb.y * vv;
        accD[2][u] += tb.z * vv; accD[3][u] += tb.w * vv;
      }
    }
    size_t base = (size_t)ch * 8192;
    #pragma unroll
    for (int r = 0; r < 4; r++)
      #pragma unroll
      for (int u = 0; u < 8; u++)
        D0_buf[base + (i04 * 4 + r) * 128 + tv_ + 16 * u] = accD[r][u];
  }
}

// ---------------------------------------------------------------------------
// phaseb v3: 256 blocks = (head bh, v-quarter vq), 256 threads, 1 block/CU.
// Per chunk: D = D0 - Kc*S0 ; Oq = diag(e^G) Q * S0 ; S <- e^{GC} S0 + Kd^T D.
// ---------------------------------------------------------------------------
__global__ __launch_bounds__(256) void phaseb_kernel(
    const float* __restrict__ rec_state, const float* __restrict__ Qn,
    const float* __restrict__ Kn, const float* __restrict__ Kc_buf,
    const float* __restrict__ G_buf,
    float* __restrict__ D_io, float* __restrict__ Oq_buf,
    float* __restrict__ final_state)
{
  __shared__ float sS[128 * 32];    // state [k][v]   16 KB
  __shared__ float sKT[128 * 64];   // Kc^T [k][i], then Kd [i][k]
  __shared__ float sQT[128 * 64];   // Qb^T [k][i]
  __shared__ float sD[64 * 32];     // D [i][v]        8 KB

  const int blk = blockIdx.x;       // 0..255
  const int bh = blk >> 2, vq = blk & 3;
  const int b = bh >> 5, hv = bh & 31, hk = hv >> 1;
  const int t = threadIdx.x;
  const int vbase = vq * 32;
  const float* gG = G_buf + (size_t)bh * S_;

  // load state quarter: sS[k][vl] = rec_state[bh][k][vbase+vl]
  #pragma unroll
  for (int u = 0; u < 4; u++) {
    int idx = u * 256 + t;            // float4 index, 0..1023
    int k = idx >> 3;
    int v4 = (idx & 7) * 4;
    *(float4*)(&sS[k * 32 + v4]) =
        *(const float4*)(&rec_state[((size_t)bh * 128 + k) * 128 + vbase + v4]);
  }
  __syncthreads();

  const int si = t & 63, skq = t >> 6;   // staging: row si, k-quarter skq
  const int ti = t >> 3;                 // 0..31 -> i-pair ti*2
  const int tv = t & 7;                  // v4 = tv*4
  const int tk = t >> 3;                 // 0..31 -> k-quad tk*4

  for (int c = 0; c < NC_; c++) {
    const size_t ch = (size_t)bh * NC_ + c;
    const int s0 = c * CS_;
    const float GC = gG[s0 + 63];
    const float eGC = __expf(GC);

    // ---- stage Kc^T and Qb^T = e^{G_i} Q^T ----
    {
      float eGi = __expf(gG[s0 + si]);
      const float* kcRow = Kc_buf + ch * 8192 + si * 128 + skq * 32;
      const float* qRow  = Qn + ((size_t)(b * HK_ + hk) * S_ + s0 + si) * DK_ + skq * 32;
      #pragma unroll
      for (int u = 0; u < 8; u++) {
        float4 kc = *(const float4*)(kcRow + u * 4);
        float4 qv = *(const float4*)(qRow + u * 4);
        int kk = skq * 32 + u * 4;
        sKT[(kk + 0) * 64 + si] = kc.x; sKT[(kk + 1) * 64 + si] = kc.y;
        sKT[(kk + 2) * 64 + si] = kc.z; sKT[(kk + 3) * 64 + si] = kc.w;
        sQT[(kk + 0) * 64 + si] = qv.x * eGi; sQT[(kk + 1) * 64 + si] = qv.y * eGi;
        sQT[(kk + 2) * 64 + si] = qv.z * eGi; sQT[(kk + 3) * 64 + si] = qv.w * eGi;
      }
    }
    __syncthreads();

    // ---- D = D0 - Kc*S0 ; Oq = Qb*S0  (2i x 4v per thread) ----
    {
      float accD[2][4], accO[2][4];
      #pragma unroll
      for (int r = 0; r < 2; r++) {
        float4 d0 = *(const float4*)(&D_io[ch * 8192 + (size_t)(ti * 2 + r) * 128 + vbase + tv * 4]);
        accD[r][0] = d0.x; accD[r][1] = d0.y; accD[r][2] = d0.z; accD[r][3] = d0.w;
        accO[r][0] = accO[r][1] = accO[r][2] = accO[r][3] = 0.f;
      }
      for (int k = 0; k < 128; k++) {
        float2 kc = *(const float2*)(&sKT[k * 64 + ti * 2]);
        float2 qb = *(const float2*)(&sQT[k * 64 + ti * 2]);
        float4 sv = *(const float4*)(&sS[k * 32 + tv * 4]);
        accD[0][0] -= kc.x * sv.x; accD[0][1] -= kc.x * sv.y;
        accD[0][2] -= kc.x * sv.z; accD[0][3] -= kc.x * sv.w;
        accD[1][0] -= kc.y * sv.x; accD[1][1] -= kc.y * sv.y;
        accD[1][2] -= kc.y * sv.z; accD[1][3] -= kc.y * sv.w;
        accO[0][0] += qb.x * sv.x; accO[0][1] += qb.x * sv.y;
        accO[0][2] += qb.x * sv.z; accO[0][3] += qb.x * sv.w;
        accO[1][0] += qb.y * sv.x; accO[1][1] += qb.y * sv.y;
        accO[1][2] += qb.y * sv.z; accO[1][3] += qb.y * sv.w;
      }
      #pragma unroll
      for (int r = 0; r < 2; r++) {
        int i = ti * 2 + r;
        float4 dv = make_float4(accD[r][0], accD[r][1], accD[r][2], accD[r][3]);
        float4 ov = make_float4(accO[r][0], accO[r][1], accO[r][2], accO[r][3]);
        *(float4*)(&sD[i * 32 + tv * 4]) = dv;
        *(float4*)(&D_io[ch * 8192 + (size_t)i * 128 + vbase + tv * 4]) = dv;
        *(float4*)(&Oq_buf[ch * 8192 + (size_t)i * 128 + vbase + tv * 4]) = ov;
      }
    }
    __syncthreads();

    // ---- stage Kd[i][k] = e^{GC-G_i} K[i][k] over sKT ----
    {
      float sc = __expf(GC - gG[s0 + si]);
      const float* kRow = Kn + ((size_t)(b * HK_ + hk) * S_ + s0 + si) * DK_ + skq * 32;
      float4* dst = (float4*)(&sKT[si * 128 + skq * 32]);
      #pragma unroll
      for (int u = 0; u < 8; u++) {
        float4 x = *(const float4*)(kRow + u * 4);
        x.x *= sc; x.y *= sc; x.z *= sc; x.w *= sc;
        dst[u] = x;
      }
    }
    __syncthreads();

    // ---- S <- e^{GC} S + Kd^T D  (4k x 4v per thread) ----
    {
      float acc[4][4];
      #pragma unroll
      for (int r = 0; r < 4; r++)
        acc[r][0] = acc[r][1] = acc[r][2] = acc[r][3] = 0.f;
      for (int i = 0; i < 64; i++) {
        float4 d  = *(const float4*)(&sD[i * 32 + tv * 4]);
        float4 ka = *(const float4*)(&sKT[i * 128 + tk * 4]);
        acc[0][0] += ka.x * d.x; acc[0][1] += ka.x * d.y;
        acc[0][2] += ka.x * d.z; acc[0][3] += ka.x * d.w;
        acc[1][0] += ka.y * d.x; acc[1][1] += ka.y * d.y;
        acc[1][2] += ka.y * d.z; acc[1][3] += ka.y * d.w;
        acc[2][0] += ka.z * d.x; acc[2][1] += ka.z * d.y;
        acc[2][2] += ka.z * d.z; acc[2][3] += ka.z * d.w;
        acc[3][0] += ka.w * d.x; acc[3][1] += ka.w * d.y;
        acc[3][2] += ka.w * d.z; acc[3][3] += ka.w * d.w;
      }
      #pragma unroll
      for (int r = 0; r < 4; r++) {
        int k = tk * 4 + r;
        float4 s = *(const float4*)(&sS[k * 32 + tv * 4]);
        s.x = s.x * eGC + acc[r][0]; s.y = s.y * eGC + acc[r][1];
        s.z = s.z * eGC + acc[r][2]; s.w = s.w * eGC + acc[r][3];
        *(float4*)(&sS[k * 32 + tv * 4]) = s;
      }
    }
    __syncthreads();
  }

  // final state
  #pragma unroll
  for (int u = 0; u < 4; u++) {
    int idx = u * 256 + t;
    int k = idx >> 3;
    int v4 = (idx & 7) * 4;
    *(float4*)(&final_state[((size_t)bh * 128 + k) * 128 + vbase + v4]) =
        *(const float4*)(&sS[k * 32 + v4]);
  }
}

// ---------------------------------------------------------------------------
// phasec: O = Oq + M*D, RMS-norm + weight + silu(z) gate -> bf16 zg
// ---------------------------------------------------------------------------
__global__ __launch_bounds__(128) void phasec_kernel(
    const float* __restrict__ D_buf, const float* __restrict__ Oq_buf,
    const float* __restrict__ M_buf, const float* __restrict__ norm_weight,
    const float* __restrict__ z_gated, ushort* __restrict__ zg_bf)
{
  __shared__ float sM[4096];
  __shared__ float red[2][2];
  int ch = blockIdx.x;
  int bh = ch / NC_, c = ch % NC_;
  int b = bh >> 5, hv = bh & 31;
  int s0 = c * CS_;
  int v = threadIdx.x;

  float Dr[64];
  #pragma unroll
  for (int j = 0; j < 64; j++) Dr[j] = D_buf[(size_t)ch * 8192 + j * 128 + v];
  {
    const float4* src = (const float4*)(M_buf + (size_t)ch * 4096);
    #pragma unroll
    for (int u = 0; u < 8; u++) ((float4*)sM)[u * 128 + v] = src[u * 128 + v];
  }
  __syncthreads();
  float nw = norm_weight[v];

  for (int i = 0; i < 64; i++) {
    float o = Oq_buf[(size_t)ch * 8192 + i * 128 + v];
    const float4* mr = (const float4*)(sM + i * 64);
    #pragma unroll
    for (int j4 = 0; j4 < 16; j4++) {
      float4 m = mr[j4];
      o += m.x * Dr[4 * j4] + m.y * Dr[4 * j4 + 1] +
           m.z * Dr[4 * j4 + 2] + m.w * Dr[4 * j4 + 3];
    }
    float p = o * o;
    #pragma unroll
    for (int off = 32; off > 0; off >>= 1) p += __shfl_xor(p, off);
    if ((v & 63) == 0) red[i & 1][v >> 6] = p;
    __syncthreads();
    float var = (red[i & 1][0] + red[i & 1][1]) * (1.f / 128.f);
    float xn = o * rsqrtf(var + 1e-6f) * nw;
    size_t zi = ((size_t)(b * S_ + s0 + i)) * VALDIM_ + hv * DV_ + v;
    float zv = z_gated[zi];
    zg_bf[zi] = f2bf_rne(xn * (zv / (1.f + __expf(-zv))));
  }
}

// ---------------------------------------------------------------------------
extern "C" void kernel_launch(void* const* d_in, const int* in_sizes, int n_in,
                              void* d_out, int out_size, void* d_ws, size_t ws_size,
                              hipStream_t stream)
{
  const float* hs          = (const float*)d_in[0];
  const float* conv_state  = (const float*)d_in[1];
  const float* rec_state   = (const float*)d_in[2];
  const float* W_qkv       = (const float*)d_in[3];
  const float* W_z         = (const float*)d_in[4];
  const float* W_b         = (const float*)d_in[5];
  const float* W_a         = (const float*)d_in[6];
  const float* conv_w      = (const float*)d_in[7];
  const float* dt_bias     = (const float*)d_in[8];
  const float* A_log       = (const float*)d_in[9];
  const float* norm_weight = (const float*)d_in[10];
  const float* W_out       = (const float*)d_in[11];

  float* out       = (float*)d_out;                      // (B,S,H)
  float* out_conv  = out + (size_t)B_ * S_ * H_;         // (B,C,3)
  float* out_state = out_conv + (size_t)B_ * CC_ * 3;    // (B,HV,DK,DV)

  float* ws = (float*)d_ws;
  float* qkv_raw  = ws;                       // 0 .. 16.7M (dead after prep)
  float* Kc_buf   = ws;                       // 0 .. 8.4M   (post-qkv alias)
  float* M_buf    = ws + 8388608;             // 8.4M .. 12.6M
  float* z_gated  = ws + 16777216;            // 16.7M .. 25.2M (fp32 z)
  float* b_act    = ws + 25165824;
  float* a_act    = ws + 25231360;
  float* Qn       = ws + 25296896;            // 4.2M
  float* Kn       = ws + 29491200;            // 4.2M
  float* Vb       = ws + 33685504;            // 8.4M (dead after cp -> Oq)
  float* g_buf    = ws + 42074112;
  float* beta_buf = ws + 42139648;
  float* G_buf    = ws + 42205184;
  float* D0_buf   = ws + 42270720;            // 8.4M  (D in-place)
  float* Oq_buf   = Vb;                       // alias

  // bf16 regions aliasing dead fp32 regions (time-ordered):
  ushort* Wqkv_bf = (ushort*)z_gated;         // used before z GEMM writes z
  ushort* Wz_bf   = (ushort*)Qn;              // used before prep writes Qn
  ushort* hs_bf   = (ushort*)Kn;              // used before prep writes Kn
  ushort* zg_bf   = (ushort*)(ws);            // after phaseb (Kc dead)
  ushort* Wout_bf = (ushort*)(ws + 4194304);  // after phaseb

  const int M = B_ * S_;  // 2048

  // 0. fp32 -> bf16 converts
  f2bf_kernel<<<(M * H_) / 1024, 256, 0, stream>>>(hs, hs_bf, M * H_);
  f2bf_kernel<<<(CC_ * H_) / 1024, 256, 0, stream>>>(W_qkv, Wqkv_bf, CC_ * H_);
  // 1. qkv GEMM (bf16 MFMA) -> fp32 qkv_raw
  gemm_bf16_nt<<<dim3(CC_ / 128, M / 128), 256, 0, stream>>>(hs_bf, Wqkv_bf, qkv_raw, M, CC_, H_);
  // 2. z GEMM (bf16 MFMA) -> fp32 z_gated
  f2bf_kernel<<<(VALDIM_ * H_) / 1024, 256, 0, stream>>>(W_z, Wz_bf, VALDIM_ * H_);
  gemm_bf16_nt<<<dim3(VALDIM_ / 128, M / 128), 256, 0, stream>>>(hs_bf, Wz_bf, z_gated, M, VALDIM_, H_);
  // 3. fused b/a projections (fp32)
  ba_kernel<<<M / 16, 256, 0, stream>>>(hs, W_b, W_a, b_act, a_act);
  // 4. conv_state_new output
  convstate_kernel<<<(B_ * CC_ * 3 + 255) / 256, 256, 0, stream>>>(qkv_raw, out_conv);
  // 5. conv+silu+l2norm -> Qn,Kn,Vb ; gates
  prep_qkv<<<dim3(64, S_, B_), 128, 0, stream>>>(qkv_raw, conv_state, conv_w, Qn, Kn, Vb);
  prep_gb<<<(B_ * HV_ * S_ + 255) / 256, 256, 0, stream>>>(a_act, b_act, A_log, dt_bias, g_buf, beta_buf);
  // 6. per-chunk matrices
  cp_kernel<<<B_ * HV_ * NC_, 256, 0, stream>>>(Qn, Kn, Vb, g_buf, beta_buf,
                                                G_buf, M_buf, Kc_buf, D0_buf);
  // 7. sequential chunk recurrence (256 blocks, 1/CU)
  phaseb_kernel<<<B_ * HV_ * 4, 256, 0, stream>>>(rec_state, Qn, Kn, Kc_buf, G_buf,
                                                  D0_buf, Oq_buf, out_state);
  // 8. intra-chunk output + RMS + gate -> bf16 zg
  phasec_kernel<<<B_ * HV_ * NC_, 128, 0, stream>>>(D0_buf, Oq_buf, M_buf,
                                                    norm_weight, z_gated, zg_bf);
  // 9. output GEMM (bf16 MFMA)
  f2bf_kernel<<<(H_ * VALDIM_) / 1024, 256, 0, stream>>>(W_out, Wout_bf, H_ * VALDIM_);
  gemm_bf16_nt<<<dim3(H_ / 128, M / 128), 256, 0, stream>>>(zg_bf, Wout_bf, out, M, H_, VALDIM_);
}

// Round 6
// 1055.382 us; speedup vs baseline: 6.8439x; 1.0513x over previous
//
#include <hip/hip_runtime.h>
#include <cstdint>
#include <cstddef>

#define B_ 2
#define S_ 1024
#define H_ 2048
#define HV_ 32
#define HK_ 16
#define DK_ 128
#define DV_ 128
#define CC_ 8192
#define KEYDIM_ 2048
#define VALDIM_ 4096
#define NC_ 16          // chunks
#define CS_ 64          // chunk size
#define NBIG 12416      // fused GEMM1 N: 8192 qkv + 4096 z + 32 b + 32 a + 64 pad

typedef __attribute__((ext_vector_type(8))) short bf16x8;
typedef __attribute__((ext_vector_type(4))) float f32x4;

__device__ __forceinline__ ushort f2bf_rne(float x) {
  union { float f; uint32_t u; } c; c.f = x;
  uint32_t u = c.u + 0x7FFFu + ((c.u >> 16) & 1u);
  return (ushort)(u >> 16);
}

// async 16B global->LDS (DMA; LDS dest = wave-uniform base + lane*16)
__device__ __forceinline__ void gld16(const void* g, void* l) {
  __builtin_amdgcn_global_load_lds(
      (const __attribute__((address_space(1))) void*)g,
      (__attribute__((address_space(3))) void*)l, 16, 0, 0);
}

// ---------------------------------------------------------------------------
// fp32 -> bf16 convert (n multiple of 1024)
// ---------------------------------------------------------------------------
__global__ void f2bf_kernel(const float* __restrict__ in, ushort* __restrict__ out, int n) {
  int i = (blockIdx.x * 256 + threadIdx.x) * 4;
  if (i >= n) return;
  float4 v = *(const float4*)(in + i);
  ushort4 o;
  o.x = f2bf_rne(v.x); o.y = f2bf_rne(v.y);
  o.z = f2bf_rne(v.z); o.w = f2bf_rne(v.w);
  *(ushort4*)(out + i) = o;
}

// ---------------------------------------------------------------------------
// wcat: build concatenated bf16 weight (NBIG, H): [W_qkv; W_z; W_b; W_a; 0]
// ---------------------------------------------------------------------------
__global__ void wcat_kernel(const float* __restrict__ Wqkv, const float* __restrict__ Wz,
                            const float* __restrict__ Wb, const float* __restrict__ Wa,
                            ushort* __restrict__ out) {
  int i = (blockIdx.x * 256 + threadIdx.x) * 4;
  if (i >= NBIG * H_) return;
  int n = i >> 11;           // / H_
  int k = i & (H_ - 1);
  float4 v = make_float4(0.f, 0.f, 0.f, 0.f);
  if (n < 8192)       v = *(const float4*)(Wqkv + (size_t)n * H_ + k);
  else if (n < 12288) v = *(const float4*)(Wz + (size_t)(n - 8192) * H_ + k);
  else if (n < 12320) v = *(const float4*)(Wb + (size_t)(n - 12288) * H_ + k);
  else if (n < 12352) v = *(const float4*)(Wa + (size_t)(n - 12320) * H_ + k);
  ushort4 o;
  o.x = f2bf_rne(v.x); o.y = f2bf_rne(v.y);
  o.z = f2bf_rne(v.z); o.w = f2bf_rne(v.w);
  *(ushort4*)(out + i) = o;
}

// ---------------------------------------------------------------------------
// bf16 MFMA GEMM (NT): C[m][n] = sum_k A[m][k]*B[n][k]. M,N,K % 128 == 0.
// 128x128 tile, BK=32, global_load_lds width-16, fragment-ordered LDS.
// ---------------------------------------------------------------------------
__global__ __launch_bounds__(256) void gemm_bf16_nt(
    const ushort* __restrict__ A, const ushort* __restrict__ B,
    float* __restrict__ C, int M, int N, int K)
{
  __shared__ ushort sA[8192];
  __shared__ ushort sB[8192];
  int t = threadIdx.x;
  int wave = t >> 6, lane = t & 63;
  int wm = wave >> 1, wn = wave & 1;
  int lrow = lane & 15, quad = lane >> 4;

  f32x4 acc[4][4];
  #pragma unroll
  for (int i = 0; i < 4; i++)
    #pragma unroll
    for (int j = 0; j < 4; j++)
      #pragma unroll
      for (int r = 0; r < 4; r++) acc[i][j][r] = 0.f;

  int seg0 = wave * 2, seg1 = wave * 2 + 1;
  const ushort* aSrc0 = A + (size_t)(blockIdx.y * 128 + seg0 * 16 + lrow) * K + quad * 8;
  const ushort* aSrc1 = A + (size_t)(blockIdx.y * 128 + seg1 * 16 + lrow) * K + quad * 8;
  const ushort* bSrc0 = B + (size_t)(blockIdx.x * 128 + seg0 * 16 + lrow) * K + quad * 8;
  const ushort* bSrc1 = B + (size_t)(blockIdx.x * 128 + seg1 * 16 + lrow) * K + quad * 8;
  ushort* ldsA0 = sA + seg0 * 512;
  ushort* ldsA1 = sA + seg1 * 512;
  ushort* ldsB0 = sB + seg0 * 512;
  ushort* ldsB1 = sB + seg1 * 512;

  for (int k0 = 0; k0 < K; k0 += 32) {
    gld16(aSrc0 + k0, ldsA0);
    gld16(aSrc1 + k0, ldsA1);
    gld16(bSrc0 + k0, ldsB0);
    gld16(bSrc1 + k0, ldsB1);
    __syncthreads();
    bf16x8 af[4], bfr[4];
    #pragma unroll
    for (int i = 0; i < 4; i++)
      af[i] = *(const bf16x8*)(sA + (wm * 4 + i) * 512 + lane * 8);
    #pragma unroll
    for (int j = 0; j < 4; j++)
      bfr[j] = *(const bf16x8*)(sB + (wn * 4 + j) * 512 + lane * 8);
    #pragma unroll
    for (int i = 0; i < 4; i++)
      #pragma unroll
      for (int j = 0; j < 4; j++)
        acc[i][j] = __builtin_amdgcn_mfma_f32_16x16x32_bf16(af[i], bfr[j], acc[i][j], 0, 0, 0);
    __syncthreads();
  }

  #pragma unroll
  for (int i = 0; i < 4; i++) {
    int m_base = blockIdx.y * 128 + wm * 64 + i * 16 + quad * 4;
    #pragma unroll
    for (int j = 0; j < 4; j++) {
      int n = blockIdx.x * 128 + wn * 64 + j * 16 + lrow;
      #pragma unroll
      for (int rr = 0; rr < 4; rr++)
        C[(size_t)(m_base + rr) * N + n] = acc[i][j][rr];
    }
  }
}

// ---------------------------------------------------------------------------
// conv_state_new[b][c][j] = mixed_qkv[b][S-3+j][c]  (from (B,S,NBIG) C-matrix)
// ---------------------------------------------------------------------------
__global__ void convstate_kernel(const float* __restrict__ Cbig,
                                 float* __restrict__ out)
{
  int idx = blockIdx.x * blockDim.x + threadIdx.x;
  if (idx >= B_ * CC_ * 3) return;
  int j = idx % 3;
  int c = (idx / 3) % CC_;
  int b = idx / (3 * CC_);
  out[idx] = Cbig[((size_t)(b * S_ + (S_ - 3 + j))) * NBIG + c];
}

// ---------------------------------------------------------------------------
// prep_qkv: conv(K=4)+silu; l2norm q/k heads. qkv read from C-matrix cols 0..8191
// ---------------------------------------------------------------------------
__global__ __launch_bounds__(128) void prep_qkv(
    const float* __restrict__ Cbig, const float* __restrict__ conv_state,
    const float* __restrict__ conv_w,
    float* __restrict__ Qn, float* __restrict__ Kn, float* __restrict__ Vb)
{
  int group = blockIdx.x, s = blockIdx.y, b = blockIdx.z;
  int t = threadIdx.x;
  int c = group * 128 + t;
  float acc = 0.f;
  #pragma unroll
  for (int kk = 0; kk < 4; kk++) {
    int sp = s - 3 + kk;
    float x = (sp < 0) ? conv_state[((size_t)(b * CC_ + c)) * 3 + (3 + sp)]
                       : Cbig[((size_t)(b * S_ + sp)) * NBIG + c];
    acc += conv_w[c * 4 + kk] * x;
  }
  float val = acc / (1.f + __expf(-acc));   // silu

  if (group < 32) {
    __shared__ float red2[2];
    float p = val * val;
    #pragma unroll
    for (int off = 32; off > 0; off >>= 1) p += __shfl_xor(p, off);
    if ((t & 63) == 0) red2[t >> 6] = p;
    __syncthreads();
    float r = rsqrtf(red2[0] + red2[1] + 1e-6f);
    if (group < 16) {
      r *= 0.08838834764831845f;  // 128^-0.5
      Qn[(((size_t)(b * HK_ + group)) * S_ + s) * DK_ + t] = val * r;
    } else {
      Kn[(((size_t)(b * HK_ + (group - 16))) * S_ + s) * DK_ + t] = val * r;
    }
  } else {
    Vb[(((size_t)(b * HV_ + (group - 32))) * S_ + s) * DV_ + t] = val;
  }
}

// ---------------------------------------------------------------------------
// prep_gb: g/beta from C-matrix cols 12288..12351
// ---------------------------------------------------------------------------
__global__ void prep_gb(const float* __restrict__ Cbig,
                        const float* __restrict__ A_log, const float* __restrict__ dt_bias,
                        float* __restrict__ g_buf, float* __restrict__ beta_buf)
{
  int idx = blockIdx.x * blockDim.x + threadIdx.x;
  if (idx >= B_ * HV_ * S_) return;
  int s = idx & (S_ - 1);
  int hv = (idx >> 10) & 31;
  int b = idx >> 15;
  float bv = Cbig[((size_t)(b * S_ + s)) * NBIG + 12288 + hv];
  float av = Cbig[((size_t)(b * S_ + s)) * NBIG + 12320 + hv];
  float x = av + dt_bias[hv];
  float sp = (x > 20.f) ? x : log1pf(__expf(x));
  g_buf[idx] = -__expf(A_log[hv]) * sp;
  beta_buf[idx] = 1.f / (1.f + __expf(-bv));
}

// ---------------------------------------------------------------------------
// cp_kernel: per (b,hv,chunk). G cumsum, M, A, Tinv, Kc, D0.
// Kc chunk ch -> KcD + ch*NBIG (C-matrix row ch, cols 0..8191)
// D0 chunk ch -> D0p + ch*NBIG (C-matrix row 1024+ch)
// ---------------------------------------------------------------------------
__device__ __forceinline__ int swf4(int r, int f) { return r * 32 + (f ^ (r & 31)); }
__device__ __forceinline__ int swf1(int r, int k) {
  return r * 128 + 4 * ((k >> 2) ^ (r & 31)) + (k & 3);
}

__global__ __launch_bounds__(256) void cp_kernel(
    const float* __restrict__ Qn, const float* __restrict__ Kn,
    const float* __restrict__ Vb,
    const float* __restrict__ g_buf, const float* __restrict__ beta_buf,
    float* __restrict__ G_buf, float* __restrict__ M_buf,
    float* __restrict__ KcD, float* __restrict__ D0p)
{
  __shared__ float sK[64 * 128];
  __shared__ float sX[32 * 128];
  __shared__ float sT[64 * 64];
  float* sG  = sT;
  float* sBe = sT + 64;
  float* sA  = sX;
  float* tTw = sX;
  float* tTb = sX;
  float4* sK4 = (float4*)sK;
  float4* sX4 = (float4*)sX;

  const int ch = blockIdx.x;
  const int bh = ch / NC_, c = ch % NC_;
  const int b = bh >> 5, hv = bh & 31, hk = hv >> 1;
  const int s0 = c * CS_;
  const int t = threadIdx.x;
  const size_t gOff = (size_t)bh * S_ + s0;

  float Gw0 = 0.f, Bw0 = 0.f;
  if (t < 64) {
    float gi = g_buf[gOff + t];
    Gw0 = gi;
    #pragma unroll
    for (int off = 1; off < 64; off <<= 1) {
      float o = __shfl_up(Gw0, off);
      if (t >= off) Gw0 += o;
    }
    G_buf[gOff + t] = Gw0;
    sG[t] = Gw0;
    Bw0 = beta_buf[gOff + t];
    sBe[t] = Bw0;
  }
  {
    const float4* src = (const float4*)(Kn + ((size_t)(b * HK_ + hk) * S_ + s0) * DK_);
    #pragma unroll
    for (int u = 0; u < 8; u++) {
      int idx = u * 256 + t;
      sK4[swf4(idx >> 5, idx & 31)] = src[idx];
    }
  }
  __syncthreads();

  const float4* qsrc = (const float4*)(Qn + ((size_t)(b * HK_ + hk) * S_ + s0) * DK_);
  {
    int ti2 = t >> 4, tj = t & 15;
    for (int h = 0; h < 2; h++) {
      #pragma unroll
      for (int u = 0; u < 4; u++) {
        int idx = u * 256 + t;
        sX4[swf4(idx >> 5, idx & 31)] = qsrc[h * 1024 + idx];
      }
      __syncthreads();
      float accM[2][4];
      #pragma unroll
      for (int a = 0; a < 2; a++)
        #pragma unroll
        for (int e = 0; e < 4; e++) accM[a][e] = 0.f;
      for (int k4 = 0; k4 < 32; k4++) {
        float4 qv[2], kv[4];
        qv[0] = sX4[swf4(ti2, k4)];
        qv[1] = sX4[swf4(ti2 + 16, k4)];
        #pragma unroll
        for (int e = 0; e < 4; e++) kv[e] = sK4[swf4(tj + 16 * e, k4)];
        #pragma unroll
        for (int a = 0; a < 2; a++)
          #pragma unroll
          for (int e = 0; e < 4; e++)
            accM[a][e] += qv[a].x * kv[e].x + qv[a].y * kv[e].y +
                          qv[a].z * kv[e].z + qv[a].w * kv[e].w;
      }
      #pragma unroll
      for (int a = 0; a < 2; a++) {
        int iG = h * 32 + ti2 + 16 * a;
        float Gi = sG[iG];
        #pragma unroll
        for (int e = 0; e < 4; e++) {
          int j = tj + 16 * e;
          float m = (j <= iG) ? __expf(Gi - sG[j]) * accM[a][e] : 0.f;
          M_buf[(size_t)ch * 4096 + iG * 64 + j] = m;
        }
      }
      __syncthreads();
    }
  }

  {
    int ti = t >> 4, tj = t & 15;
    float accA[4][4];
    #pragma unroll
    for (int a = 0; a < 4; a++)
      #pragma unroll
      for (int e = 0; e < 4; e++) accA[a][e] = 0.f;
    for (int k4 = 0; k4 < 32; k4++) {
      float4 ki[4], kj[4];
      #pragma unroll
      for (int e = 0; e < 4; e++) {
        ki[e] = sK4[swf4(ti + 16 * e, k4)];
        kj[e] = sK4[swf4(tj + 16 * e, k4)];
      }
      #pragma unroll
      for (int a = 0; a < 4; a++)
        #pragma unroll
        for (int e = 0; e < 4; e++)
          accA[a][e] += ki[a].x * kj[e].x + ki[a].y * kj[e].y +
                        ki[a].z * kj[e].z + ki[a].w * kj[e].w;
    }
    float resA[4][4];
    #pragma unroll
    for (int a = 0; a < 4; a++) {
      int i = ti + 16 * a;
      float Gi = sG[i], Bi = sBe[i];
      #pragma unroll
      for (int e = 0; e < 4; e++) {
        int j = tj + 16 * e;
        resA[a][e] = (j < i) ? Bi * __expf(Gi - sG[j]) * accA[a][e] : 0.f;
      }
    }
    __syncthreads();
    #pragma unroll
    for (int a = 0; a < 4; a++)
      #pragma unroll
      for (int e = 0; e < 4; e++)
        sA[(ti + 16 * a) * 64 + (tj + 16 * e)] = resA[a][e];
  }
  __syncthreads();

  if (t < 64) {
    sT[t] = (t == 0) ? 1.f : 0.f;
    for (int i = 1; i < 64; i++) {
      float acc = 0.f;
      for (int j = 0; j < i; j++) acc += sA[i * 64 + j] * sT[j * 64 + t];
      sT[i * 64 + t] = ((t == i) ? 1.f : 0.f) - acc;
    }
    float w = Bw0 * __expf(Gw0);
    for (int j = 0; j < 64; j++) {
      float wj = __shfl(w, j);
      tTw[j * 64 + t] = sT[t * 64 + j] * wj;
    }
  }
  __syncthreads();

  {
    int i04 = t >> 4, tk = t & 15;
    float accK[4][8];
    #pragma unroll
    for (int r = 0; r < 4; r++)
      #pragma unroll
      for (int u = 0; u < 8; u++) accK[r][u] = 0.f;
    for (int j = 0; j < 64; j++) {
      float4 tw = ((float4*)tTw)[j * 16 + i04];
      #pragma unroll
      for (int u = 0; u < 8; u++) {
        float kv = sK[swf1(j, tk + 16 * u)];
        accK[0][u] += tw.x * kv; accK[1][u] += tw.y * kv;
        accK[2][u] += tw.z * kv; accK[3][u] += tw.w * kv;
      }
    }
    size_t base = (size_t)ch * NBIG;
    #pragma unroll
    for (int r = 0; r < 4; r++)
      #pragma unroll
      for (int u = 0; u < 8; u++)
        KcD[base + (i04 * 4 + r) * 128 + tk + 16 * u] = accK[r][u];
  }
  __syncthreads();

  if (t < 64) {
    for (int j = 0; j < 64; j++) {
      float bj = __shfl(Bw0, j);
      tTb[j * 64 + t] = sT[t * 64 + j] * bj;
    }
  }
  {
    const float4* src = (const float4*)(Vb + ((size_t)bh * S_ + s0) * DV_);
    #pragma unroll
    for (int u = 0; u < 8; u++) {
      int idx = u * 256 + t;
      sK4[swf4(idx >> 5, idx & 31)] = src[idx];
    }
  }
  __syncthreads();

  {
    int i04 = t >> 4, tv_ = t & 15;
    float accD[4][8];
    #pragma unroll
    for (int r = 0; r < 4; r++)
      #pragma unroll
      for (int u = 0; u < 8; u++) accD[r][u] = 0.f;
    for (int j = 0; j < 64; j++) {
      float4 tb = ((float4*)tTb)[j * 16 + i04];
      #pragma unroll
      for (int u = 0; u < 8; u++) {
        float vv = sK[swf1(j, tv_ + 16 * u)];
        accD[0][u] += tb.x * vv; accD[1][u] += tb.y * vv;
        accD[2][u] += tb.z * vv; accD[3][u] += tb.w * vv;
      }
    }
    size_t base = (size_t)ch * NBIG;
    #pragma unroll
    for (int r = 0; r < 4; r++)
      #pragma unroll
      for (int u = 0; u < 8; u++)
        D0p[base + (i04 * 4 + r) * 128 + tv_ + 16 * u] = accD[r][u];
  }
}

// ---------------------------------------------------------------------------
// phaseb v4: 256 blocks, XCD-swizzled so 4 sibling v-quarter blocks of one
// head share blk%8 (same XCD L2 -> fetch dedup). Kd LDS layout XOR-swizzled
// (row stride 128 was 8x bank-conflicted). D written over Kc rows in C-matrix.
// ---------------------------------------------------------------------------
__global__ __launch_bounds__(256) void phaseb_kernel(
    const float* __restrict__ rec_state, const float* __restrict__ Qn,
    const float* __restrict__ Kn, const float* __restrict__ G_buf,
    float* __restrict__ KcD, const float* __restrict__ D0p,
    float* __restrict__ Oq_buf, float* __restrict__ final_state)
{
  __shared__ float sS[128 * 32];    // state [k][v]
  __shared__ float sKT[128 * 64];   // Kc^T [k][i]; then Kd (swizzled) [i][k]
  __shared__ float sQT[128 * 64];   // Qb^T [k][i]
  __shared__ float sD[64 * 32];     // D [i][v]

  const int blk = blockIdx.x;       // xcd | vq<<3 | g<<5
  const int bh = (blk & 7) | ((blk >> 5) << 3);
  const int vq = (blk >> 3) & 3;
  const int b = bh >> 5, hv = bh & 31, hk = hv >> 1;
  const int t = threadIdx.x;
  const int vbase = vq * 32;
  const float* gG = G_buf + (size_t)bh * S_;

  #pragma unroll
  for (int u = 0; u < 4; u++) {
    int idx = u * 256 + t;
    int k = idx >> 3;
    int v4 = (idx & 7) * 4;
    *(float4*)(&sS[k * 32 + v4]) =
        *(const float4*)(&rec_state[((size_t)bh * 128 + k) * 128 + vbase + v4]);
  }
  __syncthreads();

  const int si = t & 63, skq = t >> 6;
  const int ti = t >> 3;
  const int tv = t & 7;
  const int tk = t >> 3;

  for (int c = 0; c < NC_; c++) {
    const size_t ch = (size_t)bh * NC_ + c;
    const int s0 = c * CS_;
    const float GC = gG[s0 + 63];
    const float eGC = __expf(GC);

    // ---- stage Kc^T and Qb^T = e^{G_i} Q^T ----
    {
      float eGi = __expf(gG[s0 + si]);
      const float* kcRow = KcD + ch * NBIG + si * 128 + skq * 32;
      const float* qRow  = Qn + ((size_t)(b * HK_ + hk) * S_ + s0 + si) * DK_ + skq * 32;
      #pragma unroll
      for (int u = 0; u < 8; u++) {
        float4 kc = *(const float4*)(kcRow + u * 4);
        float4 qv = *(const float4*)(qRow + u * 4);
        int kk = skq * 32 + u * 4;
        sKT[(kk + 0) * 64 + si] = kc.x; sKT[(kk + 1) * 64 + si] = kc.y;
        sKT[(kk + 2) * 64 + si] = kc.z; sKT[(kk + 3) * 64 + si] = kc.w;
        sQT[(kk + 0) * 64 + si] = qv.x * eGi; sQT[(kk + 1) * 64 + si] = qv.y * eGi;
        sQT[(kk + 2) * 64 + si] = qv.z * eGi; sQT[(kk + 3) * 64 + si] = qv.w * eGi;
      }
    }
    __syncthreads();

    // ---- D = D0 - Kc*S0 ; Oq = Qb*S0  (2i x 4v per thread) ----
    {
      float accD[2][4], accO[2][4];
      #pragma unroll
      for (int r = 0; r < 2; r++) {
        float4 d0 = *(const float4*)(&D0p[ch * NBIG + (size_t)(ti * 2 + r) * 128 + vbase + tv * 4]);
        accD[r][0] = d0.x; accD[r][1] = d0.y; accD[r][2] = d0.z; accD[r][3] = d0.w;
        accO[r][0] = accO[r][1] = accO[r][2] = accO[r][3] = 0.f;
      }
      for (int k = 0; k < 128; k++) {
        float2 kc = *(const float2*)(&sKT[k * 64 + ti * 2]);
        float2 qb = *(const float2*)(&sQT[k * 64 + ti * 2]);
        float4 sv = *(const float4*)(&sS[k * 32 + tv * 4]);
        accD[0][0] -= kc.x * sv.x; accD[0][1] -= kc.x * sv.y;
        accD[0][2] -= kc.x * sv.z; accD[0][3] -= kc.x * sv.w;
        accD[1][0] -= kc.y * sv.x; accD[1][1] -= kc.y * sv.y;
        accD[1][2] -= kc.y * sv.z; accD[1][3] -= kc.y * sv.w;
        accO[0][0] += qb.x * sv.x; accO[0][1] += qb.x * sv.y;
        accO[0][2] += qb.x * sv.z; accO[0][3] += qb.x * sv.w;
        accO[1][0] += qb.y * sv.x; accO[1][1] += qb.y * sv.y;
        accO[1][2] += qb.y * sv.z; accO[1][3] += qb.y * sv.w;
      }
      #pragma unroll
      for (int r = 0; r < 2; r++) {
        int i = ti * 2 + r;
        float4 dv = make_float4(accD[r][0], accD[r][1], accD[r][2], accD[r][3]);
        float4 ov = make_float4(accO[r][0], accO[r][1], accO[r][2], accO[r][3]);
        *(float4*)(&sD[i * 32 + tv * 4]) = dv;
        *(float4*)(&KcD[ch * NBIG + (size_t)i * 128 + vbase + tv * 4]) = dv;  // D over Kc
        *(float4*)(&Oq_buf[ch * 8192 + (size_t)i * 128 + vbase + tv * 4]) = ov;
      }
    }
    __syncthreads();

    // ---- stage Kd[i][k] = e^{GC-G_i} K[i][k], XOR-swizzled k-groups ----
    {
      float sc = __expf(GC - gG[s0 + si]);
      const float* kRow = Kn + ((size_t)(b * HK_ + hk) * S_ + s0 + si) * DK_ + skq * 32;
      #pragma unroll
      for (int u = 0; u < 8; u++) {
        float4 x = *(const float4*)(kRow + u * 4);
        x.x *= sc; x.y *= sc; x.z *= sc; x.w *= sc;
        int kg = skq * 8 + u;                       // k-group 0..31
        *(float4*)(&sKT[si * 128 + 4 * (kg ^ (si & 31))]) = x;
      }
    }
    __syncthreads();

    // ---- S <- e^{GC} S + Kd^T D  (4k x 4v per thread) ----
    {
      float acc[4][4];
      #pragma unroll
      for (int r = 0; r < 4; r++)
        acc[r][0] = acc[r][1] = acc[r][2] = acc[r][3] = 0.f;
      for (int i = 0; i < 64; i++) {
        float4 d  = *(const float4*)(&sD[i * 32 + tv * 4]);
        float4 ka = *(const float4*)(&sKT[i * 128 + 4 * (tk ^ (i & 31))]);
        acc[0][0] += ka.x * d.x; acc[0][1] += ka.x * d.y;
        acc[0][2] += ka.x * d.z; acc[0][3] += ka.x * d.w;
        acc[1][0] += ka.y * d.x; acc[1][1] += ka.y * d.y;
        acc[1][2] += ka.y * d.z; acc[1][3] += ka.y * d.w;
        acc[2][0] += ka.z * d.x; acc[2][1] += ka.z * d.y;
        acc[2][2] += ka.z * d.z; acc[2][3] += ka.z * d.w;
        acc[3][0] += ka.w * d.x; acc[3][1] += ka.w * d.y;
        acc[3][2] += ka.w * d.z; acc[3][3] += ka.w * d.w;
      }
      #pragma unroll
      for (int r = 0; r < 4; r++) {
        int k = tk * 4 + r;
        float4 s = *(const float4*)(&sS[k * 32 + tv * 4]);
        s.x = s.x * eGC + acc[r][0]; s.y = s.y * eGC + acc[r][1];
        s.z = s.z * eGC + acc[r][2]; s.w = s.w * eGC + acc[r][3];
        *(float4*)(&sS[k * 32 + tv * 4]) = s;
      }
    }
    __syncthreads();
  }

  #pragma unroll
  for (int u = 0; u < 4; u++) {
    int idx = u * 256 + t;
    int k = idx >> 3;
    int v4 = (idx & 7) * 4;
    *(float4*)(&final_state[((size_t)bh * 128 + k) * 128 + vbase + v4]) =
        *(const float4*)(&sS[k * 32 + v4]);
  }
}

// ---------------------------------------------------------------------------
// phasec: O = Oq + M*D, RMS-norm + weight + silu(z) gate -> bf16 zg
// D read from C-matrix rows (stride NBIG); z from C-matrix cols 8192..12287.
// ---------------------------------------------------------------------------
__global__ __launch_bounds__(128) void phasec_kernel(
    const float* __restrict__ KcD, const float* __restrict__ Oq_buf,
    const float* __restrict__ M_buf, const float* __restrict__ norm_weight,
    const float* __restrict__ Cbig, ushort* __restrict__ zg_bf)
{
  __shared__ float sM[4096];
  __shared__ float red[2][2];
  int ch = blockIdx.x;
  int bh = ch / NC_, c = ch % NC_;
  int b = bh >> 5, hv = bh & 31;
  int s0 = c * CS_;
  int v = threadIdx.x;

  float Dr[64];
  #pragma unroll
  for (int j = 0; j < 64; j++) Dr[j] = KcD[(size_t)ch * NBIG + j * 128 + v];
  {
    const float4* src = (const float4*)(M_buf + (size_t)ch * 4096);
    #pragma unroll
    for (int u = 0; u < 8; u++) ((float4*)sM)[u * 128 + v] = src[u * 128 + v];
  }
  __syncthreads();
  float nw = norm_weight[v];

  for (int i = 0; i < 64; i++) {
    float o = Oq_buf[(size_t)ch * 8192 + i * 128 + v];
    const float4* mr = (const float4*)(sM + i * 64);
    #pragma unroll
    for (int j4 = 0; j4 < 16; j4++) {
      float4 m = mr[j4];
      o += m.x * Dr[4 * j4] + m.y * Dr[4 * j4 + 1] +
           m.z * Dr[4 * j4 + 2] + m.w * Dr[4 * j4 + 3];
    }
    float p = o * o;
    #pragma unroll
    for (int off = 32; off > 0; off >>= 1) p += __shfl_xor(p, off);
    if ((v & 63) == 0) red[i & 1][v >> 6] = p;
    __syncthreads();
    float var = (red[i & 1][0] + red[i & 1][1]) * (1.f / 128.f);
    float xn = o * rsqrtf(var + 1e-6f) * nw;
    float zv = Cbig[((size_t)(b * S_ + s0 + i)) * NBIG + 8192 + hv * DV_ + v];
    zg_bf[((size_t)(b * S_ + s0 + i)) * VALDIM_ + hv * DV_ + v] =
        f2bf_rne(xn * (zv / (1.f + __expf(-zv))));
  }
}

// ---------------------------------------------------------------------------
extern "C" void kernel_launch(void* const* d_in, const int* in_sizes, int n_in,
                              void* d_out, int out_size, void* d_ws, size_t ws_size,
                              hipStream_t stream)
{
  const float* hs          = (const float*)d_in[0];
  const float* conv_state  = (const float*)d_in[1];
  const float* rec_state   = (const float*)d_in[2];
  const float* W_qkv       = (const float*)d_in[3];
  const float* W_z         = (const float*)d_in[4];
  const float* W_b         = (const float*)d_in[5];
  const float* W_a         = (const float*)d_in[6];
  const float* conv_w      = (const float*)d_in[7];
  const float* dt_bias     = (const float*)d_in[8];
  const float* A_log       = (const float*)d_in[9];
  const float* norm_weight = (const float*)d_in[10];
  const float* W_out       = (const float*)d_in[11];

  float* out       = (float*)d_out;                      // (B,S,H)
  float* out_conv  = out + (size_t)B_ * S_ * H_;         // (B,C,3)
  float* out_state = out_conv + (size_t)B_ * CC_ * 3;    // (B,HV,DK,DV)

  float* ws = (float*)d_ws;
  // ---- workspace plan (floats), max offset 46,596,096 < proven 50,659,328 ----
  float* Cbig = ws;                            // (2048, 12416) = 25,427,968
  // After prep: Kc chunk ch -> Cbig row ch (cols 0..8191); D0 -> row 1024+ch.
  float* KcD  = Cbig;
  float* D0p  = Cbig + (size_t)1024 * NBIG;
  float* g_buf    = ws + 25427968;             // 65,536
  float* beta_buf = ws + 25493504;             // 65,536
  float* G_buf    = ws + 25559040;             // 65,536
  float* Qn       = ws + 25624576;             // 4,194,304
  float* Kn       = ws + 29818880;             // 4,194,304
  float* Vb       = ws + 34013184;             // 8,388,608
  float* M_buf    = ws + 42401792;             // 4,194,304 (end 46,596,096)
  float* Oq_buf   = Vb;                        // alias (Vb dead after cp)

  // bf16 regions aliasing dead fp32 regions (time-ordered):
  ushort* Wcat_bf = (ushort*)(ws + 25427968);  // 25.4M ushorts; dead after GEMM1
  ushort* hs_bf   = (ushort*)(ws + 38141952);  // 4.2M ushorts; dead after GEMM1
  ushort* zg_bf   = (ushort*)Qn;               // written by phasec (Qn dead)
  ushort* Wout_bf = (ushort*)Kn;               // written after phaseb (Kn dead)

  const int M = B_ * S_;  // 2048

  // 0. converts
  f2bf_kernel<<<(M * H_) / 1024, 256, 0, stream>>>(hs, hs_bf, M * H_);
  wcat_kernel<<<(NBIG * H_) / 1024, 256, 0, stream>>>(W_qkv, W_z, W_b, W_a, Wcat_bf);
  // 1. fused qkv|z|b|a GEMM -> Cbig
  gemm_bf16_nt<<<dim3(NBIG / 128, M / 128), 256, 0, stream>>>(hs_bf, Wcat_bf, Cbig, M, NBIG, H_);
  // 2. conv_state_new output
  convstate_kernel<<<(B_ * CC_ * 3 + 255) / 256, 256, 0, stream>>>(Cbig, out_conv);
  // 3. conv+silu+l2norm -> Qn,Kn,Vb ; gates
  prep_qkv<<<dim3(64, S_, B_), 128, 0, stream>>>(Cbig, conv_state, conv_w, Qn, Kn, Vb);
  prep_gb<<<(B_ * HV_ * S_ + 255) / 256, 256, 0, stream>>>(Cbig, A_log, dt_bias, g_buf, beta_buf);
  // 4. per-chunk matrices (Kc/D0 into dead qkv columns of Cbig rows)
  cp_kernel<<<B_ * HV_ * NC_, 256, 0, stream>>>(Qn, Kn, Vb, g_buf, beta_buf,
                                                G_buf, M_buf, KcD, D0p);
  // 5. sequential chunk recurrence (XCD-swizzled)
  phaseb_kernel<<<B_ * HV_ * 4, 256, 0, stream>>>(rec_state, Qn, Kn, G_buf,
                                                  KcD, D0p, Oq_buf, out_state);
  // 6. W_out convert (Kn dead now) + intra-chunk output/RMS/gate -> bf16
  f2bf_kernel<<<(H_ * VALDIM_) / 1024, 256, 0, stream>>>(W_out, Wout_bf, H_ * VALDIM_);
  phasec_kernel<<<B_ * HV_ * NC_, 128, 0, stream>>>(KcD, Oq_buf, M_buf,
                                                    norm_weight, Cbig, zg_bf);
  // 7. output GEMM
  gemm_bf16_nt<<<dim3(H_ / 128, M / 128), 256, 0, stream>>>(zg_bf, Wout_bf, out, M, H_, VALDIM_);
}

// Round 7
// 1045.992 us; speedup vs baseline: 6.9053x; 1.0090x over previous
//
#include <hip/hip_runtime.h>
#include <cstdint>
#include <cstddef>

#define B_ 2
#define S_ 1024
#define H_ 2048
#define HV_ 32
#define HK_ 16
#define DK_ 128
#define DV_ 128
#define CC_ 8192
#define KEYDIM_ 2048
#define VALDIM_ 4096
#define NC_ 16          // chunks
#define CS_ 64          // chunk size
#define NBIG 12416      // fused GEMM1 N: 8192 qkv + 4096 z + 32 b + 32 a + 64 pad

typedef __attribute__((ext_vector_type(8))) short bf16x8;
typedef __attribute__((ext_vector_type(4))) float f32x4;

__device__ __forceinline__ ushort f2bf_rne(float x) {
  union { float f; uint32_t u; } c; c.f = x;
  uint32_t u = c.u + 0x7FFFu + ((c.u >> 16) & 1u);
  return (ushort)(u >> 16);
}

// async 16B global->LDS (DMA; LDS dest = wave-uniform base + lane*16)
__device__ __forceinline__ void gld16(const void* g, void* l) {
  __builtin_amdgcn_global_load_lds(
      (const __attribute__((address_space(1))) void*)g,
      (__attribute__((address_space(3))) void*)l, 16, 0, 0);
}

// ---------------------------------------------------------------------------
// fp32 -> bf16 convert (n multiple of 1024)
// ---------------------------------------------------------------------------
__global__ void f2bf_kernel(const float* __restrict__ in, ushort* __restrict__ out, int n) {
  int i = (blockIdx.x * 256 + threadIdx.x) * 4;
  if (i >= n) return;
  float4 v = *(const float4*)(in + i);
  ushort4 o;
  o.x = f2bf_rne(v.x); o.y = f2bf_rne(v.y);
  o.z = f2bf_rne(v.z); o.w = f2bf_rne(v.w);
  *(ushort4*)(out + i) = o;
}

// ---------------------------------------------------------------------------
// wcat: build concatenated bf16 weight (NBIG, H): [W_qkv; W_z; W_b; W_a; 0]
// ---------------------------------------------------------------------------
__global__ void wcat_kernel(const float* __restrict__ Wqkv, const float* __restrict__ Wz,
                            const float* __restrict__ Wb, const float* __restrict__ Wa,
                            ushort* __restrict__ out) {
  int i = (blockIdx.x * 256 + threadIdx.x) * 4;
  if (i >= NBIG * H_) return;
  int n = i >> 11;           // / H_
  int k = i & (H_ - 1);
  float4 v = make_float4(0.f, 0.f, 0.f, 0.f);
  if (n < 8192)       v = *(const float4*)(Wqkv + (size_t)n * H_ + k);
  else if (n < 12288) v = *(const float4*)(Wz + (size_t)(n - 8192) * H_ + k);
  else if (n < 12320) v = *(const float4*)(Wb + (size_t)(n - 12288) * H_ + k);
  else if (n < 12352) v = *(const float4*)(Wa + (size_t)(n - 12320) * H_ + k);
  ushort4 o;
  o.x = f2bf_rne(v.x); o.y = f2bf_rne(v.y);
  o.z = f2bf_rne(v.z); o.w = f2bf_rne(v.w);
  *(ushort4*)(out + i) = o;
}

// ---------------------------------------------------------------------------
// bf16 MFMA GEMM (NT): C[m][n] = sum_k A[m][k]*B[n][k]. M,N,K % 128 == 0.
// 128x128 tile, BK=32, global_load_lds width-16, fragment-ordered LDS.
// Grid: (M/128, N/128) — blockIdx.x = m-tile (FASTEST in dispatch), so all
// m-tiles sharing one B n-tile are co-resident -> B fetched from HBM ~once.
// ---------------------------------------------------------------------------
__global__ __launch_bounds__(256) void gemm_bf16_nt(
    const ushort* __restrict__ A, const ushort* __restrict__ B,
    float* __restrict__ C, int M, int N, int K)
{
  __shared__ ushort sA[8192];
  __shared__ ushort sB[8192];
  int t = threadIdx.x;
  int wave = t >> 6, lane = t & 63;
  int wm = wave >> 1, wn = wave & 1;
  int lrow = lane & 15, quad = lane >> 4;
  int mt = blockIdx.x, nt = blockIdx.y;

  f32x4 acc[4][4];
  #pragma unroll
  for (int i = 0; i < 4; i++)
    #pragma unroll
    for (int j = 0; j < 4; j++)
      #pragma unroll
      for (int r = 0; r < 4; r++) acc[i][j][r] = 0.f;

  int seg0 = wave * 2, seg1 = wave * 2 + 1;
  const ushort* aSrc0 = A + (size_t)(mt * 128 + seg0 * 16 + lrow) * K + quad * 8;
  const ushort* aSrc1 = A + (size_t)(mt * 128 + seg1 * 16 + lrow) * K + quad * 8;
  const ushort* bSrc0 = B + (size_t)(nt * 128 + seg0 * 16 + lrow) * K + quad * 8;
  const ushort* bSrc1 = B + (size_t)(nt * 128 + seg1 * 16 + lrow) * K + quad * 8;
  ushort* ldsA0 = sA + seg0 * 512;
  ushort* ldsA1 = sA + seg1 * 512;
  ushort* ldsB0 = sB + seg0 * 512;
  ushort* ldsB1 = sB + seg1 * 512;

  for (int k0 = 0; k0 < K; k0 += 32) {
    gld16(aSrc0 + k0, ldsA0);
    gld16(aSrc1 + k0, ldsA1);
    gld16(bSrc0 + k0, ldsB0);
    gld16(bSrc1 + k0, ldsB1);
    __syncthreads();
    bf16x8 af[4], bfr[4];
    #pragma unroll
    for (int i = 0; i < 4; i++)
      af[i] = *(const bf16x8*)(sA + (wm * 4 + i) * 512 + lane * 8);
    #pragma unroll
    for (int j = 0; j < 4; j++)
      bfr[j] = *(const bf16x8*)(sB + (wn * 4 + j) * 512 + lane * 8);
    #pragma unroll
    for (int i = 0; i < 4; i++)
      #pragma unroll
      for (int j = 0; j < 4; j++)
        acc[i][j] = __builtin_amdgcn_mfma_f32_16x16x32_bf16(af[i], bfr[j], acc[i][j], 0, 0, 0);
    __syncthreads();
  }

  #pragma unroll
  for (int i = 0; i < 4; i++) {
    int m_base = mt * 128 + wm * 64 + i * 16 + quad * 4;
    #pragma unroll
    for (int j = 0; j < 4; j++) {
      int n = nt * 128 + wn * 64 + j * 16 + lrow;
      #pragma unroll
      for (int rr = 0; rr < 4; rr++)
        C[(size_t)(m_base + rr) * N + n] = acc[i][j][rr];
    }
  }
}

// ---------------------------------------------------------------------------
// conv_state_new[b][c][j] = mixed_qkv[b][S-3+j][c]  (from (B,S,NBIG) C-matrix)
// ---------------------------------------------------------------------------
__global__ void convstate_kernel(const float* __restrict__ Cbig,
                                 float* __restrict__ out)
{
  int idx = blockIdx.x * blockDim.x + threadIdx.x;
  if (idx >= B_ * CC_ * 3) return;
  int j = idx % 3;
  int c = (idx / 3) % CC_;
  int b = idx / (3 * CC_);
  out[idx] = Cbig[((size_t)(b * S_ + (S_ - 3 + j))) * NBIG + c];
}

// ---------------------------------------------------------------------------
// prep_qkv: conv(K=4)+silu; l2norm q/k heads. qkv read from C-matrix cols 0..8191
// ---------------------------------------------------------------------------
__global__ __launch_bounds__(128) void prep_qkv(
    const float* __restrict__ Cbig, const float* __restrict__ conv_state,
    const float* __restrict__ conv_w,
    float* __restrict__ Qn, float* __restrict__ Kn, float* __restrict__ Vb)
{
  int group = blockIdx.x, s = blockIdx.y, b = blockIdx.z;
  int t = threadIdx.x;
  int c = group * 128 + t;
  float acc = 0.f;
  #pragma unroll
  for (int kk = 0; kk < 4; kk++) {
    int sp = s - 3 + kk;
    float x = (sp < 0) ? conv_state[((size_t)(b * CC_ + c)) * 3 + (3 + sp)]
                       : Cbig[((size_t)(b * S_ + sp)) * NBIG + c];
    acc += conv_w[c * 4 + kk] * x;
  }
  float val = acc / (1.f + __expf(-acc));   // silu

  if (group < 32) {
    __shared__ float red2[2];
    float p = val * val;
    #pragma unroll
    for (int off = 32; off > 0; off >>= 1) p += __shfl_xor(p, off);
    if ((t & 63) == 0) red2[t >> 6] = p;
    __syncthreads();
    float r = rsqrtf(red2[0] + red2[1] + 1e-6f);
    if (group < 16) {
      r *= 0.08838834764831845f;  // 128^-0.5
      Qn[(((size_t)(b * HK_ + group)) * S_ + s) * DK_ + t] = val * r;
    } else {
      Kn[(((size_t)(b * HK_ + (group - 16))) * S_ + s) * DK_ + t] = val * r;
    }
  } else {
    Vb[(((size_t)(b * HV_ + (group - 32))) * S_ + s) * DV_ + t] = val;
  }
}

// ---------------------------------------------------------------------------
// prep_gb: g/beta from C-matrix cols 12288..12351
// ---------------------------------------------------------------------------
__global__ void prep_gb(const float* __restrict__ Cbig,
                        const float* __restrict__ A_log, const float* __restrict__ dt_bias,
                        float* __restrict__ g_buf, float* __restrict__ beta_buf)
{
  int idx = blockIdx.x * blockDim.x + threadIdx.x;
  if (idx >= B_ * HV_ * S_) return;
  int s = idx & (S_ - 1);
  int hv = (idx >> 10) & 31;
  int b = idx >> 15;
  float bv = Cbig[((size_t)(b * S_ + s)) * NBIG + 12288 + hv];
  float av = Cbig[((size_t)(b * S_ + s)) * NBIG + 12320 + hv];
  float x = av + dt_bias[hv];
  float sp = (x > 20.f) ? x : log1pf(__expf(x));
  g_buf[idx] = -__expf(A_log[hv]) * sp;
  beta_buf[idx] = 1.f / (1.f + __expf(-bv));
}

// ---------------------------------------------------------------------------
// cp_kernel: per (b,hv,chunk). G cumsum, M, A, Tinv, Kc, D0.
// Kc chunk ch -> KcD + ch*NBIG (C-matrix row ch, cols 0..8191)
// D0 chunk ch -> D0p + ch*NBIG (C-matrix row 1024+ch)
// ---------------------------------------------------------------------------
__device__ __forceinline__ int swf4(int r, int f) { return r * 32 + (f ^ (r & 31)); }
__device__ __forceinline__ int swf1(int r, int k) {
  return r * 128 + 4 * ((k >> 2) ^ (r & 31)) + (k & 3);
}

__global__ __launch_bounds__(256) void cp_kernel(
    const float* __restrict__ Qn, const float* __restrict__ Kn,
    const float* __restrict__ Vb,
    const float* __restrict__ g_buf, const float* __restrict__ beta_buf,
    float* __restrict__ G_buf, float* __restrict__ M_buf,
    float* __restrict__ KcD, float* __restrict__ D0p)
{
  __shared__ float sK[64 * 128];
  __shared__ float sX[32 * 128];
  __shared__ float sT[64 * 64];
  float* sG  = sT;
  float* sBe = sT + 64;
  float* sA  = sX;
  float* tTw = sX;
  float* tTb = sX;
  float4* sK4 = (float4*)sK;
  float4* sX4 = (float4*)sX;

  const int ch = blockIdx.x;
  const int bh = ch / NC_, c = ch % NC_;
  const int b = bh >> 5, hv = bh & 31, hk = hv >> 1;
  const int s0 = c * CS_;
  const int t = threadIdx.x;
  const size_t gOff = (size_t)bh * S_ + s0;

  float Gw0 = 0.f, Bw0 = 0.f;
  if (t < 64) {
    float gi = g_buf[gOff + t];
    Gw0 = gi;
    #pragma unroll
    for (int off = 1; off < 64; off <<= 1) {
      float o = __shfl_up(Gw0, off);
      if (t >= off) Gw0 += o;
    }
    G_buf[gOff + t] = Gw0;
    sG[t] = Gw0;
    Bw0 = beta_buf[gOff + t];
    sBe[t] = Bw0;
  }
  {
    const float4* src = (const float4*)(Kn + ((size_t)(b * HK_ + hk) * S_ + s0) * DK_);
    #pragma unroll
    for (int u = 0; u < 8; u++) {
      int idx = u * 256 + t;
      sK4[swf4(idx >> 5, idx & 31)] = src[idx];
    }
  }
  __syncthreads();

  const float4* qsrc = (const float4*)(Qn + ((size_t)(b * HK_ + hk) * S_ + s0) * DK_);
  {
    int ti2 = t >> 4, tj = t & 15;
    for (int h = 0; h < 2; h++) {
      #pragma unroll
      for (int u = 0; u < 4; u++) {
        int idx = u * 256 + t;
        sX4[swf4(idx >> 5, idx & 31)] = qsrc[h * 1024 + idx];
      }
      __syncthreads();
      float accM[2][4];
      #pragma unroll
      for (int a = 0; a < 2; a++)
        #pragma unroll
        for (int e = 0; e < 4; e++) accM[a][e] = 0.f;
      for (int k4 = 0; k4 < 32; k4++) {
        float4 qv[2], kv[4];
        qv[0] = sX4[swf4(ti2, k4)];
        qv[1] = sX4[swf4(ti2 + 16, k4)];
        #pragma unroll
        for (int e = 0; e < 4; e++) kv[e] = sK4[swf4(tj + 16 * e, k4)];
        #pragma unroll
        for (int a = 0; a < 2; a++)
          #pragma unroll
          for (int e = 0; e < 4; e++)
            accM[a][e] += qv[a].x * kv[e].x + qv[a].y * kv[e].y +
                          qv[a].z * kv[e].z + qv[a].w * kv[e].w;
      }
      #pragma unroll
      for (int a = 0; a < 2; a++) {
        int iG = h * 32 + ti2 + 16 * a;
        float Gi = sG[iG];
        #pragma unroll
        for (int e = 0; e < 4; e++) {
          int j = tj + 16 * e;
          float m = (j <= iG) ? __expf(Gi - sG[j]) * accM[a][e] : 0.f;
          M_buf[(size_t)ch * 4096 + iG * 64 + j] = m;
        }
      }
      __syncthreads();
    }
  }

  {
    int ti = t >> 4, tj = t & 15;
    float accA[4][4];
    #pragma unroll
    for (int a = 0; a < 4; a++)
      #pragma unroll
      for (int e = 0; e < 4; e++) accA[a][e] = 0.f;
    for (int k4 = 0; k4 < 32; k4++) {
      float4 ki[4], kj[4];
      #pragma unroll
      for (int e = 0; e < 4; e++) {
        ki[e] = sK4[swf4(ti + 16 * e, k4)];
        kj[e] = sK4[swf4(tj + 16 * e, k4)];
      }
      #pragma unroll
      for (int a = 0; a < 4; a++)
        #pragma unroll
        for (int e = 0; e < 4; e++)
          accA[a][e] += ki[a].x * kj[e].x + ki[a].y * kj[e].y +
                        ki[a].z * kj[e].z + ki[a].w * kj[e].w;
    }
    float resA[4][4];
    #pragma unroll
    for (int a = 0; a < 4; a++) {
      int i = ti + 16 * a;
      float Gi = sG[i], Bi = sBe[i];
      #pragma unroll
      for (int e = 0; e < 4; e++) {
        int j = tj + 16 * e;
        resA[a][e] = (j < i) ? Bi * __expf(Gi - sG[j]) * accA[a][e] : 0.f;
      }
    }
    __syncthreads();
    #pragma unroll
    for (int a = 0; a < 4; a++)
      #pragma unroll
      for (int e = 0; e < 4; e++)
        sA[(ti + 16 * a) * 64 + (tj + 16 * e)] = resA[a][e];
  }
  __syncthreads();

  if (t < 64) {
    sT[t] = (t == 0) ? 1.f : 0.f;
    for (int i = 1; i < 64; i++) {
      float acc = 0.f;
      for (int j = 0; j < i; j++) acc += sA[i * 64 + j] * sT[j * 64 + t];
      sT[i * 64 + t] = ((t == i) ? 1.f : 0.f) - acc;
    }
    float w = Bw0 * __expf(Gw0);
    for (int j = 0; j < 64; j++) {
      float wj = __shfl(w, j);
      tTw[j * 64 + t] = sT[t * 64 + j] * wj;
    }
  }
  __syncthreads();

  {
    int i04 = t >> 4, tk = t & 15;
    float accK[4][8];
    #pragma unroll
    for (int r = 0; r < 4; r++)
      #pragma unroll
      for (int u = 0; u < 8; u++) accK[r][u] = 0.f;
    for (int j = 0; j < 64; j++) {
      float4 tw = ((float4*)tTw)[j * 16 + i04];
      #pragma unroll
      for (int u = 0; u < 8; u++) {
        float kv = sK[swf1(j, tk + 16 * u)];
        accK[0][u] += tw.x * kv; accK[1][u] += tw.y * kv;
        accK[2][u] += tw.z * kv; accK[3][u] += tw.w * kv;
      }
    }
    size_t base = (size_t)ch * NBIG;
    #pragma unroll
    for (int r = 0; r < 4; r++)
      #pragma unroll
      for (int u = 0; u < 8; u++)
        KcD[base + (i04 * 4 + r) * 128 + tk + 16 * u] = accK[r][u];
  }
  __syncthreads();

  if (t < 64) {
    for (int j = 0; j < 64; j++) {
      float bj = __shfl(Bw0, j);
      tTb[j * 64 + t] = sT[t * 64 + j] * bj;
    }
  }
  {
    const float4* src = (const float4*)(Vb + ((size_t)bh * S_ + s0) * DV_);
    #pragma unroll
    for (int u = 0; u < 8; u++) {
      int idx = u * 256 + t;
      sK4[swf4(idx >> 5, idx & 31)] = src[idx];
    }
  }
  __syncthreads();

  {
    int i04 = t >> 4, tv_ = t & 15;
    float accD[4][8];
    #pragma unroll
    for (int r = 0; r < 4; r++)
      #pragma unroll
      for (int u = 0; u < 8; u++) accD[r][u] = 0.f;
    for (int j = 0; j < 64; j++) {
      float4 tb = ((float4*)tTb)[j * 16 + i04];
      #pragma unroll
      for (int u = 0; u < 8; u++) {
        float vv = sK[swf1(j, tv_ + 16 * u)];
        accD[0][u] += tb.x * vv; accD[1][u] += tb.y * vv;
        accD[2][u] += tb.z * vv; accD[3][u] += tb.w * vv;
      }
    }
    size_t base = (size_t)ch * NBIG;
    #pragma unroll
    for (int r = 0; r < 4; r++)
      #pragma unroll
      for (int u = 0; u < 8; u++)
        D0p[base + (i04 * 4 + r) * 128 + tv_ + 16 * u] = accD[r][u];
  }
}

// ---------------------------------------------------------------------------
// phaseb v4: 256 blocks, XCD-swizzled so 4 sibling v-quarter blocks of one
// head share blk%8 (same XCD L2 -> fetch dedup). Kd LDS layout XOR-swizzled.
// D written over Kc rows in C-matrix.
// ---------------------------------------------------------------------------
__global__ __launch_bounds__(256) void phaseb_kernel(
    const float* __restrict__ rec_state, const float* __restrict__ Qn,
    const float* __restrict__ Kn, const float* __restrict__ G_buf,
    float* __restrict__ KcD, const float* __restrict__ D0p,
    float* __restrict__ Oq_buf, float* __restrict__ final_state)
{
  __shared__ float sS[128 * 32];    // state [k][v]
  __shared__ float sKT[128 * 64];   // Kc^T [k][i]; then Kd (swizzled) [i][k]
  __shared__ float sQT[128 * 64];   // Qb^T [k][i]
  __shared__ float sD[64 * 32];     // D [i][v]

  const int blk = blockIdx.x;       // xcd | vq<<3 | g<<5
  const int bh = (blk & 7) | ((blk >> 5) << 3);
  const int vq = (blk >> 3) & 3;
  const int b = bh >> 5, hv = bh & 31, hk = hv >> 1;
  const int t = threadIdx.x;
  const int vbase = vq * 32;
  const float* gG = G_buf + (size_t)bh * S_;

  #pragma unroll
  for (int u = 0; u < 4; u++) {
    int idx = u * 256 + t;
    int k = idx >> 3;
    int v4 = (idx & 7) * 4;
    *(float4*)(&sS[k * 32 + v4]) =
        *(const float4*)(&rec_state[((size_t)bh * 128 + k) * 128 + vbase + v4]);
  }
  __syncthreads();

  const int si = t & 63, skq = t >> 6;
  const int ti = t >> 3;
  const int tv = t & 7;
  const int tk = t >> 3;

  for (int c = 0; c < NC_; c++) {
    const size_t ch = (size_t)bh * NC_ + c;
    const int s0 = c * CS_;
    const float GC = gG[s0 + 63];
    const float eGC = __expf(GC);

    // ---- stage Kc^T and Qb^T = e^{G_i} Q^T ----
    {
      float eGi = __expf(gG[s0 + si]);
      const float* kcRow = KcD + ch * NBIG + si * 128 + skq * 32;
      const float* qRow  = Qn + ((size_t)(b * HK_ + hk) * S_ + s0 + si) * DK_ + skq * 32;
      #pragma unroll
      for (int u = 0; u < 8; u++) {
        float4 kc = *(const float4*)(kcRow + u * 4);
        float4 qv = *(const float4*)(qRow + u * 4);
        int kk = skq * 32 + u * 4;
        sKT[(kk + 0) * 64 + si] = kc.x; sKT[(kk + 1) * 64 + si] = kc.y;
        sKT[(kk + 2) * 64 + si] = kc.z; sKT[(kk + 3) * 64 + si] = kc.w;
        sQT[(kk + 0) * 64 + si] = qv.x * eGi; sQT[(kk + 1) * 64 + si] = qv.y * eGi;
        sQT[(kk + 2) * 64 + si] = qv.z * eGi; sQT[(kk + 3) * 64 + si] = qv.w * eGi;
      }
    }
    __syncthreads();

    // ---- D = D0 - Kc*S0 ; Oq = Qb*S0  (2i x 4v per thread) ----
    {
      float accD[2][4], accO[2][4];
      #pragma unroll
      for (int r = 0; r < 2; r++) {
        float4 d0 = *(const float4*)(&D0p[ch * NBIG + (size_t)(ti * 2 + r) * 128 + vbase + tv * 4]);
        accD[r][0] = d0.x; accD[r][1] = d0.y; accD[r][2] = d0.z; accD[r][3] = d0.w;
        accO[r][0] = accO[r][1] = accO[r][2] = accO[r][3] = 0.f;
      }
      for (int k = 0; k < 128; k++) {
        float2 kc = *(const float2*)(&sKT[k * 64 + ti * 2]);
        float2 qb = *(const float2*)(&sQT[k * 64 + ti * 2]);
        float4 sv = *(const float4*)(&sS[k * 32 + tv * 4]);
        accD[0][0] -= kc.x * sv.x; accD[0][1] -= kc.x * sv.y;
        accD[0][2] -= kc.x * sv.z; accD[0][3] -= kc.x * sv.w;
        accD[1][0] -= kc.y * sv.x; accD[1][1] -= kc.y * sv.y;
        accD[1][2] -= kc.y * sv.z; accD[1][3] -= kc.y * sv.w;
        accO[0][0] += qb.x * sv.x; accO[0][1] += qb.x * sv.y;
        accO[0][2] += qb.x * sv.z; accO[0][3] += qb.x * sv.w;
        accO[1][0] += qb.y * sv.x; accO[1][1] += qb.y * sv.y;
        accO[1][2] += qb.y * sv.z; accO[1][3] += qb.y * sv.w;
      }
      #pragma unroll
      for (int r = 0; r < 2; r++) {
        int i = ti * 2 + r;
        float4 dv = make_float4(accD[r][0], accD[r][1], accD[r][2], accD[r][3]);
        float4 ov = make_float4(accO[r][0], accO[r][1], accO[r][2], accO[r][3]);
        *(float4*)(&sD[i * 32 + tv * 4]) = dv;
        *(float4*)(&KcD[ch * NBIG + (size_t)i * 128 + vbase + tv * 4]) = dv;  // D over Kc
        *(float4*)(&Oq_buf[ch * 8192 + (size_t)i * 128 + vbase + tv * 4]) = ov;
      }
    }
    __syncthreads();

    // ---- stage Kd[i][k] = e^{GC-G_i} K[i][k], XOR-swizzled k-groups ----
    {
      float sc = __expf(GC - gG[s0 + si]);
      const float* kRow = Kn + ((size_t)(b * HK_ + hk) * S_ + s0 + si) * DK_ + skq * 32;
      #pragma unroll
      for (int u = 0; u < 8; u++) {
        float4 x = *(const float4*)(kRow + u * 4);
        x.x *= sc; x.y *= sc; x.z *= sc; x.w *= sc;
        int kg = skq * 8 + u;                       // k-group 0..31
        *(float4*)(&sKT[si * 128 + 4 * (kg ^ (si & 31))]) = x;
      }
    }
    __syncthreads();

    // ---- S <- e^{GC} S + Kd^T D  (4k x 4v per thread) ----
    {
      float acc[4][4];
      #pragma unroll
      for (int r = 0; r < 4; r++)
        acc[r][0] = acc[r][1] = acc[r][2] = acc[r][3] = 0.f;
      for (int i = 0; i < 64; i++) {
        float4 d  = *(const float4*)(&sD[i * 32 + tv * 4]);
        float4 ka = *(const float4*)(&sKT[i * 128 + 4 * (tk ^ (i & 31))]);
        acc[0][0] += ka.x * d.x; acc[0][1] += ka.x * d.y;
        acc[0][2] += ka.x * d.z; acc[0][3] += ka.x * d.w;
        acc[1][0] += ka.y * d.x; acc[1][1] += ka.y * d.y;
        acc[1][2] += ka.y * d.z; acc[1][3] += ka.y * d.w;
        acc[2][0] += ka.z * d.x; acc[2][1] += ka.z * d.y;
        acc[2][2] += ka.z * d.z; acc[2][3] += ka.z * d.w;
        acc[3][0] += ka.w * d.x; acc[3][1] += ka.w * d.y;
        acc[3][2] += ka.w * d.z; acc[3][3] += ka.w * d.w;
      }
      #pragma unroll
      for (int r = 0; r < 4; r++) {
        int k = tk * 4 + r;
        float4 s = *(const float4*)(&sS[k * 32 + tv * 4]);
        s.x = s.x * eGC + acc[r][0]; s.y = s.y * eGC + acc[r][1];
        s.z = s.z * eGC + acc[r][2]; s.w = s.w * eGC + acc[r][3];
        *(float4*)(&sS[k * 32 + tv * 4]) = s;
      }
    }
    __syncthreads();
  }

  #pragma unroll
  for (int u = 0; u < 4; u++) {
    int idx = u * 256 + t;
    int k = idx >> 3;
    int v4 = (idx & 7) * 4;
    *(float4*)(&final_state[((size_t)bh * 128 + k) * 128 + vbase + v4]) =
        *(const float4*)(&sS[k * 32 + v4]);
  }
}

// ---------------------------------------------------------------------------
// phasec: O = Oq + M*D, RMS-norm + weight + silu(z) gate -> bf16 zg
// ---------------------------------------------------------------------------
__global__ __launch_bounds__(128) void phasec_kernel(
    const float* __restrict__ KcD, const float* __restrict__ Oq_buf,
    const float* __restrict__ M_buf, const float* __restrict__ norm_weight,
    const float* __restrict__ Cbig, ushort* __restrict__ zg_bf)
{
  __shared__ float sM[4096];
  __shared__ float red[2][2];
  int ch = blockIdx.x;
  int bh = ch / NC_, c = ch % NC_;
  int b = bh >> 5, hv = bh & 31;
  int s0 = c * CS_;
  int v = threadIdx.x;

  float Dr[64];
  #pragma unroll
  for (int j = 0; j < 64; j++) Dr[j] = KcD[(size_t)ch * NBIG + j * 128 + v];
  {
    const float4* src = (const float4*)(M_buf + (size_t)ch * 4096);
    #pragma unroll
    for (int u = 0; u < 8; u++) ((float4*)sM)[u * 128 + v] = src[u * 128 + v];
  }
  __syncthreads();
  float nw = norm_weight[v];

  for (int i = 0; i < 64; i++) {
    float o = Oq_buf[(size_t)ch * 8192 + i * 128 + v];
    const float4* mr = (const float4*)(sM + i * 64);
    #pragma unroll
    for (int j4 = 0; j4 < 16; j4++) {
      float4 m = mr[j4];
      o += m.x * Dr[4 * j4] + m.y * Dr[4 * j4 + 1] +
           m.z * Dr[4 * j4 + 2] + m.w * Dr[4 * j4 + 3];
    }
    float p = o * o;
    #pragma unroll
    for (int off = 32; off > 0; off >>= 1) p += __shfl_xor(p, off);
    if ((v & 63) == 0) red[i & 1][v >> 6] = p;
    __syncthreads();
    float var = (red[i & 1][0] + red[i & 1][1]) * (1.f / 128.f);
    float xn = o * rsqrtf(var + 1e-6f) * nw;
    float zv = Cbig[((size_t)(b * S_ + s0 + i)) * NBIG + 8192 + hv * DV_ + v];
    zg_bf[((size_t)(b * S_ + s0 + i)) * VALDIM_ + hv * DV_ + v] =
        f2bf_rne(xn * (zv / (1.f + __expf(-zv))));
  }
}

// ---------------------------------------------------------------------------
extern "C" void kernel_launch(void* const* d_in, const int* in_sizes, int n_in,
                              void* d_out, int out_size, void* d_ws, size_t ws_size,
                              hipStream_t stream)
{
  const float* hs          = (const float*)d_in[0];
  const float* conv_state  = (const float*)d_in[1];
  const float* rec_state   = (const float*)d_in[2];
  const float* W_qkv       = (const float*)d_in[3];
  const float* W_z         = (const float*)d_in[4];
  const float* W_b         = (const float*)d_in[5];
  const float* W_a         = (const float*)d_in[6];
  const float* conv_w      = (const float*)d_in[7];
  const float* dt_bias     = (const float*)d_in[8];
  const float* A_log       = (const float*)d_in[9];
  const float* norm_weight = (const float*)d_in[10];
  const float* W_out       = (const float*)d_in[11];

  float* out       = (float*)d_out;                      // (B,S,H)
  float* out_conv  = out + (size_t)B_ * S_ * H_;         // (B,C,3)
  float* out_state = out_conv + (size_t)B_ * CC_ * 3;    // (B,HV,DK,DV)

  float* ws = (float*)d_ws;
  float* Cbig = ws;                            // (2048, 12416) = 25,427,968
  float* KcD  = Cbig;
  float* D0p  = Cbig + (size_t)1024 * NBIG;
  float* g_buf    = ws + 25427968;
  float* beta_buf = ws + 25493504;
  float* G_buf    = ws + 25559040;
  float* Qn       = ws + 25624576;
  float* Kn       = ws + 29818880;
  float* Vb       = ws + 34013184;
  float* M_buf    = ws + 42401792;
  float* Oq_buf   = Vb;

  ushort* Wcat_bf = (ushort*)(ws + 25427968);
  ushort* hs_bf   = (ushort*)(ws + 38141952);
  ushort* zg_bf   = (ushort*)Qn;
  ushort* Wout_bf = (ushort*)Kn;

  const int M = B_ * S_;  // 2048

  // 0. converts
  f2bf_kernel<<<(M * H_) / 1024, 256, 0, stream>>>(hs, hs_bf, M * H_);
  wcat_kernel<<<(NBIG * H_) / 1024, 256, 0, stream>>>(W_qkv, W_z, W_b, W_a, Wcat_bf);
  // 1. fused qkv|z|b|a GEMM -> Cbig (m-fastest dispatch for B-reuse)
  gemm_bf16_nt<<<dim3(M / 128, NBIG / 128), 256, 0, stream>>>(hs_bf, Wcat_bf, Cbig, M, NBIG, H_);
  // 2. conv_state_new output
  convstate_kernel<<<(B_ * CC_ * 3 + 255) / 256, 256, 0, stream>>>(Cbig, out_conv);
  // 3. conv+silu+l2norm -> Qn,Kn,Vb ; gates
  prep_qkv<<<dim3(64, S_, B_), 128, 0, stream>>>(Cbig, conv_state, conv_w, Qn, Kn, Vb);
  prep_gb<<<(B_ * HV_ * S_ + 255) / 256, 256, 0, stream>>>(Cbig, A_log, dt_bias, g_buf, beta_buf);
  // 4. per-chunk matrices
  cp_kernel<<<B_ * HV_ * NC_, 256, 0, stream>>>(Qn, Kn, Vb, g_buf, beta_buf,
                                                G_buf, M_buf, KcD, D0p);
  // 5. sequential chunk recurrence
  phaseb_kernel<<<B_ * HV_ * 4, 256, 0, stream>>>(rec_state, Qn, Kn, G_buf,
                                                  KcD, D0p, Oq_buf, out_state);
  // 6. W_out convert + intra-chunk output/RMS/gate -> bf16
  f2bf_kernel<<<(H_ * VALDIM_) / 1024, 256, 0, stream>>>(W_out, Wout_bf, H_ * VALDIM_);
  phasec_kernel<<<B_ * HV_ * NC_, 128, 0, stream>>>(KcD, Oq_buf, M_buf,
                                                    norm_weight, Cbig, zg_bf);
  // 7. output GEMM (m-fastest dispatch)
  gemm_bf16_nt<<<dim3(M / 128, H_ / 128), 256, 0, stream>>>(zg_bf, Wout_bf, out, M, H_, VALDIM_);
}

// Round 8
// 989.680 us; speedup vs baseline: 7.2982x; 1.0569x over previous
//
#include <hip/hip_runtime.h>
#include <cstdint>
#include <cstddef>

#define B_ 2
#define S_ 1024
#define H_ 2048
#define HV_ 32
#define HK_ 16
#define DK_ 128
#define DV_ 128
#define CC_ 8192
#define KEYDIM_ 2048
#define VALDIM_ 4096
#define NC_ 16          // chunks
#define CS_ 64          // chunk size
#define NBIG 12416      // fused GEMM1 N: 8192 qkv + 4096 z + 32 b + 32 a + 64 pad

typedef __attribute__((ext_vector_type(8))) short bf16x8;
typedef __attribute__((ext_vector_type(4))) float f32x4;

__device__ __forceinline__ ushort f2bf_rne(float x) {
  union { float f; uint32_t u; } c; c.f = x;
  uint32_t u = c.u + 0x7FFFu + ((c.u >> 16) & 1u);
  return (ushort)(u >> 16);
}

// async 16B global->LDS (DMA; LDS dest = wave-uniform base + lane*16)
__device__ __forceinline__ void gld16(const void* g, void* l) {
  __builtin_amdgcn_global_load_lds(
      (const __attribute__((address_space(1))) void*)g,
      (__attribute__((address_space(3))) void*)l, 16, 0, 0);
}

// ---------------------------------------------------------------------------
// fp32 -> bf16 convert (n multiple of 1024)
// ---------------------------------------------------------------------------
__global__ void f2bf_kernel(const float* __restrict__ in, ushort* __restrict__ out, int n) {
  int i = (blockIdx.x * 256 + threadIdx.x) * 4;
  if (i >= n) return;
  float4 v = *(const float4*)(in + i);
  ushort4 o;
  o.x = f2bf_rne(v.x); o.y = f2bf_rne(v.y);
  o.z = f2bf_rne(v.z); o.w = f2bf_rne(v.w);
  *(ushort4*)(out + i) = o;
}

// ---------------------------------------------------------------------------
// wcat: build concatenated bf16 weight (NBIG, H): [W_qkv; W_z; W_b; W_a; 0]
// ---------------------------------------------------------------------------
__global__ void wcat_kernel(const float* __restrict__ Wqkv, const float* __restrict__ Wz,
                            const float* __restrict__ Wb, const float* __restrict__ Wa,
                            ushort* __restrict__ out) {
  int i = (blockIdx.x * 256 + threadIdx.x) * 4;
  if (i >= NBIG * H_) return;
  int n = i >> 11;           // / H_
  int k = i & (H_ - 1);
  float4 v = make_float4(0.f, 0.f, 0.f, 0.f);
  if (n < 8192)       v = *(const float4*)(Wqkv + (size_t)n * H_ + k);
  else if (n < 12288) v = *(const float4*)(Wz + (size_t)(n - 8192) * H_ + k);
  else if (n < 12320) v = *(const float4*)(Wb + (size_t)(n - 12288) * H_ + k);
  else if (n < 12352) v = *(const float4*)(Wa + (size_t)(n - 12320) * H_ + k);
  ushort4 o;
  o.x = f2bf_rne(v.x); o.y = f2bf_rne(v.y);
  o.z = f2bf_rne(v.z); o.w = f2bf_rne(v.w);
  *(ushort4*)(out + i) = o;
}

// ---------------------------------------------------------------------------
// Double-buffered stage of one BK=64 tile half-pair (8 gld16 per wave).
// Fragment-ordered segments: h*4096 + seg*512 ushorts; seg = 16 rows.
// ---------------------------------------------------------------------------
__device__ __forceinline__ void stage_tile(
    const ushort* aS0, const ushort* aS1, const ushort* bS0, const ushort* bS1,
    ushort* ldsA, ushort* ldsB, int wave, int k0)
{
  #pragma unroll
  for (int h = 0; h < 2; h++) {
    gld16(aS0 + k0 + h * 32, ldsA + h * 4096 + (wave * 2 + 0) * 512);
    gld16(aS1 + k0 + h * 32, ldsA + h * 4096 + (wave * 2 + 1) * 512);
    gld16(bS0 + k0 + h * 32, ldsB + h * 4096 + (wave * 2 + 0) * 512);
    gld16(bS1 + k0 + h * 32, ldsB + h * 4096 + (wave * 2 + 1) * 512);
  }
}

// ---------------------------------------------------------------------------
// bf16 MFMA GEMM (NT): C[m][n] = sum_k A[m][k]*B[n][k]. M,N % 128, K % 64.
// 128x128 tile, BK=64, DOUBLE-BUFFERED: prefetch tile k+1 during compute of
// tile k -> global_load_lds latency hidden behind 32 MFMA; 1 barrier/iter.
// Grid (M/128, N/128), m-fastest for B-tile L2/L3 reuse.
// ---------------------------------------------------------------------------
__global__ __launch_bounds__(256) void gemm_bf16_nt(
    const ushort* __restrict__ A, const ushort* __restrict__ B,
    float* __restrict__ C, int M, int N, int K)
{
  __shared__ ushort sL[2][2][8192];   // [buf][A/B][2 halves x 8 segs x 512]
  int t = threadIdx.x;
  int wave = t >> 6, lane = t & 63;
  int wm = wave >> 1, wn = wave & 1;
  int lrow = lane & 15, quad = lane >> 4;
  int mt = blockIdx.x, nt = blockIdx.y;

  f32x4 acc[4][4];
  #pragma unroll
  for (int i = 0; i < 4; i++)
    #pragma unroll
    for (int j = 0; j < 4; j++)
      #pragma unroll
      for (int r = 0; r < 4; r++) acc[i][j][r] = 0.f;

  const ushort* aS0 = A + (size_t)(mt * 128 + (wave * 2 + 0) * 16 + lrow) * K + quad * 8;
  const ushort* aS1 = A + (size_t)(mt * 128 + (wave * 2 + 1) * 16 + lrow) * K + quad * 8;
  const ushort* bS0 = B + (size_t)(nt * 128 + (wave * 2 + 0) * 16 + lrow) * K + quad * 8;
  const ushort* bS1 = B + (size_t)(nt * 128 + (wave * 2 + 1) * 16 + lrow) * K + quad * 8;

  stage_tile(aS0, aS1, bS0, bS1, &sL[0][0][0], &sL[0][1][0], wave, 0);
  __syncthreads();

  const int NK = K >> 6;
  for (int it = 0; it < NK; it++) {
    if (it + 1 < NK)
      stage_tile(aS0, aS1, bS0, bS1,
                 &sL[(it + 1) & 1][0][0], &sL[(it + 1) & 1][1][0],
                 wave, (it + 1) * 64);
    const ushort* bufA = &sL[it & 1][0][0];
    const ushort* bufB = &sL[it & 1][1][0];
    #pragma unroll
    for (int h = 0; h < 2; h++) {
      bf16x8 af[4], bfr[4];
      #pragma unroll
      for (int i = 0; i < 4; i++)
        af[i] = *(const bf16x8*)(bufA + h * 4096 + (wm * 4 + i) * 512 + lane * 8);
      #pragma unroll
      for (int j = 0; j < 4; j++)
        bfr[j] = *(const bf16x8*)(bufB + h * 4096 + (wn * 4 + j) * 512 + lane * 8);
      #pragma unroll
      for (int i = 0; i < 4; i++)
        #pragma unroll
        for (int j = 0; j < 4; j++)
          acc[i][j] = __builtin_amdgcn_mfma_f32_16x16x32_bf16(af[i], bfr[j], acc[i][j], 0, 0, 0);
    }
    __syncthreads();
  }

  #pragma unroll
  for (int i = 0; i < 4; i++) {
    int m_base = mt * 128 + wm * 64 + i * 16 + quad * 4;
    #pragma unroll
    for (int j = 0; j < 4; j++) {
      int n = nt * 128 + wn * 64 + j * 16 + lrow;
      #pragma unroll
      for (int rr = 0; rr < 4; rr++)
        C[(size_t)(m_base + rr) * N + n] = acc[i][j][rr];
    }
  }
}

// ---------------------------------------------------------------------------
// conv_state_new[b][c][j] = mixed_qkv[b][S-3+j][c]  (from (B,S,NBIG) C-matrix)
// ---------------------------------------------------------------------------
__global__ void convstate_kernel(const float* __restrict__ Cbig,
                                 float* __restrict__ out)
{
  int idx = blockIdx.x * blockDim.x + threadIdx.x;
  if (idx >= B_ * CC_ * 3) return;
  int j = idx % 3;
  int c = (idx / 3) % CC_;
  int b = idx / (3 * CC_);
  out[idx] = Cbig[((size_t)(b * S_ + (S_ - 3 + j))) * NBIG + c];
}

// ---------------------------------------------------------------------------
// prep_qkv: conv(K=4)+silu; l2norm q/k heads. qkv read from C-matrix cols 0..8191
// ---------------------------------------------------------------------------
__global__ __launch_bounds__(128) void prep_qkv(
    const float* __restrict__ Cbig, const float* __restrict__ conv_state,
    const float* __restrict__ conv_w,
    float* __restrict__ Qn, float* __restrict__ Kn, float* __restrict__ Vb)
{
  int group = blockIdx.x, s = blockIdx.y, b = blockIdx.z;
  int t = threadIdx.x;
  int c = group * 128 + t;
  float acc = 0.f;
  #pragma unroll
  for (int kk = 0; kk < 4; kk++) {
    int sp = s - 3 + kk;
    float x = (sp < 0) ? conv_state[((size_t)(b * CC_ + c)) * 3 + (3 + sp)]
                       : Cbig[((size_t)(b * S_ + sp)) * NBIG + c];
    acc += conv_w[c * 4 + kk] * x;
  }
  float val = acc / (1.f + __expf(-acc));   // silu

  if (group < 32) {
    __shared__ float red2[2];
    float p = val * val;
    #pragma unroll
    for (int off = 32; off > 0; off >>= 1) p += __shfl_xor(p, off);
    if ((t & 63) == 0) red2[t >> 6] = p;
    __syncthreads();
    float r = rsqrtf(red2[0] + red2[1] + 1e-6f);
    if (group < 16) {
      r *= 0.08838834764831845f;  // 128^-0.5
      Qn[(((size_t)(b * HK_ + group)) * S_ + s) * DK_ + t] = val * r;
    } else {
      Kn[(((size_t)(b * HK_ + (group - 16))) * S_ + s) * DK_ + t] = val * r;
    }
  } else {
    Vb[(((size_t)(b * HV_ + (group - 32))) * S_ + s) * DV_ + t] = val;
  }
}

// ---------------------------------------------------------------------------
// prep_gb: g/beta from C-matrix cols 12288..12351
// ---------------------------------------------------------------------------
__global__ void prep_gb(const float* __restrict__ Cbig,
                        const float* __restrict__ A_log, const float* __restrict__ dt_bias,
                        float* __restrict__ g_buf, float* __restrict__ beta_buf)
{
  int idx = blockIdx.x * blockDim.x + threadIdx.x;
  if (idx >= B_ * HV_ * S_) return;
  int s = idx & (S_ - 1);
  int hv = (idx >> 10) & 31;
  int b = idx >> 15;
  float bv = Cbig[((size_t)(b * S_ + s)) * NBIG + 12288 + hv];
  float av = Cbig[((size_t)(b * S_ + s)) * NBIG + 12320 + hv];
  float x = av + dt_bias[hv];
  float sp = (x > 20.f) ? x : log1pf(__expf(x));
  g_buf[idx] = -__expf(A_log[hv]) * sp;
  beta_buf[idx] = 1.f / (1.f + __expf(-bv));
}

// ---------------------------------------------------------------------------
// cp_kernel: per (b,hv,chunk). G cumsum, M, A, Tinv, Kc, D0.
// ---------------------------------------------------------------------------
__device__ __forceinline__ int swf4(int r, int f) { return r * 32 + (f ^ (r & 31)); }
__device__ __forceinline__ int swf1(int r, int k) {
  return r * 128 + 4 * ((k >> 2) ^ (r & 31)) + (k & 3);
}

__global__ __launch_bounds__(256) void cp_kernel(
    const float* __restrict__ Qn, const float* __restrict__ Kn,
    const float* __restrict__ Vb,
    const float* __restrict__ g_buf, const float* __restrict__ beta_buf,
    float* __restrict__ G_buf, float* __restrict__ M_buf,
    float* __restrict__ KcD, float* __restrict__ D0p)
{
  __shared__ float sK[64 * 128];
  __shared__ float sX[32 * 128];
  __shared__ float sT[64 * 64];
  float* sG  = sT;
  float* sBe = sT + 64;
  float* sA  = sX;
  float* tTw = sX;
  float* tTb = sX;
  float4* sK4 = (float4*)sK;
  float4* sX4 = (float4*)sX;

  const int ch = blockIdx.x;
  const int bh = ch / NC_, c = ch % NC_;
  const int b = bh >> 5, hv = bh & 31, hk = hv >> 1;
  const int s0 = c * CS_;
  const int t = threadIdx.x;
  const size_t gOff = (size_t)bh * S_ + s0;

  float Gw0 = 0.f, Bw0 = 0.f;
  if (t < 64) {
    float gi = g_buf[gOff + t];
    Gw0 = gi;
    #pragma unroll
    for (int off = 1; off < 64; off <<= 1) {
      float o = __shfl_up(Gw0, off);
      if (t >= off) Gw0 += o;
    }
    G_buf[gOff + t] = Gw0;
    sG[t] = Gw0;
    Bw0 = beta_buf[gOff + t];
    sBe[t] = Bw0;
  }
  {
    const float4* src = (const float4*)(Kn + ((size_t)(b * HK_ + hk) * S_ + s0) * DK_);
    #pragma unroll
    for (int u = 0; u < 8; u++) {
      int idx = u * 256 + t;
      sK4[swf4(idx >> 5, idx & 31)] = src[idx];
    }
  }
  __syncthreads();

  const float4* qsrc = (const float4*)(Qn + ((size_t)(b * HK_ + hk) * S_ + s0) * DK_);
  {
    int ti2 = t >> 4, tj = t & 15;
    for (int h = 0; h < 2; h++) {
      #pragma unroll
      for (int u = 0; u < 4; u++) {
        int idx = u * 256 + t;
        sX4[swf4(idx >> 5, idx & 31)] = qsrc[h * 1024 + idx];
      }
      __syncthreads();
      float accM[2][4];
      #pragma unroll
      for (int a = 0; a < 2; a++)
        #pragma unroll
        for (int e = 0; e < 4; e++) accM[a][e] = 0.f;
      for (int k4 = 0; k4 < 32; k4++) {
        float4 qv[2], kv[4];
        qv[0] = sX4[swf4(ti2, k4)];
        qv[1] = sX4[swf4(ti2 + 16, k4)];
        #pragma unroll
        for (int e = 0; e < 4; e++) kv[e] = sK4[swf4(tj + 16 * e, k4)];
        #pragma unroll
        for (int a = 0; a < 2; a++)
          #pragma unroll
          for (int e = 0; e < 4; e++)
            accM[a][e] += qv[a].x * kv[e].x + qv[a].y * kv[e].y +
                          qv[a].z * kv[e].z + qv[a].w * kv[e].w;
      }
      #pragma unroll
      for (int a = 0; a < 2; a++) {
        int iG = h * 32 + ti2 + 16 * a;
        float Gi = sG[iG];
        #pragma unroll
        for (int e = 0; e < 4; e++) {
          int j = tj + 16 * e;
          float m = (j <= iG) ? __expf(Gi - sG[j]) * accM[a][e] : 0.f;
          M_buf[(size_t)ch * 4096 + iG * 64 + j] = m;
        }
      }
      __syncthreads();
    }
  }

  {
    int ti = t >> 4, tj = t & 15;
    float accA[4][4];
    #pragma unroll
    for (int a = 0; a < 4; a++)
      #pragma unroll
      for (int e = 0; e < 4; e++) accA[a][e] = 0.f;
    for (int k4 = 0; k4 < 32; k4++) {
      float4 ki[4], kj[4];
      #pragma unroll
      for (int e = 0; e < 4; e++) {
        ki[e] = sK4[swf4(ti + 16 * e, k4)];
        kj[e] = sK4[swf4(tj + 16 * e, k4)];
      }
      #pragma unroll
      for (int a = 0; a < 4; a++)
        #pragma unroll
        for (int e = 0; e < 4; e++)
          accA[a][e] += ki[a].x * kj[e].x + ki[a].y * kj[e].y +
                        ki[a].z * kj[e].z + ki[a].w * kj[e].w;
    }
    float resA[4][4];
    #pragma unroll
    for (int a = 0; a < 4; a++) {
      int i = ti + 16 * a;
      float Gi = sG[i], Bi = sBe[i];
      #pragma unroll
      for (int e = 0; e < 4; e++) {
        int j = tj + 16 * e;
        resA[a][e] = (j < i) ? Bi * __expf(Gi - sG[j]) * accA[a][e] : 0.f;
      }
    }
    __syncthreads();
    #pragma unroll
    for (int a = 0; a < 4; a++)
      #pragma unroll
      for (int e = 0; e < 4; e++)
        sA[(ti + 16 * a) * 64 + (tj + 16 * e)] = resA[a][e];
  }
  __syncthreads();

  if (t < 64) {
    sT[t] = (t == 0) ? 1.f : 0.f;
    for (int i = 1; i < 64; i++) {
      float acc = 0.f;
      for (int j = 0; j < i; j++) acc += sA[i * 64 + j] * sT[j * 64 + t];
      sT[i * 64 + t] = ((t == i) ? 1.f : 0.f) - acc;
    }
    float w = Bw0 * __expf(Gw0);
    for (int j = 0; j < 64; j++) {
      float wj = __shfl(w, j);
      tTw[j * 64 + t] = sT[t * 64 + j] * wj;
    }
  }
  __syncthreads();

  {
    int i04 = t >> 4, tk = t & 15;
    float accK[4][8];
    #pragma unroll
    for (int r = 0; r < 4; r++)
      #pragma unroll
      for (int u = 0; u < 8; u++) accK[r][u] = 0.f;
    for (int j = 0; j < 64; j++) {
      float4 tw = ((float4*)tTw)[j * 16 + i04];
      #pragma unroll
      for (int u = 0; u < 8; u++) {
        float kv = sK[swf1(j, tk + 16 * u)];
        accK[0][u] += tw.x * kv; accK[1][u] += tw.y * kv;
        accK[2][u] += tw.z * kv; accK[3][u] += tw.w * kv;
      }
    }
    size_t base = (size_t)ch * NBIG;
    #pragma unroll
    for (int r = 0; r < 4; r++)
      #pragma unroll
      for (int u = 0; u < 8; u++)
        KcD[base + (i04 * 4 + r) * 128 + tk + 16 * u] = accK[r][u];
  }
  __syncthreads();

  if (t < 64) {
    for (int j = 0; j < 64; j++) {
      float bj = __shfl(Bw0, j);
      tTb[j * 64 + t] = sT[t * 64 + j] * bj;
    }
  }
  {
    const float4* src = (const float4*)(Vb + ((size_t)bh * S_ + s0) * DV_);
    #pragma unroll
    for (int u = 0; u < 8; u++) {
      int idx = u * 256 + t;
      sK4[swf4(idx >> 5, idx & 31)] = src[idx];
    }
  }
  __syncthreads();

  {
    int i04 = t >> 4, tv_ = t & 15;
    float accD[4][8];
    #pragma unroll
    for (int r = 0; r < 4; r++)
      #pragma unroll
      for (int u = 0; u < 8; u++) accD[r][u] = 0.f;
    for (int j = 0; j < 64; j++) {
      float4 tb = ((float4*)tTb)[j * 16 + i04];
      #pragma unroll
      for (int u = 0; u < 8; u++) {
        float vv = sK[swf1(j, tv_ + 16 * u)];
        accD[0][u] += tb.x * vv; accD[1][u] += tb.y * vv;
        accD[2][u] += tb.z * vv; accD[3][u] += tb.w * vv;
      }
    }
    size_t base = (size_t)ch * NBIG;
    #pragma unroll
    for (int r = 0; r < 4; r++)
      #pragma unroll
      for (int u = 0; u < 8; u++)
        D0p[base + (i04 * 4 + r) * 128 + tv_ + 16 * u] = accD[r][u];
  }
}

// ---------------------------------------------------------------------------
// phaseb v4: 256 blocks, XCD-swizzled; Kd LDS layout XOR-swizzled.
// ---------------------------------------------------------------------------
__global__ __launch_bounds__(256) void phaseb_kernel(
    const float* __restrict__ rec_state, const float* __restrict__ Qn,
    const float* __restrict__ Kn, const float* __restrict__ G_buf,
    float* __restrict__ KcD, const float* __restrict__ D0p,
    float* __restrict__ Oq_buf, float* __restrict__ final_state)
{
  __shared__ float sS[128 * 32];    // state [k][v]
  __shared__ float sKT[128 * 64];   // Kc^T [k][i]; then Kd (swizzled) [i][k]
  __shared__ float sQT[128 * 64];   // Qb^T [k][i]
  __shared__ float sD[64 * 32];     // D [i][v]

  const int blk = blockIdx.x;       // xcd | vq<<3 | g<<5
  const int bh = (blk & 7) | ((blk >> 5) << 3);
  const int vq = (blk >> 3) & 3;
  const int b = bh >> 5, hv = bh & 31, hk = hv >> 1;
  const int t = threadIdx.x;
  const int vbase = vq * 32;
  const float* gG = G_buf + (size_t)bh * S_;

  #pragma unroll
  for (int u = 0; u < 4; u++) {
    int idx = u * 256 + t;
    int k = idx >> 3;
    int v4 = (idx & 7) * 4;
    *(float4*)(&sS[k * 32 + v4]) =
        *(const float4*)(&rec_state[((size_t)bh * 128 + k) * 128 + vbase + v4]);
  }
  __syncthreads();

  const int si = t & 63, skq = t >> 6;
  const int ti = t >> 3;
  const int tv = t & 7;
  const int tk = t >> 3;

  for (int c = 0; c < NC_; c++) {
    const size_t ch = (size_t)bh * NC_ + c;
    const int s0 = c * CS_;
    const float GC = gG[s0 + 63];
    const float eGC = __expf(GC);

    {
      float eGi = __expf(gG[s0 + si]);
      const float* kcRow = KcD + ch * NBIG + si * 128 + skq * 32;
      const float* qRow  = Qn + ((size_t)(b * HK_ + hk) * S_ + s0 + si) * DK_ + skq * 32;
      #pragma unroll
      for (int u = 0; u < 8; u++) {
        float4 kc = *(const float4*)(kcRow + u * 4);
        float4 qv = *(const float4*)(qRow + u * 4);
        int kk = skq * 32 + u * 4;
        sKT[(kk + 0) * 64 + si] = kc.x; sKT[(kk + 1) * 64 + si] = kc.y;
        sKT[(kk + 2) * 64 + si] = kc.z; sKT[(kk + 3) * 64 + si] = kc.w;
        sQT[(kk + 0) * 64 + si] = qv.x * eGi; sQT[(kk + 1) * 64 + si] = qv.y * eGi;
        sQT[(kk + 2) * 64 + si] = qv.z * eGi; sQT[(kk + 3) * 64 + si] = qv.w * eGi;
      }
    }
    __syncthreads();

    {
      float accD[2][4], accO[2][4];
      #pragma unroll
      for (int r = 0; r < 2; r++) {
        float4 d0 = *(const float4*)(&D0p[ch * NBIG + (size_t)(ti * 2 + r) * 128 + vbase + tv * 4]);
        accD[r][0] = d0.x; accD[r][1] = d0.y; accD[r][2] = d0.z; accD[r][3] = d0.w;
        accO[r][0] = accO[r][1] = accO[r][2] = accO[r][3] = 0.f;
      }
      for (int k = 0; k < 128; k++) {
        float2 kc = *(const float2*)(&sKT[k * 64 + ti * 2]);
        float2 qb = *(const float2*)(&sQT[k * 64 + ti * 2]);
        float4 sv = *(const float4*)(&sS[k * 32 + tv * 4]);
        accD[0][0] -= kc.x * sv.x; accD[0][1] -= kc.x * sv.y;
        accD[0][2] -= kc.x * sv.z; accD[0][3] -= kc.x * sv.w;
        accD[1][0] -= kc.y * sv.x; accD[1][1] -= kc.y * sv.y;
        accD[1][2] -= kc.y * sv.z; accD[1][3] -= kc.y * sv.w;
        accO[0][0] += qb.x * sv.x; accO[0][1] += qb.x * sv.y;
        accO[0][2] += qb.x * sv.z; accO[0][3] += qb.x * sv.w;
        accO[1][0] += qb.y * sv.x; accO[1][1] += qb.y * sv.y;
        accO[1][2] += qb.y * sv.z; accO[1][3] += qb.y * sv.w;
      }
      #pragma unroll
      for (int r = 0; r < 2; r++) {
        int i = ti * 2 + r;
        float4 dv = make_float4(accD[r][0], accD[r][1], accD[r][2], accD[r][3]);
        float4 ov = make_float4(accO[r][0], accO[r][1], accO[r][2], accO[r][3]);
        *(float4*)(&sD[i * 32 + tv * 4]) = dv;
        *(float4*)(&KcD[ch * NBIG + (size_t)i * 128 + vbase + tv * 4]) = dv;
        *(float4*)(&Oq_buf[ch * 8192 + (size_t)i * 128 + vbase + tv * 4]) = ov;
      }
    }
    __syncthreads();

    {
      float sc = __expf(GC - gG[s0 + si]);
      const float* kRow = Kn + ((size_t)(b * HK_ + hk) * S_ + s0 + si) * DK_ + skq * 32;
      #pragma unroll
      for (int u = 0; u < 8; u++) {
        float4 x = *(const float4*)(kRow + u * 4);
        x.x *= sc; x.y *= sc; x.z *= sc; x.w *= sc;
        int kg = skq * 8 + u;
        *(float4*)(&sKT[si * 128 + 4 * (kg ^ (si & 31))]) = x;
      }
    }
    __syncthreads();

    {
      float acc[4][4];
      #pragma unroll
      for (int r = 0; r < 4; r++)
        acc[r][0] = acc[r][1] = acc[r][2] = acc[r][3] = 0.f;
      for (int i = 0; i < 64; i++) {
        float4 d  = *(const float4*)(&sD[i * 32 + tv * 4]);
        float4 ka = *(const float4*)(&sKT[i * 128 + 4 * (tk ^ (i & 31))]);
        acc[0][0] += ka.x * d.x; acc[0][1] += ka.x * d.y;
        acc[0][2] += ka.x * d.z; acc[0][3] += ka.x * d.w;
        acc[1][0] += ka.y * d.x; acc[1][1] += ka.y * d.y;
        acc[1][2] += ka.y * d.z; acc[1][3] += ka.y * d.w;
        acc[2][0] += ka.z * d.x; acc[2][1] += ka.z * d.y;
        acc[2][2] += ka.z * d.z; acc[2][3] += ka.z * d.w;
        acc[3][0] += ka.w * d.x; acc[3][1] += ka.w * d.y;
        acc[3][2] += ka.w * d.z; acc[3][3] += ka.w * d.w;
      }
      #pragma unroll
      for (int r = 0; r < 4; r++) {
        int k = tk * 4 + r;
        float4 s = *(const float4*)(&sS[k * 32 + tv * 4]);
        s.x = s.x * eGC + acc[r][0]; s.y = s.y * eGC + acc[r][1];
        s.z = s.z * eGC + acc[r][2]; s.w = s.w * eGC + acc[r][3];
        *(float4*)(&sS[k * 32 + tv * 4]) = s;
      }
    }
    __syncthreads();
  }

  #pragma unroll
  for (int u = 0; u < 4; u++) {
    int idx = u * 256 + t;
    int k = idx >> 3;
    int v4 = (idx & 7) * 4;
    *(float4*)(&final_state[((size_t)bh * 128 + k) * 128 + vbase + v4]) =
        *(const float4*)(&sS[k * 32 + v4]);
  }
}

// ---------------------------------------------------------------------------
// phasec: O = Oq + M*D, RMS-norm + weight + silu(z) gate -> bf16 zg
// ---------------------------------------------------------------------------
__global__ __launch_bounds__(128) void phasec_kernel(
    const float* __restrict__ KcD, const float* __restrict__ Oq_buf,
    const float* __restrict__ M_buf, const float* __restrict__ norm_weight,
    const float* __restrict__ Cbig, ushort* __restrict__ zg_bf)
{
  __shared__ float sM[4096];
  __shared__ float red[2][2];
  int ch = blockIdx.x;
  int bh = ch / NC_, c = ch % NC_;
  int b = bh >> 5, hv = bh & 31;
  int s0 = c * CS_;
  int v = threadIdx.x;

  float Dr[64];
  #pragma unroll
  for (int j = 0; j < 64; j++) Dr[j] = KcD[(size_t)ch * NBIG + j * 128 + v];
  {
    const float4* src = (const float4*)(M_buf + (size_t)ch * 4096);
    #pragma unroll
    for (int u = 0; u < 8; u++) ((float4*)sM)[u * 128 + v] = src[u * 128 + v];
  }
  __syncthreads();
  float nw = norm_weight[v];

  for (int i = 0; i < 64; i++) {
    float o = Oq_buf[(size_t)ch * 8192 + i * 128 + v];
    const float4* mr = (const float4*)(sM + i * 64);
    #pragma unroll
    for (int j4 = 0; j4 < 16; j4++) {
      float4 m = mr[j4];
      o += m.x * Dr[4 * j4] + m.y * Dr[4 * j4 + 1] +
           m.z * Dr[4 * j4 + 2] + m.w * Dr[4 * j4 + 3];
    }
    float p = o * o;
    #pragma unroll
    for (int off = 32; off > 0; off >>= 1) p += __shfl_xor(p, off);
    if ((v & 63) == 0) red[i & 1][v >> 6] = p;
    __syncthreads();
    float var = (red[i & 1][0] + red[i & 1][1]) * (1.f / 128.f);
    float xn = o * rsqrtf(var + 1e-6f) * nw;
    float zv = Cbig[((size_t)(b * S_ + s0 + i)) * NBIG + 8192 + hv * DV_ + v];
    zg_bf[((size_t)(b * S_ + s0 + i)) * VALDIM_ + hv * DV_ + v] =
        f2bf_rne(xn * (zv / (1.f + __expf(-zv))));
  }
}

// ---------------------------------------------------------------------------
extern "C" void kernel_launch(void* const* d_in, const int* in_sizes, int n_in,
                              void* d_out, int out_size, void* d_ws, size_t ws_size,
                              hipStream_t stream)
{
  const float* hs          = (const float*)d_in[0];
  const float* conv_state  = (const float*)d_in[1];
  const float* rec_state   = (const float*)d_in[2];
  const float* W_qkv       = (const float*)d_in[3];
  const float* W_z         = (const float*)d_in[4];
  const float* W_b         = (const float*)d_in[5];
  const float* W_a         = (const float*)d_in[6];
  const float* conv_w      = (const float*)d_in[7];
  const float* dt_bias     = (const float*)d_in[8];
  const float* A_log       = (const float*)d_in[9];
  const float* norm_weight = (const float*)d_in[10];
  const float* W_out       = (const float*)d_in[11];

  float* out       = (float*)d_out;                      // (B,S,H)
  float* out_conv  = out + (size_t)B_ * S_ * H_;         // (B,C,3)
  float* out_state = out_conv + (size_t)B_ * CC_ * 3;    // (B,HV,DK,DV)

  float* ws = (float*)d_ws;
  float* Cbig = ws;                            // (2048, 12416) = 25,427,968
  float* KcD  = Cbig;
  float* D0p  = Cbig + (size_t)1024 * NBIG;
  float* g_buf    = ws + 25427968;
  float* beta_buf = ws + 25493504;
  float* G_buf    = ws + 25559040;
  float* Qn       = ws + 25624576;
  float* Kn       = ws + 29818880;
  float* Vb       = ws + 34013184;
  float* M_buf    = ws + 42401792;
  float* Oq_buf   = Vb;

  ushort* Wcat_bf = (ushort*)(ws + 25427968);
  ushort* hs_bf   = (ushort*)(ws + 38141952);
  ushort* zg_bf   = (ushort*)Qn;
  ushort* Wout_bf = (ushort*)Kn;

  const int M = B_ * S_;  // 2048

  // 0. converts
  f2bf_kernel<<<(M * H_) / 1024, 256, 0, stream>>>(hs, hs_bf, M * H_);
  wcat_kernel<<<(NBIG * H_) / 1024, 256, 0, stream>>>(W_qkv, W_z, W_b, W_a, Wcat_bf);
  // 1. fused qkv|z|b|a GEMM -> Cbig (double-buffered, m-fastest)
  gemm_bf16_nt<<<dim3(M / 128, NBIG / 128), 256, 0, stream>>>(hs_bf, Wcat_bf, Cbig, M, NBIG, H_);
  // 2. conv_state_new output
  convstate_kernel<<<(B_ * CC_ * 3 + 255) / 256, 256, 0, stream>>>(Cbig, out_conv);
  // 3. conv+silu+l2norm -> Qn,Kn,Vb ; gates
  prep_qkv<<<dim3(64, S_, B_), 128, 0, stream>>>(Cbig, conv_state, conv_w, Qn, Kn, Vb);
  prep_gb<<<(B_ * HV_ * S_ + 255) / 256, 256, 0, stream>>>(Cbig, A_log, dt_bias, g_buf, beta_buf);
  // 4. per-chunk matrices
  cp_kernel<<<B_ * HV_ * NC_, 256, 0, stream>>>(Qn, Kn, Vb, g_buf, beta_buf,
                                                G_buf, M_buf, KcD, D0p);
  // 5. sequential chunk recurrence
  phaseb_kernel<<<B_ * HV_ * 4, 256, 0, stream>>>(rec_state, Qn, Kn, G_buf,
                                                  KcD, D0p, Oq_buf, out_state);
  // 6. W_out convert + intra-chunk output/RMS/gate -> bf16
  f2bf_kernel<<<(H_ * VALDIM_) / 1024, 256, 0, stream>>>(W_out, Wout_bf, H_ * VALDIM_);
  phasec_kernel<<<B_ * HV_ * NC_, 128, 0, stream>>>(KcD, Oq_buf, M_buf,
                                                    norm_weight, Cbig, zg_bf);
  // 7. output GEMM (double-buffered, m-fastest)
  gemm_bf16_nt<<<dim3(M / 128, H_ / 128), 256, 0, stream>>>(zg_bf, Wout_bf, out, M, H_, VALDIM_);
}